// Round 10
// baseline (3154.402 us; speedup 1.0000x reference)
//
#include <hip/hip_runtime.h>
#include <math.h>
#include <stdint.h>

#define HD    128      // hidden
#define GATES 512      // 4H
#define BB    64       // batch
#define CL    512      // context len
#define QL    64       // query len

#define TM 128
#define TN 128
#define TK 32

typedef __attribute__((ext_vector_type(8))) short short8_t;
typedef __attribute__((ext_vector_type(4))) short short4_t;
typedef __attribute__((ext_vector_type(4))) float f32x4;
typedef __attribute__((ext_vector_type(2))) float f32x2;

__device__ __forceinline__ float fast_sigmoid(float x) {
    float e = __builtin_amdgcn_exp2f(-1.44269504f * x);
    return __builtin_amdgcn_rcpf(1.f + e);
}
__device__ __forceinline__ float fast_tanh(float x) {
    float e = __builtin_amdgcn_exp2f(2.88539008f * x);
    float r = __builtin_amdgcn_rcpf(e + 1.f);
    return 1.f - 2.f * r;
}
// sum across the 4 lanes of a quad via DPP quad_perm; all lanes get the sum.
__device__ __forceinline__ float quad_sum(float v) {
    int y = __builtin_amdgcn_mov_dpp(__float_as_int(v), 0xB1, 0xF, 0xF, 0); // l^1
    float s = v + __int_as_float(y);
    int z = __builtin_amdgcn_mov_dpp(__float_as_int(s), 0x4E, 0xF, 0xF, 0); // l^2
    return s + __int_as_float(z);
}
#define HPOS(e) ((e) + (((e) >> 5) << 2))

// ---------------------------------------------------------------------------
// Split W (rows=1024, K) fp32 into 3 bf16 planes, each (1024, Ksp), padded.
// ---------------------------------------------------------------------------
__global__ __launch_bounds__(256)
void splitW_k(const float* __restrict__ W, ushort* __restrict__ P, int K, int Ksp)
{
    int idx = blockIdx.x * 256 + threadIdx.x;
    int per_row = Ksp >> 2;
    int total = 1024 * per_row;
    if (idx >= total) return;
    int row = idx / per_row;
    int c4  = (idx - row * per_row) * 4;

    short4_t o1, o2, o3;
#pragma unroll
    for (int e = 0; e < 4; ++e) {
        int k = c4 + e;
        float x = (k < K) ? W[(size_t)row * K + k] : 0.f;
        uint32_t u1 = __float_as_uint(x) & 0xffff0000u;
        float r1 = x - __uint_as_float(u1);
        uint32_t u2 = __float_as_uint(r1) & 0xffff0000u;
        float r2 = r1 - __uint_as_float(u2);
        uint32_t u3 = __float_as_uint(r2) & 0xffff0000u;
        o1[e] = (short)(u1 >> 16);
        o2[e] = (short)(u2 >> 16);
        o3[e] = (short)(u3 >> 16);
    }
    size_t base = (size_t)row * Ksp + c4;
    size_t ps = (size_t)1024 * Ksp;
    *reinterpret_cast<short4_t*>(&P[base]) = o1;
    *reinterpret_cast<short4_t*>(&P[ps + base]) = o2;
    *reinterpret_cast<short4_t*>(&P[2 * ps + base]) = o3;
}

// ---------------------------------------------------------------------------
// MFMA GEMM v9: A fragments loaded straight from global (L2) and split
// in-register -> NO A-side LDS, no A ds_write/ds_read. B staged via
// global_load_lds into a DOUBLE-BUFFERED Bs; ONE barrier per k-tile
// (stage next-buf -> compute cur -> barrier). LDS 49152B -> 3 blocks/CU.
// ---------------------------------------------------------------------------
__global__ __launch_bounds__(256, 3)
void gemm_bf16x3(const float* __restrict__ A, const int* __restrict__ gidx,
                 const ushort* __restrict__ Wpl, const float* __restrict__ bias,
                 float* __restrict__ C, int M, int K, int Ksp)
{
    const int n0   = (blockIdx.x & 3) * TN;
    const int dir  = blockIdx.x >> 2;
    const int m0   = blockIdx.y * TM;
    const int tid  = threadIdx.x;
    const int lane = tid & 63;
    const int wid  = tid >> 6;
    const int wm   = (wid >> 1) * 64;
    const int wn   = (wid & 1) * 64;

    __shared__ __align__(16) ushort Bs[2][3][TN * TK];   // 49152 B

    // A fragment rows (hoisted gather)
    size_t arow[4];
#pragma unroll
    for (int i = 0; i < 4; ++i) {
        int m = m0 + wm + i * 16 + (lane & 15);
        arow[i] = gidx ? (size_t)gidx[m] : (size_t)m;
    }
    const int koffE = (lane >> 4) * 8;    // fp32 element offset in k-tile

    f32x4 acc[4][4];
#pragma unroll
    for (int i = 0; i < 4; ++i)
#pragma unroll
        for (int j = 0; j < 4; ++j) acc[i][j] = (f32x4)0.f;

    const size_t wps    = (size_t)1024 * Ksp;
    const size_t wdbase = (size_t)dir * 512 * Ksp;

    // stage helper constants (per-thread)
    const int s_pl   = (wid * 6) / 8;         // not used; chunks computed per t
    (void)s_pl;

    const int nt = Ksp / TK;

    // ---- prologue: stage tile 0 into buf 0 ----
#pragma unroll
    for (int t = 0; t < 6; ++t) {
        int chunk = wid * 6 + t;
        int pl = chunk >> 3;
        int ch = chunk & 7;
        int rrow = ch * 16 + (lane >> 2);
        int ksw  = ((lane & 3) ^ ((rrow >> 1) & 3)) * 8;
        const ushort* src = Wpl + (size_t)pl * wps + wdbase +
                            (size_t)(n0 + rrow) * Ksp + 0 + ksw;
        ushort* dst = &Bs[0][pl][ch * 512];
        __builtin_amdgcn_global_load_lds(
            reinterpret_cast<const __attribute__((address_space(1))) void*>(
                reinterpret_cast<uintptr_t>(src)),
            reinterpret_cast<__attribute__((address_space(3))) void*>(
                reinterpret_cast<uintptr_t>(dst)),
            16, 0, 0);
    }
    __syncthreads();

    int buf = 0;
    for (int kt = 0; kt < nt; ++kt) {
        const int k0 = kt * TK;

        // ---- stage next tile into the other buffer ----
        if (kt + 1 < nt) {
#pragma unroll
            for (int t = 0; t < 6; ++t) {
                int chunk = wid * 6 + t;
                int pl = chunk >> 3;
                int ch = chunk & 7;
                int rrow = ch * 16 + (lane >> 2);
                int ksw  = ((lane & 3) ^ ((rrow >> 1) & 3)) * 8;
                const ushort* src = Wpl + (size_t)pl * wps + wdbase +
                                    (size_t)(n0 + rrow) * Ksp + (k0 + TK) + ksw;
                ushort* dst = &Bs[buf ^ 1][pl][ch * 512];
                __builtin_amdgcn_global_load_lds(
                    reinterpret_cast<const __attribute__((address_space(1))) void*>(
                        reinterpret_cast<uintptr_t>(src)),
                    reinterpret_cast<__attribute__((address_space(3))) void*>(
                        reinterpret_cast<uintptr_t>(dst)),
                    16, 0, 0);
            }
        }

        // ---- A loads (issue early; L2 latency hides under B ds_reads) ----
        float4 ra[4][2];
        const bool tail = (k0 + TK > K);
        if (!tail) {
#pragma unroll
            for (int i = 0; i < 4; ++i) {
                const float* ap = A + arow[i] * K + k0 + koffE;
                ra[i][0] = *(const float4*)ap;
                ra[i][1] = *(const float4*)(ap + 4);
            }
        } else {
#pragma unroll
            for (int i = 0; i < 4; ++i) {
                const float* ap = A + arow[i] * K;
                float tmp[8];
#pragma unroll
                for (int e = 0; e < 8; ++e) {
                    int k = k0 + koffE + e;
                    tmp[e] = (k < K) ? ap[k] : 0.f;
                }
                ra[i][0] = make_float4(tmp[0], tmp[1], tmp[2], tmp[3]);
                ra[i][1] = make_float4(tmp[4], tmp[5], tmp[6], tmp[7]);
            }
        }

        // ---- B fragments (swizzled read; 2-way banks = free) ----
        short8_t bf0[4], bf1[4], bf2[4];
#pragma unroll
        for (int j = 0; j < 4; ++j) {
            int nrow = wn + j * 16 + (lane & 15);
            int ks = (((lane >> 4) ^ ((nrow >> 1) & 3)) * 8);
            bf0[j] = *reinterpret_cast<const short8_t*>(&Bs[buf][0][nrow * TK + ks]);
            bf1[j] = *reinterpret_cast<const short8_t*>(&Bs[buf][1][nrow * TK + ks]);
            bf2[j] = *reinterpret_cast<const short8_t*>(&Bs[buf][2][nrow * TK + ks]);
        }

        // ---- per-i: in-register split + 6-term MFMA ----
#pragma unroll
        for (int i = 0; i < 4; ++i) {
            float xs[8] = {ra[i][0].x, ra[i][0].y, ra[i][0].z, ra[i][0].w,
                           ra[i][1].x, ra[i][1].y, ra[i][1].z, ra[i][1].w};
            short8_t a1, a2, a3;
#pragma unroll
            for (int e = 0; e < 8; ++e) {
                uint32_t u1 = __float_as_uint(xs[e]) & 0xffff0000u;
                float r1 = xs[e] - __uint_as_float(u1);
                uint32_t u2 = __float_as_uint(r1) & 0xffff0000u;
                float r2 = r1 - __uint_as_float(u2);
                uint32_t u3 = __float_as_uint(r2) & 0xffff0000u;
                a1[e] = (short)(u1 >> 16);
                a2[e] = (short)(u2 >> 16);
                a3[e] = (short)(u3 >> 16);
            }
#pragma unroll
            for (int j = 0; j < 4; ++j) {
                f32x4 c = acc[i][j];
                c = __builtin_amdgcn_mfma_f32_16x16x32_bf16(a1, bf0[j], c, 0, 0, 0);
                c = __builtin_amdgcn_mfma_f32_16x16x32_bf16(a1, bf1[j], c, 0, 0, 0);
                c = __builtin_amdgcn_mfma_f32_16x16x32_bf16(a2, bf0[j], c, 0, 0, 0);
                c = __builtin_amdgcn_mfma_f32_16x16x32_bf16(a2, bf1[j], c, 0, 0, 0);
                c = __builtin_amdgcn_mfma_f32_16x16x32_bf16(a1, bf2[j], c, 0, 0, 0);
                c = __builtin_amdgcn_mfma_f32_16x16x32_bf16(a3, bf0[j], c, 0, 0, 0);
                acc[i][j] = c;
            }
        }
        __syncthreads();     // drains stage DMAs (vmcnt 0) + joins waves
        buf ^= 1;
    }

    float* Cd = C + (size_t)dir * M * 512;
#pragma unroll
    for (int j = 0; j < 4; ++j) {
        int col = n0 + wn + j * 16 + (lane & 15);
        float bv = bias[dir * 512 + col];
#pragma unroll
        for (int i = 0; i < 4; ++i) {
            int rbase = m0 + wm + i * 16 + ((lane >> 4) << 2);
#pragma unroll
            for (int r = 0; r < 4; ++r)
                Cd[(size_t)(rbase + r) * 512 + col] = acc[i][j][r] + bv;
        }
    }
}

// ---------------------------------------------------------------------------
// LSTM scan (DPP + packed fp32): block per (batch, dir[, layer via z]).
// ---------------------------------------------------------------------------
__global__ __launch_bounds__(512) __attribute__((amdgpu_waves_per_eu(2, 2)))
void lstm_dpp(const float* __restrict__ xgP, const float* __restrict__ WhhP,
              float* __restrict__ hoP, int TP,
              const float* __restrict__ xgQ, const float* __restrict__ WhhQ,
              float* __restrict__ hoQ, int TQ)
{
    const int b    = blockIdx.x;
    const int dir  = blockIdx.y;
    const int tid  = threadIdx.x;
    const int l    = tid & 63;
    const int w    = tid >> 6;
    const int u    = w * 16 + (l >> 2);   // hidden unit 0..127
    const int s    = l & 3;               // k-slice 0..3

    const float* xg; const float* Whh; float* ho; int T;
    if (blockIdx.z == 0) { xg = xgP; Whh = WhhP; ho = hoP; T = TP; }
    else                 { xg = xgQ; Whh = WhhQ; ho = hoQ; T = TQ; }

    const float* xgd = xg + (size_t)dir * BB * T * GATES;

    f32x2 wv2[4][16];
#pragma unroll
    for (int g = 0; g < 4; ++g) {
        const float* wr = Whh + ((size_t)dir * GATES + g * 128 + u) * HD + s * 32;
#pragma unroll
        for (int j = 0; j < 8; ++j) {
            float4 t4 = *(const float4*)(wr + j * 4);
            wv2[g][2 * j]     = f32x2{t4.x, t4.y};
            wv2[g][2 * j + 1] = f32x2{t4.z, t4.w};
        }
    }

    __shared__ __align__(16) float hs[2][140];

    if (tid < 140) { hs[0][tid] = 0.f; }
    float c = 0.f;

    int t = dir ? (T - 1) : 0;
    const int dt = dir ? -1 : 1;

    float xc[4], xn[4];
#pragma unroll
    for (int g = 0; g < 4; ++g)
        xc[g] = xgd[((size_t)b * T + t) * GATES + g * 128 + u];

    const int rdbase = HPOS(s * 32);
    __syncthreads();

    for (int step = 0; step < T; ++step) {
        const int tn = t + dt;
        const int rbuf = step & 1, wbuf = rbuf ^ 1;

        if (step + 1 < T) {
#pragma unroll
            for (int g = 0; g < 4; ++g)
                xn[g] = xgd[((size_t)b * T + tn) * GATES + g * 128 + u];
        }

        f32x2 p0 = {0.f, 0.f}, p1 = {0.f, 0.f}, p2 = {0.f, 0.f}, p3 = {0.f, 0.f};
#pragma unroll
        for (int j = 0; j < 8; ++j) {
            float4 h4 = *(const float4*)&hs[rbuf][rdbase + j * 4];
            f32x2 hl = {h4.x, h4.y}, hh = {h4.z, h4.w};
            p0 = __builtin_elementwise_fma(wv2[0][2 * j], hl, p0);
            p1 = __builtin_elementwise_fma(wv2[1][2 * j], hl, p1);
            p2 = __builtin_elementwise_fma(wv2[2][2 * j], hl, p2);
            p3 = __builtin_elementwise_fma(wv2[3][2 * j], hl, p3);
            p0 = __builtin_elementwise_fma(wv2[0][2 * j + 1], hh, p0);
            p1 = __builtin_elementwise_fma(wv2[1][2 * j + 1], hh, p1);
            p2 = __builtin_elementwise_fma(wv2[2][2 * j + 1], hh, p2);
            p3 = __builtin_elementwise_fma(wv2[3][2 * j + 1], hh, p3);
        }
        float pre0 = quad_sum(p0.x + p0.y) + xc[0];
        float pre1 = quad_sum(p1.x + p1.y) + xc[1];
        float pre2 = quad_sum(p2.x + p2.y) + xc[2];
        float pre3 = quad_sum(p3.x + p3.y) + xc[3];

        float ig = fast_sigmoid(pre0);
        float fg = fast_sigmoid(pre1);
        float gg = fast_tanh(pre2);
        float og = fast_sigmoid(pre3);
        c = fg * c + ig * gg;
        float h = og * fast_tanh(c);

        if (s == 0) {
            hs[wbuf][HPOS(u)] = h;
            ho[((size_t)b * T + t) * 256 + dir * HD + u] = h;
        }
        __syncthreads();

#pragma unroll
        for (int g = 0; g < 4; ++g) xc[g] = xn[g];
        t = tn;
    }
}

// ---------------------------------------------------------------------------
__global__ void rowdot(const float* __restrict__ X, const float* __restrict__ w,
                       float* __restrict__ out, int N, int D)
{
    int gw   = (int)((blockIdx.x * blockDim.x + threadIdx.x) >> 6);
    int lane = threadIdx.x & 63;
    if (gw >= N) return;
    const float* xp = X + (size_t)gw * D;
    float s = 0.f;
    for (int d = lane; d < D; d += 64) s += xp[d] * w[d];
#pragma unroll
    for (int off = 32; off; off >>= 1) s += __shfl_down(s, off);
    if (lane == 0) out[gw] = s;
}

// ---------------------------------------------------------------------------
__global__ __launch_bounds__(256)
void att_s(const float* __restrict__ co, const float* __restrict__ qo,
           const float* __restrict__ cw, const float* __restrict__ qw,
           const float* __restrict__ wcq, const float* __restrict__ attb,
           float* __restrict__ s)
{
    int b  = blockIdx.x;
    int c0 = blockIdx.y * 64;
    int tid = threadIdx.x;
    int tq = tid & 15, trc = tid >> 4;
    int cbase = c0 + trc * 4, qbase = tq * 4;

    float acc[4][4];
#pragma unroll
    for (int i = 0; i < 4; ++i)
#pragma unroll
        for (int j = 0; j < 4; ++j) acc[i][j] = 0.f;

    for (int d = 0; d < 256; d += 4) {
        float4 wv = *(const float4*)&wcq[d];
        float4 cv[4], qv[4];
#pragma unroll
        for (int i = 0; i < 4; ++i) {
            float4 v = *(const float4*)&co[((size_t)b * CL + cbase + i) * 256 + d];
            cv[i].x = v.x * wv.x; cv[i].y = v.y * wv.y;
            cv[i].z = v.z * wv.z; cv[i].w = v.w * wv.w;
        }
#pragma unroll
        for (int j = 0; j < 4; ++j)
            qv[j] = *(const float4*)&qo[((size_t)b * QL + qbase + j) * 256 + d];
#pragma unroll
        for (int i = 0; i < 4; ++i)
#pragma unroll
            for (int j = 0; j < 4; ++j)
                acc[i][j] += cv[i].x * qv[j].x + cv[i].y * qv[j].y +
                             cv[i].z * qv[j].z + cv[i].w * qv[j].w;
    }
    float ab = attb[0];
#pragma unroll
    for (int i = 0; i < 4; ++i) {
        float cwv = cw[b * CL + cbase + i];
#pragma unroll
        for (int j = 0; j < 4; ++j) {
            s[((size_t)b * CL + cbase + i) * QL + qbase + j] =
                acc[i][j] + cwv + qw[b * QL + qbase + j] + ab;
        }
    }
}

// ---------------------------------------------------------------------------
__global__ void softmax_q(float* __restrict__ s, float* __restrict__ smax)
{
    int gw   = (int)((blockIdx.x * blockDim.x + threadIdx.x) >> 6);
    int lane = threadIdx.x & 63;
    float v = s[(size_t)gw * QL + lane];
    float mx = v;
#pragma unroll
    for (int off = 32; off; off >>= 1) mx = fmaxf(mx, __shfl_xor(mx, off));
    float e = expf(v - mx);
    float sm = e;
#pragma unroll
    for (int off = 32; off; off >>= 1) sm += __shfl_xor(sm, off);
    s[(size_t)gw * QL + lane] = e / sm;
    if (lane == 0) smax[gw] = mx;
}

// ---------------------------------------------------------------------------
__global__ __launch_bounds__(512)
void bw_k(const float* __restrict__ smax, float* __restrict__ bw)
{
    int b = blockIdx.x, c = threadIdx.x;
    int lane = c & 63, wid = c >> 6;
    __shared__ float red[8];
    float v = smax[b * CL + c];
    float mx = v;
#pragma unroll
    for (int off = 32; off; off >>= 1) mx = fmaxf(mx, __shfl_xor(mx, off));
    if (lane == 0) red[wid] = mx;
    __syncthreads();
    float bm = red[0];
#pragma unroll
    for (int w = 1; w < 8; ++w) bm = fmaxf(bm, red[w]);
    float e = expf(v - bm);
    float sm = e;
#pragma unroll
    for (int off = 32; off; off >>= 1) sm += __shfl_xor(sm, off);
    __syncthreads();
    if (lane == 0) red[wid] = sm;
    __syncthreads();
    float ts = 0.f;
#pragma unroll
    for (int w = 0; w < 8; ++w) ts += red[w];
    bw[b * CL + c] = e / ts;
}

// ---------------------------------------------------------------------------
__global__ __launch_bounds__(256)
void q2c_k(const float* __restrict__ bw, const float* __restrict__ co,
           float* __restrict__ q2c)
{
    int b = blockIdx.x, d = threadIdx.x;
    float acc = 0.f;
    for (int c = 0; c < CL; ++c)
        acc += bw[b * CL + c] * co[((size_t)b * CL + c) * 256 + d];
    q2c[b * 256 + d] = acc;
}

// ---------------------------------------------------------------------------
__global__ __launch_bounds__(256)
void c2q_g(const float* __restrict__ a, const float* __restrict__ qo,
           const float* __restrict__ co, const float* __restrict__ q2c,
           float* __restrict__ g)
{
    int b  = blockIdx.x;
    int c  = blockIdx.y * 64 + (threadIdx.x >> 2);
    int gq = threadIdx.x & 3;

    float4 acc[16];
#pragma unroll
    for (int jj = 0; jj < 16; ++jj) acc[jj] = make_float4(0.f, 0.f, 0.f, 0.f);

    const float* ar = a + ((size_t)b * CL + c) * QL;
    for (int q = 0; q < QL; ++q) {
        float av = ar[q];
        const float* qr = qo + ((size_t)b * QL + q) * 256;
#pragma unroll
        for (int jj = 0; jj < 16; ++jj) {
            float4 qv = *(const float4*)&qr[4 * gq + 16 * jj];
            acc[jj].x += av * qv.x; acc[jj].y += av * qv.y;
            acc[jj].z += av * qv.z; acc[jj].w += av * qv.w;
        }
    }
    size_t gbase = ((size_t)b * CL + c) * 1024;
    const float* corow = co + ((size_t)b * CL + c) * 256;
    const float* q2cr  = q2c + b * 256;
#pragma unroll
    for (int jj = 0; jj < 16; ++jj) {
        int d = 4 * gq + 16 * jj;
        float4 cv = *(const float4*)&corow[d];
        float4 qc = *(const float4*)&q2cr[d];
        float4 cq = acc[jj];
        *(float4*)&g[gbase + d] = cv;
        *(float4*)&g[gbase + 256 + d] = cq;
        float4 t;
        t.x = cv.x * cq.x; t.y = cv.y * cq.y; t.z = cv.z * cq.z; t.w = cv.w * cq.w;
        *(float4*)&g[gbase + 512 + d] = t;
        t.x = cv.x * qc.x; t.y = cv.y * qc.y; t.z = cv.z * qc.z; t.w = cv.w * qc.w;
        *(float4*)&g[gbase + 768 + d] = t;
    }
}

// ---------------------------------------------------------------------------
__global__ void logits_k(const float* __restrict__ g, const float* __restrict__ m,
                         const float* __restrict__ m2o,
                         const float* __restrict__ p1wg, const float* __restrict__ p1wm,
                         const float* __restrict__ p1b,
                         const float* __restrict__ p2wg, const float* __restrict__ p2wm,
                         const float* __restrict__ p2b,
                         float* __restrict__ lp1, float* __restrict__ lp2)
{
    int row  = (int)((blockIdx.x * blockDim.x + threadIdx.x) >> 6);
    int lane = threadIdx.x & 63;
    const float* gr = g + (size_t)row * 1024;
    float s1 = 0.f, s2 = 0.f;
    for (int d = lane; d < 1024; d += 64) {
        float gv = gr[d];
        s1 += gv * p1wg[d];
        s2 += gv * p2wg[d];
    }
    const float* mr  = m   + (size_t)row * 256;
    const float* m2r = m2o + (size_t)row * 256;
    for (int d = lane; d < 256; d += 64) {
        s1 += mr[d] * p1wm[d];
        s2 += m2r[d] * p2wm[d];
    }
#pragma unroll
    for (int off = 32; off; off >>= 1) {
        s1 += __shfl_down(s1, off);
        s2 += __shfl_down(s2, off);
    }
    if (lane == 0) {
        lp1[row] = s1 + p1b[0];
        lp2[row] = s2 + p2b[0];
    }
}

// ---------------------------------------------------------------------------
__global__ __launch_bounds__(512)
void masked_softmax(const float* __restrict__ lp1, const float* __restrict__ lp2,
                    const int* __restrict__ p, float* __restrict__ out)
{
    int b = blockIdx.x, c = threadIdx.x;
    int lane = c & 63, wid = c >> 6;
    const float* lp = blockIdx.y ? lp2 : lp1;
    float* o = out + (size_t)blockIdx.y * BB * CL;

    __shared__ float red[8];
    float v = (p[b * CL + c] != 0) ? lp[b * CL + c] : -INFINITY;
    float mx = v;
#pragma unroll
    for (int off = 32; off; off >>= 1) mx = fmaxf(mx, __shfl_xor(mx, off));
    if (lane == 0) red[wid] = mx;
    __syncthreads();
    float bm = red[0];
#pragma unroll
    for (int w = 1; w < 8; ++w) bm = fmaxf(bm, red[w]);
    float e = expf(v - bm);
    float sm = e;
#pragma unroll
    for (int off = 32; off; off >>= 1) sm += __shfl_xor(sm, off);
    __syncthreads();
    if (lane == 0) red[wid] = sm;
    __syncthreads();
    float ts = 0.f;
#pragma unroll
    for (int w = 0; w < 8; ++w) ts += red[w];
    o[b * CL + c] = e / ts;
}

// ---------------------------------------------------------------------------
extern "C" void kernel_launch(void* const* d_in, const int* in_sizes, int n_in,
                              void* d_out, int out_size, void* d_ws, size_t ws_size,
                              hipStream_t stream)
{
    const int*   p        = (const int*)d_in[0];
    const int*   q        = (const int*)d_in[1];
    const float* emb      = (const float*)d_in[2];
    const float* qenc_Wih = (const float*)d_in[3];
    const float* qenc_Whh = (const float*)d_in[4];
    const float* qenc_b   = (const float*)d_in[5];
    const float* penc_Wih = (const float*)d_in[6];
    const float* penc_Whh = (const float*)d_in[7];
    const float* penc_b   = (const float*)d_in[8];
    const float* m1_Wih   = (const float*)d_in[9];
    const float* m1_Whh   = (const float*)d_in[10];
    const float* m1_b     = (const float*)d_in[11];
    const float* m2_Wih   = (const float*)d_in[12];
    const float* m2_Whh   = (const float*)d_in[13];
    const float* m2_b     = (const float*)d_in[14];
    const float* out_Wih  = (const float*)d_in[15];
    const float* out_Whh  = (const float*)d_in[16];
    const float* out_b    = (const float*)d_in[17];
    const float* att_wc   = (const float*)d_in[18];
    const float* att_wq   = (const float*)d_in[19];
    const float* att_wcq  = (const float*)d_in[20];
    const float* att_b    = (const float*)d_in[21];
    const float* p1_wg    = (const float*)d_in[22];
    const float* p1_wm    = (const float*)d_in[23];
    const float* p1_b     = (const float*)d_in[24];
    const float* p2_wg    = (const float*)d_in[25];
    const float* p2_wm    = (const float*)d_in[26];
    const float* p2_b     = (const float*)d_in[27];

    float* ws = (float*)d_ws;
    size_t off = 0;
    auto alloc = [&](size_t n) { float* r = ws + off; off += n; return r; };
    auto allocU = [&](size_t nsh) { ushort* r = (ushort*)(ws + off); off += (nsh + 1) / 2; return r; };

    const size_t NC = (size_t)BB * CL;     // 32768
    const size_t NQ = (size_t)BB * QL;     // 4096

    float* xgA  = alloc(2 * NC * GATES);   // gate preacts, reused per layer
    float* gbuf = alloc(NC * 1024);        // g  (xgQ aliases its head: dead before g written)
    float* xgQ  = gbuf;
    float* co   = alloc(NC * 256);
    float* qo   = alloc(NQ * 256);
    float* sbuf = alloc(NC * QL);          // s, then a (in place)
    float* cw   = alloc(NC);
    float* qw   = alloc(NQ);
    float* smax = alloc(NC);
    float* bw   = alloc(NC);
    float* q2c  = alloc((size_t)BB * 256);
    float* mmid = alloc(NC * 256);
    float* mbuf = alloc(NC * 256);
    float* m2o  = alloc(NC * 256);
    float* lp1  = alloc(NC);
    float* lp2  = alloc(NC);
    // bf16 weight planes: [3][1024][Ksp]
    ushort* WqP  = allocU((size_t)3 * 1024 * 320);
    ushort* WpP  = allocU((size_t)3 * 1024 * 320);
    ushort* Wm1P = allocU((size_t)3 * 1024 * 1024);
    ushort* Wm2P = allocU((size_t)3 * 1024 * 256);
    ushort* WoP  = allocU((size_t)3 * 1024 * 256);
    (void)ws_size; (void)in_sizes; (void)n_in; (void)out_size;

    // ---- weight splits ----
    splitW_k<<<dim3(1024 * 80 / 256), 256, 0, stream>>>(qenc_Wih, WqP, 300, 320);
    splitW_k<<<dim3(1024 * 80 / 256), 256, 0, stream>>>(penc_Wih, WpP, 300, 320);
    splitW_k<<<dim3(1024 * 256 / 256), 256, 0, stream>>>(m1_Wih, Wm1P, 1024, 1024);
    splitW_k<<<dim3(1024 * 64 / 256), 256, 0, stream>>>(m2_Wih, Wm2P, 256, 256);
    splitW_k<<<dim3(1024 * 64 / 256), 256, 0, stream>>>(out_Wih, WoP, 256, 256);

    // ---- encoders (P and Q scans in one launch via z) ----
    gemm_bf16x3<<<dim3(8, (int)(NQ / TM)), 256, 0, stream>>>(emb, q, WqP, qenc_b, xgQ, (int)NQ, 300, 320);
    gemm_bf16x3<<<dim3(8, (int)(NC / TM)), 256, 0, stream>>>(emb, p, WpP, penc_b, xgA, (int)NC, 300, 320);
    lstm_dpp<<<dim3(BB, 2, 2), 512, 0, stream>>>(xgA, penc_Whh, co, CL,
                                                 xgQ, qenc_Whh, qo, QL);

    // ---- attention ----
    rowdot<<<dim3((int)(NC * 64 / 256)), 256, 0, stream>>>(co, att_wc, cw, (int)NC, 256);
    rowdot<<<dim3((int)(NQ * 64 / 256)), 256, 0, stream>>>(qo, att_wq, qw, (int)NQ, 256);
    att_s<<<dim3(BB, CL / 64), 256, 0, stream>>>(co, qo, cw, qw, att_wcq, att_b, sbuf);
    softmax_q<<<dim3((int)(NC * 64 / 256)), 256, 0, stream>>>(sbuf, smax);
    bw_k<<<dim3(BB), 512, 0, stream>>>(smax, bw);
    q2c_k<<<dim3(BB), 256, 0, stream>>>(bw, co, q2c);
    c2q_g<<<dim3(BB, CL / 64), 256, 0, stream>>>(sbuf, qo, co, q2c, gbuf);

    // ---- modeling layers ----
    gemm_bf16x3<<<dim3(8, (int)(NC / TM)), 256, 0, stream>>>(gbuf, nullptr, Wm1P, m1_b, xgA, (int)NC, 1024, 1024);
    lstm_dpp<<<dim3(BB, 2, 1), 512, 0, stream>>>(xgA, m1_Whh, mmid, CL,
                                                 xgA, m1_Whh, mmid, CL);
    gemm_bf16x3<<<dim3(8, (int)(NC / TM)), 256, 0, stream>>>(mmid, nullptr, Wm2P, m2_b, xgA, (int)NC, 256, 256);
    lstm_dpp<<<dim3(BB, 2, 1), 512, 0, stream>>>(xgA, m2_Whh, mbuf, CL,
                                                 xgA, m2_Whh, mbuf, CL);
    gemm_bf16x3<<<dim3(8, (int)(NC / TM)), 256, 0, stream>>>(mbuf, nullptr, WoP, out_b, xgA, (int)NC, 256, 256);
    lstm_dpp<<<dim3(BB, 2, 1), 512, 0, stream>>>(xgA, out_Whh, m2o, CL,
                                                 xgA, out_Whh, m2o, CL);

    // ---- output ----
    logits_k<<<dim3((int)(NC * 64 / 256)), 256, 0, stream>>>(gbuf, mbuf, m2o,
        p1_wg, p1_wm, p1_b, p2_wg, p2_wm, p2_b, lp1, lp2);
    masked_softmax<<<dim3(BB, 2), 512, 0, stream>>>(lp1, lp2, p, (float*)d_out);
}

// Round 11
// 2739.785 us; speedup vs baseline: 1.1513x; 1.1513x over previous
//
#include <hip/hip_runtime.h>
#include <math.h>
#include <stdint.h>

#define HD    128      // hidden
#define GATES 512      // 4H
#define BB    64       // batch
#define CL    512      // context len
#define QL    64       // query len

#define TM 128
#define TN 128
#define TK 32

typedef __attribute__((ext_vector_type(8))) short short8_t;
typedef __attribute__((ext_vector_type(4))) short short4_t;
typedef __attribute__((ext_vector_type(4))) float f32x4;
typedef __attribute__((ext_vector_type(2))) float f32x2;

__device__ __forceinline__ float fast_sigmoid(float x) {
    float e = __builtin_amdgcn_exp2f(-1.44269504f * x);
    return __builtin_amdgcn_rcpf(1.f + e);
}
__device__ __forceinline__ float fast_tanh(float x) {
    float e = __builtin_amdgcn_exp2f(2.88539008f * x);
    float r = __builtin_amdgcn_rcpf(e + 1.f);
    return 1.f - 2.f * r;
}
__device__ __forceinline__ float quad_sum(float v) {
    int y = __builtin_amdgcn_mov_dpp(__float_as_int(v), 0xB1, 0xF, 0xF, 0); // l^1
    float s = v + __int_as_float(y);
    int z = __builtin_amdgcn_mov_dpp(__float_as_int(s), 0x4E, 0xF, 0xF, 0); // l^2
    return s + __int_as_float(z);
}
#define HPOS(e) ((e) + (((e) >> 5) << 2))

// ---------------------------------------------------------------------------
// Split W (rows=1024, K) fp32 into 3 bf16 planes, each (1024, Ksp), padded.
// ---------------------------------------------------------------------------
__global__ __launch_bounds__(256)
void splitW_k(const float* __restrict__ W, ushort* __restrict__ P, int K, int Ksp)
{
    int idx = blockIdx.x * 256 + threadIdx.x;
    int per_row = Ksp >> 2;
    int total = 1024 * per_row;
    if (idx >= total) return;
    int row = idx / per_row;
    int c4  = (idx - row * per_row) * 4;

    short4_t o1, o2, o3;
#pragma unroll
    for (int e = 0; e < 4; ++e) {
        int k = c4 + e;
        float x = (k < K) ? W[(size_t)row * K + k] : 0.f;
        uint32_t u1 = __float_as_uint(x) & 0xffff0000u;
        float r1 = x - __uint_as_float(u1);
        uint32_t u2 = __float_as_uint(r1) & 0xffff0000u;
        float r2 = r1 - __uint_as_float(u2);
        uint32_t u3 = __float_as_uint(r2) & 0xffff0000u;
        o1[e] = (short)(u1 >> 16);
        o2[e] = (short)(u2 >> 16);
        o3[e] = (short)(u3 >> 16);
    }
    size_t base = (size_t)row * Ksp + c4;
    size_t ps = (size_t)1024 * Ksp;
    *reinterpret_cast<short4_t*>(&P[base]) = o1;
    *reinterpret_cast<short4_t*>(&P[ps + base]) = o2;
    *reinterpret_cast<short4_t*>(&P[2 * ps + base]) = o3;
}

// ---------------------------------------------------------------------------
// MFMA GEMM v10: A staged in LDS as RAW FP32 [128][32] with 16B-slot XOR
// swizzle (slot' = slot ^ (row&7)): conflict-free writes AND reads (128-B
// rows). bf16x3 split happens in-register after the LDS read. B staged via
// global_load_lds (swizzled source + read). Both double-buffered: 80 KB LDS,
// 2 blocks/CU, ONE barrier per k-tile.
// ---------------------------------------------------------------------------
__global__ __launch_bounds__(256, 2)
void gemm_bf16x3(const float* __restrict__ A, const int* __restrict__ gidx,
                 const ushort* __restrict__ Wpl, const float* __restrict__ bias,
                 float* __restrict__ C, int M, int K, int Ksp)
{
    const int n0   = (blockIdx.x & 3) * TN;
    const int dir  = blockIdx.x >> 2;
    const int m0   = blockIdx.y * TM;
    const int tid  = threadIdx.x;
    const int lane = tid & 63;
    const int wid  = tid >> 6;
    const int wm   = (wid >> 1) * 64;
    const int wn   = (wid & 1) * 64;

    __shared__ __align__(16) float  Asf[2][TM * TK];     // 32768 B
    __shared__ __align__(16) ushort Bs[2][3][TN * TK];   // 49152 B

    // --- A staging mapping: thread -> (rows srow+32r, col slot scol) ---
    const int srow = tid >> 3;          // 0..31
    const int scol = tid & 7;           // 16B slot 0..7
    size_t sArow[4];
#pragma unroll
    for (int r = 0; r < 4; ++r) {
        int m = m0 + srow + r * 32;
        sArow[r] = gidx ? (size_t)gidx[m] : (size_t)m;
    }

    // --- A fragment read mapping ---
    const int s0 = (lane >> 4) * 2;     // first 16B slot of this lane's 8 floats

    f32x4 acc[4][4];
#pragma unroll
    for (int i = 0; i < 4; ++i)
#pragma unroll
        for (int j = 0; j < 4; ++j) acc[i][j] = (f32x4)0.f;

    const size_t wps    = (size_t)1024 * Ksp;
    const size_t wdbase = (size_t)dir * 512 * Ksp;
    const int nt = Ksp / TK;

    auto stageB = [&](int k0, int bufb) {
#pragma unroll
        for (int t = 0; t < 6; ++t) {
            int chunk = wid * 6 + t;
            int pl = chunk >> 3;
            int ch = chunk & 7;
            int rrow = ch * 16 + (lane >> 2);
            int ksw  = ((lane & 3) ^ ((rrow >> 1) & 3)) * 8;
            const ushort* src = Wpl + (size_t)pl * wps + wdbase +
                                (size_t)(n0 + rrow) * Ksp + k0 + ksw;
            ushort* dst = &Bs[bufb][pl][ch * 512];
            __builtin_amdgcn_global_load_lds(
                reinterpret_cast<const __attribute__((address_space(1))) void*>(
                    reinterpret_cast<uintptr_t>(src)),
                reinterpret_cast<__attribute__((address_space(3))) void*>(
                    reinterpret_cast<uintptr_t>(dst)),
                16, 0, 0);
        }
    };
    auto stageA = [&](int k0, int bufb) {
#pragma unroll
        for (int r = 0; r < 4; ++r) {
            int row = srow + r * 32;
            int kf  = k0 + scol * 4;
            float4 v;
            if (kf + 4 <= K) {
                v = *(const float4*)(A + sArow[r] * K + kf);
            } else {
                const float* ap = A + sArow[r] * K;
                v.x = (kf     < K) ? ap[kf]     : 0.f;
                v.y = (kf + 1 < K) ? ap[kf + 1] : 0.f;
                v.z = (kf + 2 < K) ? ap[kf + 2] : 0.f;
                v.w = (kf + 3 < K) ? ap[kf + 3] : 0.f;
            }
            int sw = scol ^ (row & 7);
            *(float4*)&Asf[bufb][row * TK + sw * 4] = v;
        }
    };

    // ---- prologue ----
    stageB(0, 0);
    stageA(0, 0);
    __syncthreads();

    int buf = 0;
    for (int kt = 0; kt < nt; ++kt) {
        if (kt + 1 < nt) {
            stageB((kt + 1) * TK, buf ^ 1);
            stageA((kt + 1) * TK, buf ^ 1);
        }

        // ---- B fragments (swizzled read) ----
        short8_t bf0[4], bf1[4], bf2[4];
#pragma unroll
        for (int j = 0; j < 4; ++j) {
            int nrow = wn + j * 16 + (lane & 15);
            int ks = (((lane >> 4) ^ ((nrow >> 1) & 3)) * 8);
            bf0[j] = *reinterpret_cast<const short8_t*>(&Bs[buf][0][nrow * TK + ks]);
            bf1[j] = *reinterpret_cast<const short8_t*>(&Bs[buf][1][nrow * TK + ks]);
            bf2[j] = *reinterpret_cast<const short8_t*>(&Bs[buf][2][nrow * TK + ks]);
        }

        // ---- A fragments from LDS (swizzled, fp32) + in-register split ----
#pragma unroll
        for (int i = 0; i < 4; ++i) {
            int mrow = wm + i * 16 + (lane & 15);
            int rx = mrow & 7;
            float4 fa = *(const float4*)&Asf[buf][mrow * TK + ((s0)     ^ rx) * 4];
            float4 fb = *(const float4*)&Asf[buf][mrow * TK + ((s0 + 1) ^ rx) * 4];
            float xs[8] = {fa.x, fa.y, fa.z, fa.w, fb.x, fb.y, fb.z, fb.w};
            short8_t a1, a2, a3;
#pragma unroll
            for (int e = 0; e < 8; ++e) {
                uint32_t u1 = __float_as_uint(xs[e]) & 0xffff0000u;
                float r1 = xs[e] - __uint_as_float(u1);
                uint32_t u2 = __float_as_uint(r1) & 0xffff0000u;
                float r2 = r1 - __uint_as_float(u2);
                uint32_t u3 = __float_as_uint(r2) & 0xffff0000u;
                a1[e] = (short)(u1 >> 16);
                a2[e] = (short)(u2 >> 16);
                a3[e] = (short)(u3 >> 16);
            }
#pragma unroll
            for (int j = 0; j < 4; ++j) {
                f32x4 c = acc[i][j];
                c = __builtin_amdgcn_mfma_f32_16x16x32_bf16(a1, bf0[j], c, 0, 0, 0);
                c = __builtin_amdgcn_mfma_f32_16x16x32_bf16(a1, bf1[j], c, 0, 0, 0);
                c = __builtin_amdgcn_mfma_f32_16x16x32_bf16(a2, bf0[j], c, 0, 0, 0);
                c = __builtin_amdgcn_mfma_f32_16x16x32_bf16(a2, bf1[j], c, 0, 0, 0);
                c = __builtin_amdgcn_mfma_f32_16x16x32_bf16(a1, bf2[j], c, 0, 0, 0);
                c = __builtin_amdgcn_mfma_f32_16x16x32_bf16(a3, bf0[j], c, 0, 0, 0);
                acc[i][j] = c;
            }
        }
        __syncthreads();   // joins: next-buf DMA/ds_writes done, cur reads done
        buf ^= 1;
    }

    float* Cd = C + (size_t)dir * M * 512;
#pragma unroll
    for (int j = 0; j < 4; ++j) {
        int col = n0 + wn + j * 16 + (lane & 15);
        float bv = bias[dir * 512 + col];
#pragma unroll
        for (int i = 0; i < 4; ++i) {
            int rbase = m0 + wm + i * 16 + ((lane >> 4) << 2);
#pragma unroll
            for (int r = 0; r < 4; ++r)
                Cd[(size_t)(rbase + r) * 512 + col] = acc[i][j][r] + bv;
        }
    }
}

// ---------------------------------------------------------------------------
// LSTM scan (DPP + packed fp32): block per (batch, dir[, layer via z]).
// ---------------------------------------------------------------------------
__global__ __launch_bounds__(512) __attribute__((amdgpu_waves_per_eu(2, 2)))
void lstm_dpp(const float* __restrict__ xgP, const float* __restrict__ WhhP,
              float* __restrict__ hoP, int TP,
              const float* __restrict__ xgQ, const float* __restrict__ WhhQ,
              float* __restrict__ hoQ, int TQ)
{
    const int b    = blockIdx.x;
    const int dir  = blockIdx.y;
    const int tid  = threadIdx.x;
    const int l    = tid & 63;
    const int w    = tid >> 6;
    const int u    = w * 16 + (l >> 2);   // hidden unit 0..127
    const int s    = l & 3;               // k-slice 0..3

    const float* xg; const float* Whh; float* ho; int T;
    if (blockIdx.z == 0) { xg = xgP; Whh = WhhP; ho = hoP; T = TP; }
    else                 { xg = xgQ; Whh = WhhQ; ho = hoQ; T = TQ; }

    const float* xgd = xg + (size_t)dir * BB * T * GATES;

    f32x2 wv2[4][16];
#pragma unroll
    for (int g = 0; g < 4; ++g) {
        const float* wr = Whh + ((size_t)dir * GATES + g * 128 + u) * HD + s * 32;
#pragma unroll
        for (int j = 0; j < 8; ++j) {
            float4 t4 = *(const float4*)(wr + j * 4);
            wv2[g][2 * j]     = f32x2{t4.x, t4.y};
            wv2[g][2 * j + 1] = f32x2{t4.z, t4.w};
        }
    }

    __shared__ __align__(16) float hs[2][140];

    if (tid < 140) { hs[0][tid] = 0.f; }
    float c = 0.f;

    int t = dir ? (T - 1) : 0;
    const int dt = dir ? -1 : 1;

    float xc[4], xn[4];
#pragma unroll
    for (int g = 0; g < 4; ++g)
        xc[g] = xgd[((size_t)b * T + t) * GATES + g * 128 + u];

    const int rdbase = HPOS(s * 32);
    __syncthreads();

    for (int step = 0; step < T; ++step) {
        const int tn = t + dt;
        const int rbuf = step & 1, wbuf = rbuf ^ 1;

        if (step + 1 < T) {
#pragma unroll
            for (int g = 0; g < 4; ++g)
                xn[g] = xgd[((size_t)b * T + tn) * GATES + g * 128 + u];
        }

        f32x2 p0 = {0.f, 0.f}, p1 = {0.f, 0.f}, p2 = {0.f, 0.f}, p3 = {0.f, 0.f};
#pragma unroll
        for (int j = 0; j < 8; ++j) {
            float4 h4 = *(const float4*)&hs[rbuf][rdbase + j * 4];
            f32x2 hl = {h4.x, h4.y}, hh = {h4.z, h4.w};
            p0 = __builtin_elementwise_fma(wv2[0][2 * j], hl, p0);
            p1 = __builtin_elementwise_fma(wv2[1][2 * j], hl, p1);
            p2 = __builtin_elementwise_fma(wv2[2][2 * j], hl, p2);
            p3 = __builtin_elementwise_fma(wv2[3][2 * j], hl, p3);
            p0 = __builtin_elementwise_fma(wv2[0][2 * j + 1], hh, p0);
            p1 = __builtin_elementwise_fma(wv2[1][2 * j + 1], hh, p1);
            p2 = __builtin_elementwise_fma(wv2[2][2 * j + 1], hh, p2);
            p3 = __builtin_elementwise_fma(wv2[3][2 * j + 1], hh, p3);
        }
        float pre0 = quad_sum(p0.x + p0.y) + xc[0];
        float pre1 = quad_sum(p1.x + p1.y) + xc[1];
        float pre2 = quad_sum(p2.x + p2.y) + xc[2];
        float pre3 = quad_sum(p3.x + p3.y) + xc[3];

        float ig = fast_sigmoid(pre0);
        float fg = fast_sigmoid(pre1);
        float gg = fast_tanh(pre2);
        float og = fast_sigmoid(pre3);
        c = fg * c + ig * gg;
        float h = og * fast_tanh(c);

        if (s == 0) {
            hs[wbuf][HPOS(u)] = h;
            ho[((size_t)b * T + t) * 256 + dir * HD + u] = h;
        }
        __syncthreads();

#pragma unroll
        for (int g = 0; g < 4; ++g) xc[g] = xn[g];
        t = tn;
    }
}

// ---------------------------------------------------------------------------
__global__ void rowdot(const float* __restrict__ X, const float* __restrict__ w,
                       float* __restrict__ out, int N, int D)
{
    int gw   = (int)((blockIdx.x * blockDim.x + threadIdx.x) >> 6);
    int lane = threadIdx.x & 63;
    if (gw >= N) return;
    const float* xp = X + (size_t)gw * D;
    float s = 0.f;
    for (int d = lane; d < D; d += 64) s += xp[d] * w[d];
#pragma unroll
    for (int off = 32; off; off >>= 1) s += __shfl_down(s, off);
    if (lane == 0) out[gw] = s;
}

// ---------------------------------------------------------------------------
__global__ __launch_bounds__(256)
void att_s(const float* __restrict__ co, const float* __restrict__ qo,
           const float* __restrict__ cw, const float* __restrict__ qw,
           const float* __restrict__ wcq, const float* __restrict__ attb,
           float* __restrict__ s)
{
    int b  = blockIdx.x;
    int c0 = blockIdx.y * 64;
    int tid = threadIdx.x;
    int tq = tid & 15, trc = tid >> 4;
    int cbase = c0 + trc * 4, qbase = tq * 4;

    float acc[4][4];
#pragma unroll
    for (int i = 0; i < 4; ++i)
#pragma unroll
        for (int j = 0; j < 4; ++j) acc[i][j] = 0.f;

    for (int d = 0; d < 256; d += 4) {
        float4 wv = *(const float4*)&wcq[d];
        float4 cv[4], qv[4];
#pragma unroll
        for (int i = 0; i < 4; ++i) {
            float4 v = *(const float4*)&co[((size_t)b * CL + cbase + i) * 256 + d];
            cv[i].x = v.x * wv.x; cv[i].y = v.y * wv.y;
            cv[i].z = v.z * wv.z; cv[i].w = v.w * wv.w;
        }
#pragma unroll
        for (int j = 0; j < 4; ++j)
            qv[j] = *(const float4*)&qo[((size_t)b * QL + qbase + j) * 256 + d];
#pragma unroll
        for (int i = 0; i < 4; ++i)
#pragma unroll
            for (int j = 0; j < 4; ++j)
                acc[i][j] += cv[i].x * qv[j].x + cv[i].y * qv[j].y +
                             cv[i].z * qv[j].z + cv[i].w * qv[j].w;
    }
    float ab = attb[0];
#pragma unroll
    for (int i = 0; i < 4; ++i) {
        float cwv = cw[b * CL + cbase + i];
#pragma unroll
        for (int j = 0; j < 4; ++j) {
            s[((size_t)b * CL + cbase + i) * QL + qbase + j] =
                acc[i][j] + cwv + qw[b * QL + qbase + j] + ab;
        }
    }
}

// ---------------------------------------------------------------------------
__global__ void softmax_q(float* __restrict__ s, float* __restrict__ smax)
{
    int gw   = (int)((blockIdx.x * blockDim.x + threadIdx.x) >> 6);
    int lane = threadIdx.x & 63;
    float v = s[(size_t)gw * QL + lane];
    float mx = v;
#pragma unroll
    for (int off = 32; off; off >>= 1) mx = fmaxf(mx, __shfl_xor(mx, off));
    float e = expf(v - mx);
    float sm = e;
#pragma unroll
    for (int off = 32; off; off >>= 1) sm += __shfl_xor(sm, off);
    s[(size_t)gw * QL + lane] = e / sm;
    if (lane == 0) smax[gw] = mx;
}

// ---------------------------------------------------------------------------
__global__ __launch_bounds__(512)
void bw_k(const float* __restrict__ smax, float* __restrict__ bw)
{
    int b = blockIdx.x, c = threadIdx.x;
    int lane = c & 63, wid = c >> 6;
    __shared__ float red[8];
    float v = smax[b * CL + c];
    float mx = v;
#pragma unroll
    for (int off = 32; off; off >>= 1) mx = fmaxf(mx, __shfl_xor(mx, off));
    if (lane == 0) red[wid] = mx;
    __syncthreads();
    float bm = red[0];
#pragma unroll
    for (int w = 1; w < 8; ++w) bm = fmaxf(bm, red[w]);
    float e = expf(v - bm);
    float sm = e;
#pragma unroll
    for (int off = 32; off; off >>= 1) sm += __shfl_xor(sm, off);
    __syncthreads();
    if (lane == 0) red[wid] = sm;
    __syncthreads();
    float ts = 0.f;
#pragma unroll
    for (int w = 0; w < 8; ++w) ts += red[w];
    bw[b * CL + c] = e / ts;
}

// ---------------------------------------------------------------------------
__global__ __launch_bounds__(256)
void q2c_k(const float* __restrict__ bw, const float* __restrict__ co,
           float* __restrict__ q2c)
{
    int b = blockIdx.x, d = threadIdx.x;
    float acc = 0.f;
    for (int c = 0; c < CL; ++c)
        acc += bw[b * CL + c] * co[((size_t)b * CL + c) * 256 + d];
    q2c[b * 256 + d] = acc;
}

// ---------------------------------------------------------------------------
__global__ __launch_bounds__(256)
void c2q_g(const float* __restrict__ a, const float* __restrict__ qo,
           const float* __restrict__ co, const float* __restrict__ q2c,
           float* __restrict__ g)
{
    int b  = blockIdx.x;
    int c  = blockIdx.y * 64 + (threadIdx.x >> 2);
    int gq = threadIdx.x & 3;

    float4 acc[16];
#pragma unroll
    for (int jj = 0; jj < 16; ++jj) acc[jj] = make_float4(0.f, 0.f, 0.f, 0.f);

    const float* ar = a + ((size_t)b * CL + c) * QL;
    for (int q = 0; q < QL; ++q) {
        float av = ar[q];
        const float* qr = qo + ((size_t)b * QL + q) * 256;
#pragma unroll
        for (int jj = 0; jj < 16; ++jj) {
            float4 qv = *(const float4*)&qr[4 * gq + 16 * jj];
            acc[jj].x += av * qv.x; acc[jj].y += av * qv.y;
            acc[jj].z += av * qv.z; acc[jj].w += av * qv.w;
        }
    }
    size_t gbase = ((size_t)b * CL + c) * 1024;
    const float* corow = co + ((size_t)b * CL + c) * 256;
    const float* q2cr  = q2c + b * 256;
#pragma unroll
    for (int jj = 0; jj < 16; ++jj) {
        int d = 4 * gq + 16 * jj;
        float4 cv = *(const float4*)&corow[d];
        float4 qc = *(const float4*)&q2cr[d];
        float4 cq = acc[jj];
        *(float4*)&g[gbase + d] = cv;
        *(float4*)&g[gbase + 256 + d] = cq;
        float4 t;
        t.x = cv.x * cq.x; t.y = cv.y * cq.y; t.z = cv.z * cq.z; t.w = cv.w * cq.w;
        *(float4*)&g[gbase + 512 + d] = t;
        t.x = cv.x * qc.x; t.y = cv.y * qc.y; t.z = cv.z * qc.z; t.w = cv.w * qc.w;
        *(float4*)&g[gbase + 768 + d] = t;
    }
}

// ---------------------------------------------------------------------------
__global__ void logits_k(const float* __restrict__ g, const float* __restrict__ m,
                         const float* __restrict__ m2o,
                         const float* __restrict__ p1wg, const float* __restrict__ p1wm,
                         const float* __restrict__ p1b,
                         const float* __restrict__ p2wg, const float* __restrict__ p2wm,
                         const float* __restrict__ p2b,
                         float* __restrict__ lp1, float* __restrict__ lp2)
{
    int row  = (int)((blockIdx.x * blockDim.x + threadIdx.x) >> 6);
    int lane = threadIdx.x & 63;
    const float* gr = g + (size_t)row * 1024;
    float s1 = 0.f, s2 = 0.f;
    for (int d = lane; d < 1024; d += 64) {
        float gv = gr[d];
        s1 += gv * p1wg[d];
        s2 += gv * p2wg[d];
    }
    const float* mr  = m   + (size_t)row * 256;
    const float* m2r = m2o + (size_t)row * 256;
    for (int d = lane; d < 256; d += 64) {
        s1 += mr[d] * p1wm[d];
        s2 += m2r[d] * p2wm[d];
    }
#pragma unroll
    for (int off = 32; off; off >>= 1) {
        s1 += __shfl_down(s1, off);
        s2 += __shfl_down(s2, off);
    }
    if (lane == 0) {
        lp1[row] = s1 + p1b[0];
        lp2[row] = s2 + p2b[0];
    }
}

// ---------------------------------------------------------------------------
__global__ __launch_bounds__(512)
void masked_softmax(const float* __restrict__ lp1, const float* __restrict__ lp2,
                    const int* __restrict__ p, float* __restrict__ out)
{
    int b = blockIdx.x, c = threadIdx.x;
    int lane = c & 63, wid = c >> 6;
    const float* lp = blockIdx.y ? lp2 : lp1;
    float* o = out + (size_t)blockIdx.y * BB * CL;

    __shared__ float red[8];
    float v = (p[b * CL + c] != 0) ? lp[b * CL + c] : -INFINITY;
    float mx = v;
#pragma unroll
    for (int off = 32; off; off >>= 1) mx = fmaxf(mx, __shfl_xor(mx, off));
    if (lane == 0) red[wid] = mx;
    __syncthreads();
    float bm = red[0];
#pragma unroll
    for (int w = 1; w < 8; ++w) bm = fmaxf(bm, red[w]);
    float e = expf(v - bm);
    float sm = e;
#pragma unroll
    for (int off = 32; off; off >>= 1) sm += __shfl_xor(sm, off);
    __syncthreads();
    if (lane == 0) red[wid] = sm;
    __syncthreads();
    float ts = 0.f;
#pragma unroll
    for (int w = 0; w < 8; ++w) ts += red[w];
    o[b * CL + c] = e / ts;
}

// ---------------------------------------------------------------------------
extern "C" void kernel_launch(void* const* d_in, const int* in_sizes, int n_in,
                              void* d_out, int out_size, void* d_ws, size_t ws_size,
                              hipStream_t stream)
{
    const int*   p        = (const int*)d_in[0];
    const int*   q        = (const int*)d_in[1];
    const float* emb      = (const float*)d_in[2];
    const float* qenc_Wih = (const float*)d_in[3];
    const float* qenc_Whh = (const float*)d_in[4];
    const float* qenc_b   = (const float*)d_in[5];
    const float* penc_Wih = (const float*)d_in[6];
    const float* penc_Whh = (const float*)d_in[7];
    const float* penc_b   = (const float*)d_in[8];
    const float* m1_Wih   = (const float*)d_in[9];
    const float* m1_Whh   = (const float*)d_in[10];
    const float* m1_b     = (const float*)d_in[11];
    const float* m2_Wih   = (const float*)d_in[12];
    const float* m2_Whh   = (const float*)d_in[13];
    const float* m2_b     = (const float*)d_in[14];
    const float* out_Wih  = (const float*)d_in[15];
    const float* out_Whh  = (const float*)d_in[16];
    const float* out_b    = (const float*)d_in[17];
    const float* att_wc   = (const float*)d_in[18];
    const float* att_wq   = (const float*)d_in[19];
    const float* att_wcq  = (const float*)d_in[20];
    const float* att_b    = (const float*)d_in[21];
    const float* p1_wg    = (const float*)d_in[22];
    const float* p1_wm    = (const float*)d_in[23];
    const float* p1_b     = (const float*)d_in[24];
    const float* p2_wg    = (const float*)d_in[25];
    const float* p2_wm    = (const float*)d_in[26];
    const float* p2_b     = (const float*)d_in[27];

    float* ws = (float*)d_ws;
    size_t off = 0;
    auto alloc = [&](size_t n) { float* r = ws + off; off += n; return r; };
    auto allocU = [&](size_t nsh) { ushort* r = (ushort*)(ws + off); off += (nsh + 1) / 2; return r; };

    const size_t NC = (size_t)BB * CL;     // 32768
    const size_t NQ = (size_t)BB * QL;     // 4096

    float* xgA  = alloc(2 * NC * GATES);   // gate preacts, reused per layer
    float* gbuf = alloc(NC * 1024);        // g  (xgQ aliases its head: dead before g written)
    float* xgQ  = gbuf;
    float* co   = alloc(NC * 256);
    float* qo   = alloc(NQ * 256);
    float* sbuf = alloc(NC * QL);          // s, then a (in place)
    float* cw   = alloc(NC);
    float* qw   = alloc(NQ);
    float* smax = alloc(NC);
    float* bw   = alloc(NC);
    float* q2c  = alloc((size_t)BB * 256);
    float* mmid = alloc(NC * 256);
    float* mbuf = alloc(NC * 256);
    float* m2o  = alloc(NC * 256);
    float* lp1  = alloc(NC);
    float* lp2  = alloc(NC);
    // bf16 weight planes: [3][1024][Ksp]
    ushort* WqP  = allocU((size_t)3 * 1024 * 320);
    ushort* WpP  = allocU((size_t)3 * 1024 * 320);
    ushort* Wm1P = allocU((size_t)3 * 1024 * 1024);
    ushort* Wm2P = allocU((size_t)3 * 1024 * 256);
    ushort* WoP  = allocU((size_t)3 * 1024 * 256);
    (void)ws_size; (void)in_sizes; (void)n_in; (void)out_size;

    // ---- weight splits ----
    splitW_k<<<dim3(1024 * 80 / 256), 256, 0, stream>>>(qenc_Wih, WqP, 300, 320);
    splitW_k<<<dim3(1024 * 80 / 256), 256, 0, stream>>>(penc_Wih, WpP, 300, 320);
    splitW_k<<<dim3(1024 * 256 / 256), 256, 0, stream>>>(m1_Wih, Wm1P, 1024, 1024);
    splitW_k<<<dim3(1024 * 64 / 256), 256, 0, stream>>>(m2_Wih, Wm2P, 256, 256);
    splitW_k<<<dim3(1024 * 64 / 256), 256, 0, stream>>>(out_Wih, WoP, 256, 256);

    // ---- encoders (P and Q scans in one launch via z) ----
    gemm_bf16x3<<<dim3(8, (int)(NQ / TM)), 256, 0, stream>>>(emb, q, WqP, qenc_b, xgQ, (int)NQ, 300, 320);
    gemm_bf16x3<<<dim3(8, (int)(NC / TM)), 256, 0, stream>>>(emb, p, WpP, penc_b, xgA, (int)NC, 300, 320);
    lstm_dpp<<<dim3(BB, 2, 2), 512, 0, stream>>>(xgA, penc_Whh, co, CL,
                                                 xgQ, qenc_Whh, qo, QL);

    // ---- attention ----
    rowdot<<<dim3((int)(NC * 64 / 256)), 256, 0, stream>>>(co, att_wc, cw, (int)NC, 256);
    rowdot<<<dim3((int)(NQ * 64 / 256)), 256, 0, stream>>>(qo, att_wq, qw, (int)NQ, 256);
    att_s<<<dim3(BB, CL / 64), 256, 0, stream>>>(co, qo, cw, qw, att_wcq, att_b, sbuf);
    softmax_q<<<dim3((int)(NC * 64 / 256)), 256, 0, stream>>>(sbuf, smax);
    bw_k<<<dim3(BB), 512, 0, stream>>>(smax, bw);
    q2c_k<<<dim3(BB), 256, 0, stream>>>(bw, co, q2c);
    c2q_g<<<dim3(BB, CL / 64), 256, 0, stream>>>(sbuf, qo, co, q2c, gbuf);

    // ---- modeling layers ----
    gemm_bf16x3<<<dim3(8, (int)(NC / TM)), 256, 0, stream>>>(gbuf, nullptr, Wm1P, m1_b, xgA, (int)NC, 1024, 1024);
    lstm_dpp<<<dim3(BB, 2, 1), 512, 0, stream>>>(xgA, m1_Whh, mmid, CL,
                                                 xgA, m1_Whh, mmid, CL);
    gemm_bf16x3<<<dim3(8, (int)(NC / TM)), 256, 0, stream>>>(mmid, nullptr, Wm2P, m2_b, xgA, (int)NC, 256, 256);
    lstm_dpp<<<dim3(BB, 2, 1), 512, 0, stream>>>(xgA, m2_Whh, mbuf, CL,
                                                 xgA, m2_Whh, mbuf, CL);
    gemm_bf16x3<<<dim3(8, (int)(NC / TM)), 256, 0, stream>>>(mbuf, nullptr, WoP, out_b, xgA, (int)NC, 256, 256);
    lstm_dpp<<<dim3(BB, 2, 1), 512, 0, stream>>>(xgA, out_Whh, m2o, CL,
                                                 xgA, out_Whh, m2o, CL);

    // ---- output ----
    logits_k<<<dim3((int)(NC * 64 / 256)), 256, 0, stream>>>(gbuf, mbuf, m2o,
        p1_wg, p1_wm, p1_b, p2_wg, p2_wm, p2_b, lp1, lp2);
    masked_softmax<<<dim3(BB, 2), 512, 0, stream>>>(lp1, lp2, p, (float*)d_out);
}

// Round 12
// 2564.665 us; speedup vs baseline: 1.2299x; 1.0683x over previous
//
#include <hip/hip_runtime.h>
#include <math.h>
#include <stdint.h>

#define HD    128      // hidden
#define GATES 512      // 4H
#define BB    64       // batch
#define CL    512      // context len
#define QL    64       // query len

#define TM 128
#define TN 128
#define TK 32

typedef __attribute__((ext_vector_type(8))) short short8_t;
typedef __attribute__((ext_vector_type(4))) short short4_t;
typedef __attribute__((ext_vector_type(4))) float f32x4;
typedef __attribute__((ext_vector_type(2))) float f32x2;

__device__ __forceinline__ float fast_sigmoid(float x) {
    float e = __builtin_amdgcn_exp2f(-1.44269504f * x);
    return __builtin_amdgcn_rcpf(1.f + e);
}
__device__ __forceinline__ float fast_tanh(float x) {
    float e = __builtin_amdgcn_exp2f(2.88539008f * x);
    float r = __builtin_amdgcn_rcpf(e + 1.f);
    return 1.f - 2.f * r;
}
__device__ __forceinline__ float quad_sum(float v) {
    int y = __builtin_amdgcn_mov_dpp(__float_as_int(v), 0xB1, 0xF, 0xF, 0); // l^1
    float s = v + __int_as_float(y);
    int z = __builtin_amdgcn_mov_dpp(__float_as_int(s), 0x4E, 0xF, 0xF, 0); // l^2
    return s + __int_as_float(z);
}
// barrier that drains ONLY LDS ops (hs writes); global loads/stores stay in
// flight across it (xg prefetch + ho store need no barrier ordering).
__device__ __forceinline__ void lds_barrier() {
    asm volatile("s_waitcnt lgkmcnt(0)\n\ts_barrier" ::: "memory");
}
#define HPOS(e) ((e) + (((e) >> 5) << 2))

// ---------------------------------------------------------------------------
// Split W (rows=1024, K) fp32 into 3 bf16 planes, each (1024, Ksp), padded.
// ---------------------------------------------------------------------------
__global__ __launch_bounds__(256)
void splitW_k(const float* __restrict__ W, ushort* __restrict__ P, int K, int Ksp)
{
    int idx = blockIdx.x * 256 + threadIdx.x;
    int per_row = Ksp >> 2;
    int total = 1024 * per_row;
    if (idx >= total) return;
    int row = idx / per_row;
    int c4  = (idx - row * per_row) * 4;

    short4_t o1, o2, o3;
#pragma unroll
    for (int e = 0; e < 4; ++e) {
        int k = c4 + e;
        float x = (k < K) ? W[(size_t)row * K + k] : 0.f;
        uint32_t u1 = __float_as_uint(x) & 0xffff0000u;
        float r1 = x - __uint_as_float(u1);
        uint32_t u2 = __float_as_uint(r1) & 0xffff0000u;
        float r2 = r1 - __uint_as_float(u2);
        uint32_t u3 = __float_as_uint(r2) & 0xffff0000u;
        o1[e] = (short)(u1 >> 16);
        o2[e] = (short)(u2 >> 16);
        o3[e] = (short)(u3 >> 16);
    }
    size_t base = (size_t)row * Ksp + c4;
    size_t ps = (size_t)1024 * Ksp;
    *reinterpret_cast<short4_t*>(&P[base]) = o1;
    *reinterpret_cast<short4_t*>(&P[ps + base]) = o2;
    *reinterpret_cast<short4_t*>(&P[2 * ps + base]) = o3;
}

// ---------------------------------------------------------------------------
// MFMA GEMM v10 (unchanged from round 10): A in LDS as raw fp32 w/ XOR
// swizzle, B via global_load_lds (swizzled src+read), both double-buffered,
// one barrier per k-tile.
// ---------------------------------------------------------------------------
__global__ __launch_bounds__(256, 2)
void gemm_bf16x3(const float* __restrict__ A, const int* __restrict__ gidx,
                 const ushort* __restrict__ Wpl, const float* __restrict__ bias,
                 float* __restrict__ C, int M, int K, int Ksp)
{
    const int n0   = (blockIdx.x & 3) * TN;
    const int dir  = blockIdx.x >> 2;
    const int m0   = blockIdx.y * TM;
    const int tid  = threadIdx.x;
    const int lane = tid & 63;
    const int wid  = tid >> 6;
    const int wm   = (wid >> 1) * 64;
    const int wn   = (wid & 1) * 64;

    __shared__ __align__(16) float  Asf[2][TM * TK];     // 32768 B
    __shared__ __align__(16) ushort Bs[2][3][TN * TK];   // 49152 B

    const int srow = tid >> 3;          // 0..31
    const int scol = tid & 7;           // 16B slot 0..7
    size_t sArow[4];
#pragma unroll
    for (int r = 0; r < 4; ++r) {
        int m = m0 + srow + r * 32;
        sArow[r] = gidx ? (size_t)gidx[m] : (size_t)m;
    }

    const int s0 = (lane >> 4) * 2;

    f32x4 acc[4][4];
#pragma unroll
    for (int i = 0; i < 4; ++i)
#pragma unroll
        for (int j = 0; j < 4; ++j) acc[i][j] = (f32x4)0.f;

    const size_t wps    = (size_t)1024 * Ksp;
    const size_t wdbase = (size_t)dir * 512 * Ksp;
    const int nt = Ksp / TK;

    auto stageB = [&](int k0, int bufb) {
#pragma unroll
        for (int t = 0; t < 6; ++t) {
            int chunk = wid * 6 + t;
            int pl = chunk >> 3;
            int ch = chunk & 7;
            int rrow = ch * 16 + (lane >> 2);
            int ksw  = ((lane & 3) ^ ((rrow >> 1) & 3)) * 8;
            const ushort* src = Wpl + (size_t)pl * wps + wdbase +
                                (size_t)(n0 + rrow) * Ksp + k0 + ksw;
            ushort* dst = &Bs[bufb][pl][ch * 512];
            __builtin_amdgcn_global_load_lds(
                reinterpret_cast<const __attribute__((address_space(1))) void*>(
                    reinterpret_cast<uintptr_t>(src)),
                reinterpret_cast<__attribute__((address_space(3))) void*>(
                    reinterpret_cast<uintptr_t>(dst)),
                16, 0, 0);
        }
    };
    auto stageA = [&](int k0, int bufb) {
#pragma unroll
        for (int r = 0; r < 4; ++r) {
            int row = srow + r * 32;
            int kf  = k0 + scol * 4;
            float4 v;
            if (kf + 4 <= K) {
                v = *(const float4*)(A + sArow[r] * K + kf);
            } else {
                const float* ap = A + sArow[r] * K;
                v.x = (kf     < K) ? ap[kf]     : 0.f;
                v.y = (kf + 1 < K) ? ap[kf + 1] : 0.f;
                v.z = (kf + 2 < K) ? ap[kf + 2] : 0.f;
                v.w = (kf + 3 < K) ? ap[kf + 3] : 0.f;
            }
            int sw = scol ^ (row & 7);
            *(float4*)&Asf[bufb][row * TK + sw * 4] = v;
        }
    };

    stageB(0, 0);
    stageA(0, 0);
    __syncthreads();

    int buf = 0;
    for (int kt = 0; kt < nt; ++kt) {
        if (kt + 1 < nt) {
            stageB((kt + 1) * TK, buf ^ 1);
            stageA((kt + 1) * TK, buf ^ 1);
        }

        short8_t bf0[4], bf1[4], bf2[4];
#pragma unroll
        for (int j = 0; j < 4; ++j) {
            int nrow = wn + j * 16 + (lane & 15);
            int ks = (((lane >> 4) ^ ((nrow >> 1) & 3)) * 8);
            bf0[j] = *reinterpret_cast<const short8_t*>(&Bs[buf][0][nrow * TK + ks]);
            bf1[j] = *reinterpret_cast<const short8_t*>(&Bs[buf][1][nrow * TK + ks]);
            bf2[j] = *reinterpret_cast<const short8_t*>(&Bs[buf][2][nrow * TK + ks]);
        }

#pragma unroll
        for (int i = 0; i < 4; ++i) {
            int mrow = wm + i * 16 + (lane & 15);
            int rx = mrow & 7;
            float4 fa = *(const float4*)&Asf[buf][mrow * TK + ((s0)     ^ rx) * 4];
            float4 fb = *(const float4*)&Asf[buf][mrow * TK + ((s0 + 1) ^ rx) * 4];
            float xs[8] = {fa.x, fa.y, fa.z, fa.w, fb.x, fb.y, fb.z, fb.w};
            short8_t a1, a2, a3;
#pragma unroll
            for (int e = 0; e < 8; ++e) {
                uint32_t u1 = __float_as_uint(xs[e]) & 0xffff0000u;
                float r1 = xs[e] - __uint_as_float(u1);
                uint32_t u2 = __float_as_uint(r1) & 0xffff0000u;
                float r2 = r1 - __uint_as_float(u2);
                uint32_t u3 = __float_as_uint(r2) & 0xffff0000u;
                a1[e] = (short)(u1 >> 16);
                a2[e] = (short)(u2 >> 16);
                a3[e] = (short)(u3 >> 16);
            }
#pragma unroll
            for (int j = 0; j < 4; ++j) {
                f32x4 c = acc[i][j];
                c = __builtin_amdgcn_mfma_f32_16x16x32_bf16(a1, bf0[j], c, 0, 0, 0);
                c = __builtin_amdgcn_mfma_f32_16x16x32_bf16(a1, bf1[j], c, 0, 0, 0);
                c = __builtin_amdgcn_mfma_f32_16x16x32_bf16(a2, bf0[j], c, 0, 0, 0);
                c = __builtin_amdgcn_mfma_f32_16x16x32_bf16(a2, bf1[j], c, 0, 0, 0);
                c = __builtin_amdgcn_mfma_f32_16x16x32_bf16(a1, bf2[j], c, 0, 0, 0);
                c = __builtin_amdgcn_mfma_f32_16x16x32_bf16(a3, bf0[j], c, 0, 0, 0);
                acc[i][j] = c;
            }
        }
        __syncthreads();
        buf ^= 1;
    }

    float* Cd = C + (size_t)dir * M * 512;
#pragma unroll
    for (int j = 0; j < 4; ++j) {
        int col = n0 + wn + j * 16 + (lane & 15);
        float bv = bias[dir * 512 + col];
#pragma unroll
        for (int i = 0; i < 4; ++i) {
            int rbase = m0 + wm + i * 16 + ((lane >> 4) << 2);
#pragma unroll
            for (int r = 0; r < 4; ++r)
                Cd[(size_t)(rbase + r) * 512 + col] = acc[i][j][r] + bv;
        }
    }
}

// ---------------------------------------------------------------------------
// LSTM scan v11: DPP + packed fp32 + LDS-only barrier (vmcnt never drained
// in the loop: xg prefetch loads + ho stores stay in flight across steps,
// AITER-style) + 2-step-deep xg ring (xc/xn1/xn2, statically indexed).
// ---------------------------------------------------------------------------
__global__ __launch_bounds__(512) __attribute__((amdgpu_waves_per_eu(2, 2)))
void lstm_dpp(const float* __restrict__ xgP, const float* __restrict__ WhhP,
              float* __restrict__ hoP, int TP,
              const float* __restrict__ xgQ, const float* __restrict__ WhhQ,
              float* __restrict__ hoQ, int TQ)
{
    const int b    = blockIdx.x;
    const int dir  = blockIdx.y;
    const int tid  = threadIdx.x;
    const int l    = tid & 63;
    const int w    = tid >> 6;
    const int u    = w * 16 + (l >> 2);   // hidden unit 0..127
    const int s    = l & 3;               // k-slice 0..3

    const float* xg; const float* Whh; float* ho; int T;
    if (blockIdx.z == 0) { xg = xgP; Whh = WhhP; ho = hoP; T = TP; }
    else                 { xg = xgQ; Whh = WhhQ; ho = hoQ; T = TQ; }

    const float* xgd = xg + (size_t)dir * BB * T * GATES;

    f32x2 wv2[4][16];
#pragma unroll
    for (int g = 0; g < 4; ++g) {
        const float* wr = Whh + ((size_t)dir * GATES + g * 128 + u) * HD + s * 32;
#pragma unroll
        for (int j = 0; j < 8; ++j) {
            float4 t4 = *(const float4*)(wr + j * 4);
            wv2[g][2 * j]     = f32x2{t4.x, t4.y};
            wv2[g][2 * j + 1] = f32x2{t4.z, t4.w};
        }
    }

    __shared__ __align__(16) float hs[2][140];

    if (tid < 140) { hs[0][tid] = 0.f; }
    float c = 0.f;

    int t = dir ? (T - 1) : 0;
    const int dt = dir ? -1 : 1;

    // xg ring: xc = step t, xn1 = t+dt, xn2 = t+2dt (clamped; statically named)
    float xc[4], xn1[4], xn2[4];
    {
        int t1 = t + dt; if (t1 < 0) t1 = 0; if (t1 >= T) t1 = T - 1;
#pragma unroll
        for (int g = 0; g < 4; ++g) {
            xc[g]  = xgd[((size_t)b * T + t)  * GATES + g * 128 + u];
            xn1[g] = xgd[((size_t)b * T + t1) * GATES + g * 128 + u];
        }
    }

    const int rdbase = HPOS(s * 32);
    __syncthreads();

    for (int step = 0; step < T; ++step) {
        const int rbuf = step & 1, wbuf = rbuf ^ 1;

        // prefetch t+2 (2 steps of slack; never forced to drain)
        {
            int t2 = t + 2 * dt;
            if (t2 < 0) t2 = 0; if (t2 >= T) t2 = T - 1;
#pragma unroll
            for (int g = 0; g < 4; ++g)
                xn2[g] = xgd[((size_t)b * T + t2) * GATES + g * 128 + u];
        }

        f32x2 p0 = {0.f, 0.f}, p1 = {0.f, 0.f}, p2 = {0.f, 0.f}, p3 = {0.f, 0.f};
#pragma unroll
        for (int j = 0; j < 8; ++j) {
            float4 h4 = *(const float4*)&hs[rbuf][rdbase + j * 4];
            f32x2 hl = {h4.x, h4.y}, hh = {h4.z, h4.w};
            p0 = __builtin_elementwise_fma(wv2[0][2 * j], hl, p0);
            p1 = __builtin_elementwise_fma(wv2[1][2 * j], hl, p1);
            p2 = __builtin_elementwise_fma(wv2[2][2 * j], hl, p2);
            p3 = __builtin_elementwise_fma(wv2[3][2 * j], hl, p3);
            p0 = __builtin_elementwise_fma(wv2[0][2 * j + 1], hh, p0);
            p1 = __builtin_elementwise_fma(wv2[1][2 * j + 1], hh, p1);
            p2 = __builtin_elementwise_fma(wv2[2][2 * j + 1], hh, p2);
            p3 = __builtin_elementwise_fma(wv2[3][2 * j + 1], hh, p3);
        }
        float pre0 = quad_sum(p0.x + p0.y) + xc[0];
        float pre1 = quad_sum(p1.x + p1.y) + xc[1];
        float pre2 = quad_sum(p2.x + p2.y) + xc[2];
        float pre3 = quad_sum(p3.x + p3.y) + xc[3];

        float ig = fast_sigmoid(pre0);
        float fg = fast_sigmoid(pre1);
        float gg = fast_tanh(pre2);
        float og = fast_sigmoid(pre3);
        c = fg * c + ig * gg;
        float h = og * fast_tanh(c);

        if (s == 0) {
            hs[wbuf][HPOS(u)] = h;
            ho[((size_t)b * T + t) * 256 + dir * HD + u] = h;
        }
        lds_barrier();   // lgkm-only: xg loads + ho stores stay in flight

#pragma unroll
        for (int g = 0; g < 4; ++g) { xc[g] = xn1[g]; xn1[g] = xn2[g]; }
        t += dt;
    }
}

// ---------------------------------------------------------------------------
__global__ void rowdot(const float* __restrict__ X, const float* __restrict__ w,
                       float* __restrict__ out, int N, int D)
{
    int gw   = (int)((blockIdx.x * blockDim.x + threadIdx.x) >> 6);
    int lane = threadIdx.x & 63;
    if (gw >= N) return;
    const float* xp = X + (size_t)gw * D;
    float s = 0.f;
    for (int d = lane; d < D; d += 64) s += xp[d] * w[d];
#pragma unroll
    for (int off = 32; off; off >>= 1) s += __shfl_down(s, off);
    if (lane == 0) out[gw] = s;
}

// ---------------------------------------------------------------------------
__global__ __launch_bounds__(256)
void att_s(const float* __restrict__ co, const float* __restrict__ qo,
           const float* __restrict__ cw, const float* __restrict__ qw,
           const float* __restrict__ wcq, const float* __restrict__ attb,
           float* __restrict__ s)
{
    int b  = blockIdx.x;
    int c0 = blockIdx.y * 64;
    int tid = threadIdx.x;
    int tq = tid & 15, trc = tid >> 4;
    int cbase = c0 + trc * 4, qbase = tq * 4;

    float acc[4][4];
#pragma unroll
    for (int i = 0; i < 4; ++i)
#pragma unroll
        for (int j = 0; j < 4; ++j) acc[i][j] = 0.f;

    for (int d = 0; d < 256; d += 4) {
        float4 wv = *(const float4*)&wcq[d];
        float4 cv[4], qv[4];
#pragma unroll
        for (int i = 0; i < 4; ++i) {
            float4 v = *(const float4*)&co[((size_t)b * CL + cbase + i) * 256 + d];
            cv[i].x = v.x * wv.x; cv[i].y = v.y * wv.y;
            cv[i].z = v.z * wv.z; cv[i].w = v.w * wv.w;
        }
#pragma unroll
        for (int j = 0; j < 4; ++j)
            qv[j] = *(const float4*)&qo[((size_t)b * QL + qbase + j) * 256 + d];
#pragma unroll
        for (int i = 0; i < 4; ++i)
#pragma unroll
            for (int j = 0; j < 4; ++j)
                acc[i][j] += cv[i].x * qv[j].x + cv[i].y * qv[j].y +
                             cv[i].z * qv[j].z + cv[i].w * qv[j].w;
    }
    float ab = attb[0];
#pragma unroll
    for (int i = 0; i < 4; ++i) {
        float cwv = cw[b * CL + cbase + i];
#pragma unroll
        for (int j = 0; j < 4; ++j) {
            s[((size_t)b * CL + cbase + i) * QL + qbase + j] =
                acc[i][j] + cwv + qw[b * QL + qbase + j] + ab;
        }
    }
}

// ---------------------------------------------------------------------------
__global__ void softmax_q(float* __restrict__ s, float* __restrict__ smax)
{
    int gw   = (int)((blockIdx.x * blockDim.x + threadIdx.x) >> 6);
    int lane = threadIdx.x & 63;
    float v = s[(size_t)gw * QL + lane];
    float mx = v;
#pragma unroll
    for (int off = 32; off; off >>= 1) mx = fmaxf(mx, __shfl_xor(mx, off));
    float e = expf(v - mx);
    float sm = e;
#pragma unroll
    for (int off = 32; off; off >>= 1) sm += __shfl_xor(sm, off);
    s[(size_t)gw * QL + lane] = e / sm;
    if (lane == 0) smax[gw] = mx;
}

// ---------------------------------------------------------------------------
__global__ __launch_bounds__(512)
void bw_k(const float* __restrict__ smax, float* __restrict__ bw)
{
    int b = blockIdx.x, c = threadIdx.x;
    int lane = c & 63, wid = c >> 6;
    __shared__ float red[8];
    float v = smax[b * CL + c];
    float mx = v;
#pragma unroll
    for (int off = 32; off; off >>= 1) mx = fmaxf(mx, __shfl_xor(mx, off));
    if (lane == 0) red[wid] = mx;
    __syncthreads();
    float bm = red[0];
#pragma unroll
    for (int w = 1; w < 8; ++w) bm = fmaxf(bm, red[w]);
    float e = expf(v - bm);
    float sm = e;
#pragma unroll
    for (int off = 32; off; off >>= 1) sm += __shfl_xor(sm, off);
    __syncthreads();
    if (lane == 0) red[wid] = sm;
    __syncthreads();
    float ts = 0.f;
#pragma unroll
    for (int w = 0; w < 8; ++w) ts += red[w];
    bw[b * CL + c] = e / ts;
}

// ---------------------------------------------------------------------------
__global__ __launch_bounds__(256)
void q2c_k(const float* __restrict__ bw, const float* __restrict__ co,
           float* __restrict__ q2c)
{
    int b = blockIdx.x, d = threadIdx.x;
    float acc = 0.f;
    for (int c = 0; c < CL; ++c)
        acc += bw[b * CL + c] * co[((size_t)b * CL + c) * 256 + d];
    q2c[b * 256 + d] = acc;
}

// ---------------------------------------------------------------------------
__global__ __launch_bounds__(256)
void c2q_g(const float* __restrict__ a, const float* __restrict__ qo,
           const float* __restrict__ co, const float* __restrict__ q2c,
           float* __restrict__ g)
{
    int b  = blockIdx.x;
    int c  = blockIdx.y * 64 + (threadIdx.x >> 2);
    int gq = threadIdx.x & 3;

    float4 acc[16];
#pragma unroll
    for (int jj = 0; jj < 16; ++jj) acc[jj] = make_float4(0.f, 0.f, 0.f, 0.f);

    const float* ar = a + ((size_t)b * CL + c) * QL;
    for (int q = 0; q < QL; ++q) {
        float av = ar[q];
        const float* qr = qo + ((size_t)b * QL + q) * 256;
#pragma unroll
        for (int jj = 0; jj < 16; ++jj) {
            float4 qv = *(const float4*)&qr[4 * gq + 16 * jj];
            acc[jj].x += av * qv.x; acc[jj].y += av * qv.y;
            acc[jj].z += av * qv.z; acc[jj].w += av * qv.w;
        }
    }
    size_t gbase = ((size_t)b * CL + c) * 1024;
    const float* corow = co + ((size_t)b * CL + c) * 256;
    const float* q2cr  = q2c + b * 256;
#pragma unroll
    for (int jj = 0; jj < 16; ++jj) {
        int d = 4 * gq + 16 * jj;
        float4 cv = *(const float4*)&corow[d];
        float4 qc = *(const float4*)&q2cr[d];
        float4 cq = acc[jj];
        *(float4*)&g[gbase + d] = cv;
        *(float4*)&g[gbase + 256 + d] = cq;
        float4 t;
        t.x = cv.x * cq.x; t.y = cv.y * cq.y; t.z = cv.z * cq.z; t.w = cv.w * cq.w;
        *(float4*)&g[gbase + 512 + d] = t;
        t.x = cv.x * qc.x; t.y = cv.y * qc.y; t.z = cv.z * qc.z; t.w = cv.w * qc.w;
        *(float4*)&g[gbase + 768 + d] = t;
    }
}

// ---------------------------------------------------------------------------
__global__ void logits_k(const float* __restrict__ g, const float* __restrict__ m,
                         const float* __restrict__ m2o,
                         const float* __restrict__ p1wg, const float* __restrict__ p1wm,
                         const float* __restrict__ p1b,
                         const float* __restrict__ p2wg, const float* __restrict__ p2wm,
                         const float* __restrict__ p2b,
                         float* __restrict__ lp1, float* __restrict__ lp2)
{
    int row  = (int)((blockIdx.x * blockDim.x + threadIdx.x) >> 6);
    int lane = threadIdx.x & 63;
    const float* gr = g + (size_t)row * 1024;
    float s1 = 0.f, s2 = 0.f;
    for (int d = lane; d < 1024; d += 64) {
        float gv = gr[d];
        s1 += gv * p1wg[d];
        s2 += gv * p2wg[d];
    }
    const float* mr  = m   + (size_t)row * 256;
    const float* m2r = m2o + (size_t)row * 256;
    for (int d = lane; d < 256; d += 64) {
        s1 += mr[d] * p1wm[d];
        s2 += m2r[d] * p2wm[d];
    }
#pragma unroll
    for (int off = 32; off; off >>= 1) {
        s1 += __shfl_down(s1, off);
        s2 += __shfl_down(s2, off);
    }
    if (lane == 0) {
        lp1[row] = s1 + p1b[0];
        lp2[row] = s2 + p2b[0];
    }
}

// ---------------------------------------------------------------------------
__global__ __launch_bounds__(512)
void masked_softmax(const float* __restrict__ lp1, const float* __restrict__ lp2,
                    const int* __restrict__ p, float* __restrict__ out)
{
    int b = blockIdx.x, c = threadIdx.x;
    int lane = c & 63, wid = c >> 6;
    const float* lp = blockIdx.y ? lp2 : lp1;
    float* o = out + (size_t)blockIdx.y * BB * CL;

    __shared__ float red[8];
    float v = (p[b * CL + c] != 0) ? lp[b * CL + c] : -INFINITY;
    float mx = v;
#pragma unroll
    for (int off = 32; off; off >>= 1) mx = fmaxf(mx, __shfl_xor(mx, off));
    if (lane == 0) red[wid] = mx;
    __syncthreads();
    float bm = red[0];
#pragma unroll
    for (int w = 1; w < 8; ++w) bm = fmaxf(bm, red[w]);
    float e = expf(v - bm);
    float sm = e;
#pragma unroll
    for (int off = 32; off; off >>= 1) sm += __shfl_xor(sm, off);
    __syncthreads();
    if (lane == 0) red[wid] = sm;
    __syncthreads();
    float ts = 0.f;
#pragma unroll
    for (int w = 0; w < 8; ++w) ts += red[w];
    o[b * CL + c] = e / ts;
}

// ---------------------------------------------------------------------------
extern "C" void kernel_launch(void* const* d_in, const int* in_sizes, int n_in,
                              void* d_out, int out_size, void* d_ws, size_t ws_size,
                              hipStream_t stream)
{
    const int*   p        = (const int*)d_in[0];
    const int*   q        = (const int*)d_in[1];
    const float* emb      = (const float*)d_in[2];
    const float* qenc_Wih = (const float*)d_in[3];
    const float* qenc_Whh = (const float*)d_in[4];
    const float* qenc_b   = (const float*)d_in[5];
    const float* penc_Wih = (const float*)d_in[6];
    const float* penc_Whh = (const float*)d_in[7];
    const float* penc_b   = (const float*)d_in[8];
    const float* m1_Wih   = (const float*)d_in[9];
    const float* m1_Whh   = (const float*)d_in[10];
    const float* m1_b     = (const float*)d_in[11];
    const float* m2_Wih   = (const float*)d_in[12];
    const float* m2_Whh   = (const float*)d_in[13];
    const float* m2_b     = (const float*)d_in[14];
    const float* out_Wih  = (const float*)d_in[15];
    const float* out_Whh  = (const float*)d_in[16];
    const float* out_b    = (const float*)d_in[17];
    const float* att_wc   = (const float*)d_in[18];
    const float* att_wq   = (const float*)d_in[19];
    const float* att_wcq  = (const float*)d_in[20];
    const float* att_b    = (const float*)d_in[21];
    const float* p1_wg    = (const float*)d_in[22];
    const float* p1_wm    = (const float*)d_in[23];
    const float* p1_b     = (const float*)d_in[24];
    const float* p2_wg    = (const float*)d_in[25];
    const float* p2_wm    = (const float*)d_in[26];
    const float* p2_b     = (const float*)d_in[27];

    float* ws = (float*)d_ws;
    size_t off = 0;
    auto alloc = [&](size_t n) { float* r = ws + off; off += n; return r; };
    auto allocU = [&](size_t nsh) { ushort* r = (ushort*)(ws + off); off += (nsh + 1) / 2; return r; };

    const size_t NC = (size_t)BB * CL;     // 32768
    const size_t NQ = (size_t)BB * QL;     // 4096

    float* xgA  = alloc(2 * NC * GATES);   // gate preacts, reused per layer
    float* gbuf = alloc(NC * 1024);        // g  (xgQ aliases its head: dead before g written)
    float* xgQ  = gbuf;
    float* co   = alloc(NC * 256);
    float* qo   = alloc(NQ * 256);
    float* sbuf = alloc(NC * QL);          // s, then a (in place)
    float* cw   = alloc(NC);
    float* qw   = alloc(NQ);
    float* smax = alloc(NC);
    float* bw   = alloc(NC);
    float* q2c  = alloc((size_t)BB * 256);
    float* mmid = alloc(NC * 256);
    float* mbuf = alloc(NC * 256);
    float* m2o  = alloc(NC * 256);
    float* lp1  = alloc(NC);
    float* lp2  = alloc(NC);
    // bf16 weight planes: [3][1024][Ksp]
    ushort* WqP  = allocU((size_t)3 * 1024 * 320);
    ushort* WpP  = allocU((size_t)3 * 1024 * 320);
    ushort* Wm1P = allocU((size_t)3 * 1024 * 1024);
    ushort* Wm2P = allocU((size_t)3 * 1024 * 256);
    ushort* WoP  = allocU((size_t)3 * 1024 * 256);
    (void)ws_size; (void)in_sizes; (void)n_in; (void)out_size;

    // ---- weight splits ----
    splitW_k<<<dim3(1024 * 80 / 256), 256, 0, stream>>>(qenc_Wih, WqP, 300, 320);
    splitW_k<<<dim3(1024 * 80 / 256), 256, 0, stream>>>(penc_Wih, WpP, 300, 320);
    splitW_k<<<dim3(1024 * 256 / 256), 256, 0, stream>>>(m1_Wih, Wm1P, 1024, 1024);
    splitW_k<<<dim3(1024 * 64 / 256), 256, 0, stream>>>(m2_Wih, Wm2P, 256, 256);
    splitW_k<<<dim3(1024 * 64 / 256), 256, 0, stream>>>(out_Wih, WoP, 256, 256);

    // ---- encoders (P and Q scans in one launch via z) ----
    gemm_bf16x3<<<dim3(8, (int)(NQ / TM)), 256, 0, stream>>>(emb, q, WqP, qenc_b, xgQ, (int)NQ, 300, 320);
    gemm_bf16x3<<<dim3(8, (int)(NC / TM)), 256, 0, stream>>>(emb, p, WpP, penc_b, xgA, (int)NC, 300, 320);
    lstm_dpp<<<dim3(BB, 2, 2), 512, 0, stream>>>(xgA, penc_Whh, co, CL,
                                                 xgQ, qenc_Whh, qo, QL);

    // ---- attention ----
    rowdot<<<dim3((int)(NC * 64 / 256)), 256, 0, stream>>>(co, att_wc, cw, (int)NC, 256);
    rowdot<<<dim3((int)(NQ * 64 / 256)), 256, 0, stream>>>(qo, att_wq, qw, (int)NQ, 256);
    att_s<<<dim3(BB, CL / 64), 256, 0, stream>>>(co, qo, cw, qw, att_wcq, att_b, sbuf);
    softmax_q<<<dim3((int)(NC * 64 / 256)), 256, 0, stream>>>(sbuf, smax);
    bw_k<<<dim3(BB), 512, 0, stream>>>(smax, bw);
    q2c_k<<<dim3(BB), 256, 0, stream>>>(bw, co, q2c);
    c2q_g<<<dim3(BB, CL / 64), 256, 0, stream>>>(sbuf, qo, co, q2c, gbuf);

    // ---- modeling layers ----
    gemm_bf16x3<<<dim3(8, (int)(NC / TM)), 256, 0, stream>>>(gbuf, nullptr, Wm1P, m1_b, xgA, (int)NC, 1024, 1024);
    lstm_dpp<<<dim3(BB, 2, 1), 512, 0, stream>>>(xgA, m1_Whh, mmid, CL,
                                                 xgA, m1_Whh, mmid, CL);
    gemm_bf16x3<<<dim3(8, (int)(NC / TM)), 256, 0, stream>>>(mmid, nullptr, Wm2P, m2_b, xgA, (int)NC, 256, 256);
    lstm_dpp<<<dim3(BB, 2, 1), 512, 0, stream>>>(xgA, m2_Whh, mbuf, CL,
                                                 xgA, m2_Whh, mbuf, CL);
    gemm_bf16x3<<<dim3(8, (int)(NC / TM)), 256, 0, stream>>>(mbuf, nullptr, WoP, out_b, xgA, (int)NC, 256, 256);
    lstm_dpp<<<dim3(BB, 2, 1), 512, 0, stream>>>(xgA, out_Whh, m2o, CL,
                                                 xgA, out_Whh, m2o, CL);

    // ---- output ----
    logits_k<<<dim3((int)(NC * 64 / 256)), 256, 0, stream>>>(gbuf, mbuf, m2o,
        p1_wg, p1_wm, p1_b, p2_wg, p2_wm, p2_b, lp1, lp2);
    masked_softmax<<<dim3(BB, 2), 512, 0, stream>>>(lp1, lp2, p, (float*)d_out);
}

// Round 14
// 2540.647 us; speedup vs baseline: 1.2416x; 1.0095x over previous
//
#include <hip/hip_runtime.h>
#include <math.h>
#include <stdint.h>

#define HD    128      // hidden
#define GATES 512      // 4H
#define BB    64       // batch
#define CL    512      // context len
#define QL    64       // query len

#define TM 128
#define TN 128
#define TK 32

typedef __attribute__((ext_vector_type(8))) short short8_t;
typedef __attribute__((ext_vector_type(4))) short short4_t;
typedef __attribute__((ext_vector_type(4))) float f32x4;
typedef __attribute__((ext_vector_type(2))) float f32x2;

__device__ __forceinline__ float fast_sigmoid(float x) {
    float e = __builtin_amdgcn_exp2f(-1.44269504f * x);
    return __builtin_amdgcn_rcpf(1.f + e);
}
__device__ __forceinline__ float fast_tanh(float x) {
    float e = __builtin_amdgcn_exp2f(2.88539008f * x);
    float r = __builtin_amdgcn_rcpf(e + 1.f);
    return 1.f - 2.f * r;
}
__device__ __forceinline__ float quad_sum(float v) {
    int y = __builtin_amdgcn_mov_dpp(__float_as_int(v), 0xB1, 0xF, 0xF, 0); // l^1
    float s = v + __int_as_float(y);
    int z = __builtin_amdgcn_mov_dpp(__float_as_int(s), 0x4E, 0xF, 0xF, 0); // l^2
    return s + __int_as_float(z);
}
// barrier that drains ONLY LDS ops; global loads/stores stay in flight.
__device__ __forceinline__ void lds_barrier() {
    asm volatile("s_waitcnt lgkmcnt(0)\n\ts_barrier" ::: "memory");
}
#define HPOS(e) ((e) + (((e) >> 5) << 2))

// ---------------------------------------------------------------------------
// Split W (rows=1024, K) fp32 into 3 bf16 planes, each (1024, Ksp), padded.
// ---------------------------------------------------------------------------
__global__ __launch_bounds__(256)
void splitW_k(const float* __restrict__ W, ushort* __restrict__ P, int K, int Ksp)
{
    int idx = blockIdx.x * 256 + threadIdx.x;
    int per_row = Ksp >> 2;
    int total = 1024 * per_row;
    if (idx >= total) return;
    int row = idx / per_row;
    int c4  = (idx - row * per_row) * 4;

    short4_t o1, o2, o3;
#pragma unroll
    for (int e = 0; e < 4; ++e) {
        int k = c4 + e;
        float x = (k < K) ? W[(size_t)row * K + k] : 0.f;
        uint32_t u1 = __float_as_uint(x) & 0xffff0000u;
        float r1 = x - __uint_as_float(u1);
        uint32_t u2 = __float_as_uint(r1) & 0xffff0000u;
        float r2 = r1 - __uint_as_float(u2);
        uint32_t u3 = __float_as_uint(r2) & 0xffff0000u;
        o1[e] = (short)(u1 >> 16);
        o2[e] = (short)(u2 >> 16);
        o3[e] = (short)(u3 >> 16);
    }
    size_t base = (size_t)row * Ksp + c4;
    size_t ps = (size_t)1024 * Ksp;
    *reinterpret_cast<short4_t*>(&P[base]) = o1;
    *reinterpret_cast<short4_t*>(&P[ps + base]) = o2;
    *reinterpret_cast<short4_t*>(&P[2 * ps + base]) = o3;
}

// ---------------------------------------------------------------------------
// MFMA GEMM v10: A in LDS as raw fp32 w/ XOR swizzle, B via global_load_lds
// (swizzled src+read), both double-buffered, 1 barrier/tile.
// ---------------------------------------------------------------------------
__global__ __launch_bounds__(256, 2)
void gemm_bf16x3(const float* __restrict__ A, const int* __restrict__ gidx,
                 const ushort* __restrict__ Wpl, const float* __restrict__ bias,
                 float* __restrict__ C, int M, int K, int Ksp)
{
    const int n0   = (blockIdx.x & 3) * TN;
    const int dir  = blockIdx.x >> 2;
    const int m0   = blockIdx.y * TM;
    const int tid  = threadIdx.x;
    const int lane = tid & 63;
    const int wid  = tid >> 6;
    const int wm   = (wid >> 1) * 64;
    const int wn   = (wid & 1) * 64;

    __shared__ __align__(16) float  Asf[2][TM * TK];     // 32768 B
    __shared__ __align__(16) ushort Bs[2][3][TN * TK];   // 49152 B

    const int srow = tid >> 3;
    const int scol = tid & 7;
    size_t sArow[4];
#pragma unroll
    for (int r = 0; r < 4; ++r) {
        int m = m0 + srow + r * 32;
        sArow[r] = gidx ? (size_t)gidx[m] : (size_t)m;
    }

    const int s0 = (lane >> 4) * 2;

    f32x4 acc[4][4];
#pragma unroll
    for (int i = 0; i < 4; ++i)
#pragma unroll
        for (int j = 0; j < 4; ++j) acc[i][j] = (f32x4)0.f;

    const size_t wps    = (size_t)1024 * Ksp;
    const size_t wdbase = (size_t)dir * 512 * Ksp;
    const int nt = Ksp / TK;

    auto stageB = [&](int k0, int bufb) {
#pragma unroll
        for (int t = 0; t < 6; ++t) {
            int chunk = wid * 6 + t;
            int pl = chunk >> 3;
            int ch = chunk & 7;
            int rrow = ch * 16 + (lane >> 2);
            int ksw  = ((lane & 3) ^ ((rrow >> 1) & 3)) * 8;
            const ushort* src = Wpl + (size_t)pl * wps + wdbase +
                                (size_t)(n0 + rrow) * Ksp + k0 + ksw;
            ushort* dst = &Bs[bufb][pl][ch * 512];
            __builtin_amdgcn_global_load_lds(
                reinterpret_cast<const __attribute__((address_space(1))) void*>(
                    reinterpret_cast<uintptr_t>(src)),
                reinterpret_cast<__attribute__((address_space(3))) void*>(
                    reinterpret_cast<uintptr_t>(dst)),
                16, 0, 0);
        }
    };
    auto stageA = [&](int k0, int bufb) {
#pragma unroll
        for (int r = 0; r < 4; ++r) {
            int row = srow + r * 32;
            int kf  = k0 + scol * 4;
            float4 v;
            if (kf + 4 <= K) {
                v = *(const float4*)(A + sArow[r] * K + kf);
            } else {
                const float* ap = A + sArow[r] * K;
                v.x = (kf     < K) ? ap[kf]     : 0.f;
                v.y = (kf + 1 < K) ? ap[kf + 1] : 0.f;
                v.z = (kf + 2 < K) ? ap[kf + 2] : 0.f;
                v.w = (kf + 3 < K) ? ap[kf + 3] : 0.f;
            }
            int sw = scol ^ (row & 7);
            *(float4*)&Asf[bufb][row * TK + sw * 4] = v;
        }
    };

    stageB(0, 0);
    stageA(0, 0);
    __syncthreads();

    int buf = 0;
    for (int kt = 0; kt < nt; ++kt) {
        if (kt + 1 < nt) {
            stageB((kt + 1) * TK, buf ^ 1);
            stageA((kt + 1) * TK, buf ^ 1);
        }

        short8_t bf0[4], bf1[4], bf2[4];
#pragma unroll
        for (int j = 0; j < 4; ++j) {
            int nrow = wn + j * 16 + (lane & 15);
            int ks = (((lane >> 4) ^ ((nrow >> 1) & 3)) * 8);
            bf0[j] = *reinterpret_cast<const short8_t*>(&Bs[buf][0][nrow * TK + ks]);
            bf1[j] = *reinterpret_cast<const short8_t*>(&Bs[buf][1][nrow * TK + ks]);
            bf2[j] = *reinterpret_cast<const short8_t*>(&Bs[buf][2][nrow * TK + ks]);
        }

#pragma unroll
        for (int i = 0; i < 4; ++i) {
            int mrow = wm + i * 16 + (lane & 15);
            int rx = mrow & 7;
            float4 fa = *(const float4*)&Asf[buf][mrow * TK + ((s0)     ^ rx) * 4];
            float4 fb = *(const float4*)&Asf[buf][mrow * TK + ((s0 + 1) ^ rx) * 4];
            float xs[8] = {fa.x, fa.y, fa.z, fa.w, fb.x, fb.y, fb.z, fb.w};
            short8_t a1, a2, a3;
#pragma unroll
            for (int e = 0; e < 8; ++e) {
                uint32_t u1 = __float_as_uint(xs[e]) & 0xffff0000u;
                float r1 = xs[e] - __uint_as_float(u1);
                uint32_t u2 = __float_as_uint(r1) & 0xffff0000u;
                float r2 = r1 - __uint_as_float(u2);
                uint32_t u3 = __float_as_uint(r2) & 0xffff0000u;
                a1[e] = (short)(u1 >> 16);
                a2[e] = (short)(u2 >> 16);
                a3[e] = (short)(u3 >> 16);
            }
#pragma unroll
            for (int j = 0; j < 4; ++j) {
                f32x4 c = acc[i][j];
                c = __builtin_amdgcn_mfma_f32_16x16x32_bf16(a1, bf0[j], c, 0, 0, 0);
                c = __builtin_amdgcn_mfma_f32_16x16x32_bf16(a1, bf1[j], c, 0, 0, 0);
                c = __builtin_amdgcn_mfma_f32_16x16x32_bf16(a2, bf0[j], c, 0, 0, 0);
                c = __builtin_amdgcn_mfma_f32_16x16x32_bf16(a2, bf1[j], c, 0, 0, 0);
                c = __builtin_amdgcn_mfma_f32_16x16x32_bf16(a1, bf2[j], c, 0, 0, 0);
                c = __builtin_amdgcn_mfma_f32_16x16x32_bf16(a3, bf0[j], c, 0, 0, 0);
                acc[i][j] = c;
            }
        }
        __syncthreads();
        buf ^= 1;
    }

    float* Cd = C + (size_t)dir * M * 512;
#pragma unroll
    for (int j = 0; j < 4; ++j) {
        int col = n0 + wn + j * 16 + (lane & 15);
        float bv = bias[dir * 512 + col];
#pragma unroll
        for (int i = 0; i < 4; ++i) {
            int rbase = m0 + wm + i * 16 + ((lane >> 4) << 2);
#pragma unroll
            for (int r = 0; r < 4; ++r)
                Cd[(size_t)(rbase + r) * 512 + col] = acc[i][j][r] + bv;
        }
    }
}

// ---------------------------------------------------------------------------
// LSTM scan v11 (EXACT round-11 version, measured pass @1.5e-5):
// DPP + packed fp32 + lgkm-only barrier + 2-step xg ring.
// ---------------------------------------------------------------------------
__global__ __launch_bounds__(512) __attribute__((amdgpu_waves_per_eu(2, 2)))
void lstm_dpp(const float* __restrict__ xgP, const float* __restrict__ WhhP,
              float* __restrict__ hoP, int TP,
              const float* __restrict__ xgQ, const float* __restrict__ WhhQ,
              float* __restrict__ hoQ, int TQ)
{
    const int b    = blockIdx.x;
    const int dir  = blockIdx.y;
    const int tid  = threadIdx.x;
    const int l    = tid & 63;
    const int w    = tid >> 6;
    const int u    = w * 16 + (l >> 2);   // hidden unit 0..127
    const int s    = l & 3;               // k-slice 0..3

    const float* xg; const float* Whh; float* ho; int T;
    if (blockIdx.z == 0) { xg = xgP; Whh = WhhP; ho = hoP; T = TP; }
    else                 { xg = xgQ; Whh = WhhQ; ho = hoQ; T = TQ; }

    const float* xgd = xg + (size_t)dir * BB * T * GATES;

    f32x2 wv2[4][16];
#pragma unroll
    for (int g = 0; g < 4; ++g) {
        const float* wr = Whh + ((size_t)dir * GATES + g * 128 + u) * HD + s * 32;
#pragma unroll
        for (int j = 0; j < 8; ++j) {
            float4 t4 = *(const float4*)(wr + j * 4);
            wv2[g][2 * j]     = f32x2{t4.x, t4.y};
            wv2[g][2 * j + 1] = f32x2{t4.z, t4.w};
        }
    }

    __shared__ __align__(16) float hs[2][140];

    if (tid < 140) { hs[0][tid] = 0.f; }
    float c = 0.f;

    int t = dir ? (T - 1) : 0;
    const int dt = dir ? -1 : 1;

    // xg ring: xc = step t, xn1 = t+dt, xn2 = t+2dt (clamped; statically named)
    float xc[4], xn1[4], xn2[4];
    {
        int t1 = t + dt; if (t1 < 0) t1 = 0; if (t1 >= T) t1 = T - 1;
#pragma unroll
        for (int g = 0; g < 4; ++g) {
            xc[g]  = xgd[((size_t)b * T + t)  * GATES + g * 128 + u];
            xn1[g] = xgd[((size_t)b * T + t1) * GATES + g * 128 + u];
        }
    }

    const int rdbase = HPOS(s * 32);
    __syncthreads();

    for (int step = 0; step < T; ++step) {
        const int rbuf = step & 1, wbuf = rbuf ^ 1;

        // prefetch t+2 (never drained by the lgkm barrier)
        {
            int t2 = t + 2 * dt;
            if (t2 < 0) t2 = 0; if (t2 >= T) t2 = T - 1;
#pragma unroll
            for (int g = 0; g < 4; ++g)
                xn2[g] = xgd[((size_t)b * T + t2) * GATES + g * 128 + u];
        }

        f32x2 p0 = {0.f, 0.f}, p1 = {0.f, 0.f}, p2 = {0.f, 0.f}, p3 = {0.f, 0.f};
#pragma unroll
        for (int j = 0; j < 8; ++j) {
            float4 h4 = *(const float4*)&hs[rbuf][rdbase + j * 4];
            f32x2 hl = {h4.x, h4.y}, hh = {h4.z, h4.w};
            p0 = __builtin_elementwise_fma(wv2[0][2 * j], hl, p0);
            p1 = __builtin_elementwise_fma(wv2[1][2 * j], hl, p1);
            p2 = __builtin_elementwise_fma(wv2[2][2 * j], hl, p2);
            p3 = __builtin_elementwise_fma(wv2[3][2 * j], hl, p3);
            p0 = __builtin_elementwise_fma(wv2[0][2 * j + 1], hh, p0);
            p1 = __builtin_elementwise_fma(wv2[1][2 * j + 1], hh, p1);
            p2 = __builtin_elementwise_fma(wv2[2][2 * j + 1], hh, p2);
            p3 = __builtin_elementwise_fma(wv2[3][2 * j + 1], hh, p3);
        }
        float pre0 = quad_sum(p0.x + p0.y) + xc[0];
        float pre1 = quad_sum(p1.x + p1.y) + xc[1];
        float pre2 = quad_sum(p2.x + p2.y) + xc[2];
        float pre3 = quad_sum(p3.x + p3.y) + xc[3];

        float ig = fast_sigmoid(pre0);
        float fg = fast_sigmoid(pre1);
        float gg = fast_tanh(pre2);
        float og = fast_sigmoid(pre3);
        c = fg * c + ig * gg;
        float h = og * fast_tanh(c);

        if (s == 0) {
            hs[wbuf][HPOS(u)] = h;
            ho[((size_t)b * T + t) * 256 + dir * HD + u] = h;
        }
        lds_barrier();   // lgkm-only: xg loads + ho stores stay in flight

#pragma unroll
        for (int g = 0; g < 4; ++g) { xc[g] = xn1[g]; xn1[g] = xn2[g]; }
        t += dt;
    }
}

// ---------------------------------------------------------------------------
// Fused attention: s = cw + qw + (co*wcq)·qo + b, row softmax over q (in
// 16-lane groups), writes probabilities a and pre-softmax row max.
// cw/qw dots computed redundantly per thread (each thread streams full rows).
// ---------------------------------------------------------------------------
__global__ __launch_bounds__(256)
void att_sm(const float* __restrict__ co, const float* __restrict__ qo,
            const float* __restrict__ wc, const float* __restrict__ wq,
            const float* __restrict__ wcq, const float* __restrict__ attb,
            float* __restrict__ a_out, float* __restrict__ smax)
{
    int b  = blockIdx.x;
    int c0 = blockIdx.y * 64;
    int tid = threadIdx.x;
    int tq = tid & 15, trc = tid >> 4;
    int cbase = c0 + trc * 4, qbase = tq * 4;

    float acc[4][4], cwa[4], qwa[4];
#pragma unroll
    for (int i = 0; i < 4; ++i) {
        cwa[i] = 0.f; qwa[i] = 0.f;
#pragma unroll
        for (int j = 0; j < 4; ++j) acc[i][j] = 0.f;
    }

    for (int d = 0; d < 256; d += 4) {
        float4 wv  = *(const float4*)&wcq[d];
        float4 wcv = *(const float4*)&wc[d];
        float4 wqv = *(const float4*)&wq[d];
        float4 cvw[4], qv[4];
#pragma unroll
        for (int i = 0; i < 4; ++i) {
            float4 v = *(const float4*)&co[((size_t)b * CL + cbase + i) * 256 + d];
            cwa[i] += v.x * wcv.x + v.y * wcv.y + v.z * wcv.z + v.w * wcv.w;
            cvw[i].x = v.x * wv.x; cvw[i].y = v.y * wv.y;
            cvw[i].z = v.z * wv.z; cvw[i].w = v.w * wv.w;
        }
#pragma unroll
        for (int j = 0; j < 4; ++j) {
            qv[j] = *(const float4*)&qo[((size_t)b * QL + qbase + j) * 256 + d];
            qwa[j] += qv[j].x * wqv.x + qv[j].y * wqv.y +
                      qv[j].z * wqv.z + qv[j].w * wqv.w;
        }
#pragma unroll
        for (int i = 0; i < 4; ++i)
#pragma unroll
            for (int j = 0; j < 4; ++j)
                acc[i][j] += cvw[i].x * qv[j].x + cvw[i].y * qv[j].y +
                             cvw[i].z * qv[j].z + cvw[i].w * qv[j].w;
    }
    float ab = attb[0];
#pragma unroll
    for (int i = 0; i < 4; ++i) {
        float sv[4];
#pragma unroll
        for (int j = 0; j < 4; ++j)
            sv[j] = acc[i][j] + cwa[i] + qwa[j] + ab;
        // row max over all 64 q (16-lane group x 4 local)
        float m = fmaxf(fmaxf(sv[0], sv[1]), fmaxf(sv[2], sv[3]));
#pragma unroll
        for (int off = 8; off; off >>= 1) m = fmaxf(m, __shfl_xor(m, off));
        float e0 = expf(sv[0] - m), e1 = expf(sv[1] - m);
        float e2 = expf(sv[2] - m), e3 = expf(sv[3] - m);
        float ls = (e0 + e1) + (e2 + e3);
#pragma unroll
        for (int off = 8; off; off >>= 1) ls += __shfl_xor(ls, off);
        float inv = 1.f / ls;
        float* ar = a_out + ((size_t)b * CL + cbase + i) * QL + qbase;
        ar[0] = e0 * inv; ar[1] = e1 * inv; ar[2] = e2 * inv; ar[3] = e3 * inv;
        if (tq == 0) smax[b * CL + cbase + i] = m;
    }
}

// ---------------------------------------------------------------------------
__global__ __launch_bounds__(512)
void bw_k(const float* __restrict__ smax, float* __restrict__ bw)
{
    int b = blockIdx.x, c = threadIdx.x;
    int lane = c & 63, wid = c >> 6;
    __shared__ float red[8];
    float v = smax[b * CL + c];
    float mx = v;
#pragma unroll
    for (int off = 32; off; off >>= 1) mx = fmaxf(mx, __shfl_xor(mx, off));
    if (lane == 0) red[wid] = mx;
    __syncthreads();
    float bm = red[0];
#pragma unroll
    for (int w = 1; w < 8; ++w) bm = fmaxf(bm, red[w]);
    float e = expf(v - bm);
    float sm = e;
#pragma unroll
    for (int off = 32; off; off >>= 1) sm += __shfl_xor(sm, off);
    __syncthreads();
    if (lane == 0) red[wid] = sm;
    __syncthreads();
    float ts = 0.f;
#pragma unroll
    for (int w = 0; w < 8; ++w) ts += red[w];
    bw[b * CL + c] = e / ts;
}

// ---------------------------------------------------------------------------
__global__ __launch_bounds__(256)
void q2c_k(const float* __restrict__ bw, const float* __restrict__ co,
           float* __restrict__ q2c)
{
    int b = blockIdx.x, d = threadIdx.x;
    float acc = 0.f;
    for (int c = 0; c < CL; ++c)
        acc += bw[b * CL + c] * co[((size_t)b * CL + c) * 256 + d];
    q2c[b * 256 + d] = acc;
}

// ---------------------------------------------------------------------------
__global__ __launch_bounds__(256)
void c2q_g(const float* __restrict__ a, const float* __restrict__ qo,
           const float* __restrict__ co, const float* __restrict__ q2c,
           float* __restrict__ g)
{
    int b  = blockIdx.x;
    int c  = blockIdx.y * 64 + (threadIdx.x >> 2);
    int gq = threadIdx.x & 3;

    float4 acc[16];
#pragma unroll
    for (int jj = 0; jj < 16; ++jj) acc[jj] = make_float4(0.f, 0.f, 0.f, 0.f);

    const float* ar = a + ((size_t)b * CL + c) * QL;
    for (int q = 0; q < QL; ++q) {
        float av = ar[q];
        const float* qr = qo + ((size_t)b * QL + q) * 256;
#pragma unroll
        for (int jj = 0; jj < 16; ++jj) {
            float4 qv = *(const float4*)&qr[4 * gq + 16 * jj];
            acc[jj].x += av * qv.x; acc[jj].y += av * qv.y;
            acc[jj].z += av * qv.z; acc[jj].w += av * qv.w;
        }
    }
    size_t gbase = ((size_t)b * CL + c) * 1024;
    const float* corow = co + ((size_t)b * CL + c) * 256;
    const float* q2cr  = q2c + b * 256;
#pragma unroll
    for (int jj = 0; jj < 16; ++jj) {
        int d = 4 * gq + 16 * jj;
        float4 cv = *(const float4*)&corow[d];
        float4 qc = *(const float4*)&q2cr[d];
        float4 cq = acc[jj];
        *(float4*)&g[gbase + d] = cv;
        *(float4*)&g[gbase + 256 + d] = cq;
        float4 t;
        t.x = cv.x * cq.x; t.y = cv.y * cq.y; t.z = cv.z * cq.z; t.w = cv.w * cq.w;
        *(float4*)&g[gbase + 512 + d] = t;
        t.x = cv.x * qc.x; t.y = cv.y * qc.y; t.z = cv.z * qc.z; t.w = cv.w * qc.w;
        *(float4*)&g[gbase + 768 + d] = t;
    }
}

// ---------------------------------------------------------------------------
__global__ void logits_k(const float* __restrict__ g, const float* __restrict__ m,
                         const float* __restrict__ m2o,
                         const float* __restrict__ p1wg, const float* __restrict__ p1wm,
                         const float* __restrict__ p1b,
                         const float* __restrict__ p2wg, const float* __restrict__ p2wm,
                         const float* __restrict__ p2b,
                         float* __restrict__ lp1, float* __restrict__ lp2)
{
    int row  = (int)((blockIdx.x * blockDim.x + threadIdx.x) >> 6);
    int lane = threadIdx.x & 63;
    const float* gr = g + (size_t)row * 1024;
    float s1 = 0.f, s2 = 0.f;
    for (int d = lane; d < 1024; d += 64) {
        float gv = gr[d];
        s1 += gv * p1wg[d];
        s2 += gv * p2wg[d];
    }
    const float* mr  = m   + (size_t)row * 256;
    const float* m2r = m2o + (size_t)row * 256;
    for (int d = lane; d < 256; d += 64) {
        s1 += mr[d] * p1wm[d];
        s2 += m2r[d] * p2wm[d];
    }
#pragma unroll
    for (int off = 32; off; off >>= 1) {
        s1 += __shfl_down(s1, off);
        s2 += __shfl_down(s2, off);
    }
    if (lane == 0) {
        lp1[row] = s1 + p1b[0];
        lp2[row] = s2 + p2b[0];
    }
}

// ---------------------------------------------------------------------------
__global__ __launch_bounds__(512)
void masked_softmax(const float* __restrict__ lp1, const float* __restrict__ lp2,
                    const int* __restrict__ p, float* __restrict__ out)
{
    int b = blockIdx.x, c = threadIdx.x;
    int lane = c & 63, wid = c >> 6;
    const float* lp = blockIdx.y ? lp2 : lp1;
    float* o = out + (size_t)blockIdx.y * BB * CL;

    __shared__ float red[8];
    float v = (p[b * CL + c] != 0) ? lp[b * CL + c] : -INFINITY;
    float mx = v;
#pragma unroll
    for (int off = 32; off; off >>= 1) mx = fmaxf(mx, __shfl_xor(mx, off));
    if (lane == 0) red[wid] = mx;
    __syncthreads();
    float bm = red[0];
#pragma unroll
    for (int w = 1; w < 8; ++w) bm = fmaxf(bm, red[w]);
    float e = expf(v - bm);
    float sm = e;
#pragma unroll
    for (int off = 32; off; off >>= 1) sm += __shfl_xor(sm, off);
    __syncthreads();
    if (lane == 0) red[wid] = sm;
    __syncthreads();
    float ts = 0.f;
#pragma unroll
    for (int w = 0; w < 8; ++w) ts += red[w];
    o[b * CL + c] = e / ts;
}

// ---------------------------------------------------------------------------
extern "C" void kernel_launch(void* const* d_in, const int* in_sizes, int n_in,
                              void* d_out, int out_size, void* d_ws, size_t ws_size,
                              hipStream_t stream)
{
    const int*   p        = (const int*)d_in[0];
    const int*   q        = (const int*)d_in[1];
    const float* emb      = (const float*)d_in[2];
    const float* qenc_Wih = (const float*)d_in[3];
    const float* qenc_Whh = (const float*)d_in[4];
    const float* qenc_b   = (const float*)d_in[5];
    const float* penc_Wih = (const float*)d_in[6];
    const float* penc_Whh = (const float*)d_in[7];
    const float* penc_b   = (const float*)d_in[8];
    const float* m1_Wih   = (const float*)d_in[9];
    const float* m1_Whh   = (const float*)d_in[10];
    const float* m1_b     = (const float*)d_in[11];
    const float* m2_Wih   = (const float*)d_in[12];
    const float* m2_Whh   = (const float*)d_in[13];
    const float* m2_b     = (const float*)d_in[14];
    const float* out_Wih  = (const float*)d_in[15];
    const float* out_Whh  = (const float*)d_in[16];
    const float* out_b    = (const float*)d_in[17];
    const float* att_wc   = (const float*)d_in[18];
    const float* att_wq   = (const float*)d_in[19];
    const float* att_wcq  = (const float*)d_in[20];
    const float* att_b    = (const float*)d_in[21];
    const float* p1_wg    = (const float*)d_in[22];
    const float* p1_wm    = (const float*)d_in[23];
    const float* p1_b     = (const float*)d_in[24];
    const float* p2_wg    = (const float*)d_in[25];
    const float* p2_wm    = (const float*)d_in[26];
    const float* p2_b     = (const float*)d_in[27];

    float* ws = (float*)d_ws;
    size_t off = 0;
    auto alloc = [&](size_t n) { float* r = ws + off; off += n; return r; };
    auto allocU = [&](size_t nsh) { ushort* r = (ushort*)(ws + off); off += (nsh + 1) / 2; return r; };

    const size_t NC = (size_t)BB * CL;     // 32768
    const size_t NQ = (size_t)BB * QL;     // 4096

    float* xgA  = alloc(2 * NC * GATES);   // gate preacts, reused per layer
    float* gbuf = alloc(NC * 1024);        // g  (xgQ aliases its head: dead before g written)
    float* xgQ  = gbuf;
    float* co   = alloc(NC * 256);
    float* qo   = alloc(NQ * 256);
    float* sbuf = alloc(NC * QL);          // a (softmaxed attention)
    float* smax = alloc(NC);
    float* bw   = alloc(NC);
    float* q2c  = alloc((size_t)BB * 256);
    float* mmid = alloc(NC * 256);
    float* mbuf = alloc(NC * 256);
    float* m2o  = alloc(NC * 256);
    float* lp1  = alloc(NC);
    float* lp2  = alloc(NC);
    // bf16 weight planes: [3][1024][Ksp]
    ushort* WqP  = allocU((size_t)3 * 1024 * 320);
    ushort* WpP  = allocU((size_t)3 * 1024 * 320);
    ushort* Wm1P = allocU((size_t)3 * 1024 * 1024);
    ushort* Wm2P = allocU((size_t)3 * 1024 * 256);
    ushort* WoP  = allocU((size_t)3 * 1024 * 256);
    (void)ws_size; (void)in_sizes; (void)n_in; (void)out_size;

    // ---- weight splits ----
    splitW_k<<<dim3(1024 * 80 / 256), 256, 0, stream>>>(qenc_Wih, WqP, 300, 320);
    splitW_k<<<dim3(1024 * 80 / 256), 256, 0, stream>>>(penc_Wih, WpP, 300, 320);
    splitW_k<<<dim3(1024 * 256 / 256), 256, 0, stream>>>(m1_Wih, Wm1P, 1024, 1024);
    splitW_k<<<dim3(1024 * 64 / 256), 256, 0, stream>>>(m2_Wih, Wm2P, 256, 256);
    splitW_k<<<dim3(1024 * 64 / 256), 256, 0, stream>>>(out_Wih, WoP, 256, 256);

    // ---- encoders (P and Q scans in one launch via z) ----
    gemm_bf16x3<<<dim3(8, (int)(NQ / TM)), 256, 0, stream>>>(emb, q, WqP, qenc_b, xgQ, (int)NQ, 300, 320);
    gemm_bf16x3<<<dim3(8, (int)(NC / TM)), 256, 0, stream>>>(emb, p, WpP, penc_b, xgA, (int)NC, 300, 320);
    lstm_dpp<<<dim3(BB, 2, 2), 512, 0, stream>>>(xgA, penc_Whh, co, CL,
                                                 xgQ, qenc_Whh, qo, QL);

    // ---- attention (fused: rowdots + similarity + q-softmax + row max) ----
    att_sm<<<dim3(BB, CL / 64), 256, 0, stream>>>(co, qo, att_wc, att_wq,
                                                  att_wcq, att_b, sbuf, smax);
    bw_k<<<dim3(BB), 512, 0, stream>>>(smax, bw);
    q2c_k<<<dim3(BB), 256, 0, stream>>>(bw, co, q2c);
    c2q_g<<<dim3(BB, CL / 64), 256, 0, stream>>>(sbuf, qo, co, q2c, gbuf);

    // ---- modeling layers ----
    gemm_bf16x3<<<dim3(8, (int)(NC / TM)), 256, 0, stream>>>(gbuf, nullptr, Wm1P, m1_b, xgA, (int)NC, 1024, 1024);
    lstm_dpp<<<dim3(BB, 2, 1), 512, 0, stream>>>(xgA, m1_Whh, mmid, CL,
                                                 xgA, m1_Whh, mmid, CL);
    gemm_bf16x3<<<dim3(8, (int)(NC / TM)), 256, 0, stream>>>(mmid, nullptr, Wm2P, m2_b, xgA, (int)NC, 256, 256);
    lstm_dpp<<<dim3(BB, 2, 1), 512, 0, stream>>>(xgA, m2_Whh, mbuf, CL,
                                                 xgA, m2_Whh, mbuf, CL);
    gemm_bf16x3<<<dim3(8, (int)(NC / TM)), 256, 0, stream>>>(mbuf, nullptr, WoP, out_b, xgA, (int)NC, 256, 256);
    lstm_dpp<<<dim3(BB, 2, 1), 512, 0, stream>>>(xgA, out_Whh, m2o, CL,
                                                 xgA, out_Whh, m2o, CL);

    // ---- output ----
    logits_k<<<dim3((int)(NC * 64 / 256)), 256, 0, stream>>>(gbuf, mbuf, m2o,
        p1_wg, p1_wm, p1_b, p2_wg, p2_wm, p2_b, lp1, lp2);
    masked_softmax<<<dim3(BB, 2), 512, 0, stream>>>(lp1, lp2, p, (float*)d_out);
}

// Round 15
// 2517.234 us; speedup vs baseline: 1.2531x; 1.0093x over previous
//
#include <hip/hip_runtime.h>
#include <math.h>
#include <stdint.h>

#define HD    128      // hidden
#define GATES 512      // 4H
#define BB    64       // batch
#define CL    512      // context len
#define QL    64       // query len

#define TM 128
#define TN 128
#define TK 32

typedef __attribute__((ext_vector_type(8))) short short8_t;
typedef __attribute__((ext_vector_type(4))) short short4_t;
typedef __attribute__((ext_vector_type(4))) float f32x4;
typedef __attribute__((ext_vector_type(2))) float f32x2;

__device__ __forceinline__ float fast_sigmoid(float x) {
    float e = __builtin_amdgcn_exp2f(-1.44269504f * x);
    return __builtin_amdgcn_rcpf(1.f + e);
}
__device__ __forceinline__ float fast_tanh(float x) {
    float e = __builtin_amdgcn_exp2f(2.88539008f * x);
    float r = __builtin_amdgcn_rcpf(e + 1.f);
    return 1.f - 2.f * r;
}
__device__ __forceinline__ float quad_sum(float v) {
    int y = __builtin_amdgcn_mov_dpp(__float_as_int(v), 0xB1, 0xF, 0xF, 0); // l^1
    float s = v + __int_as_float(y);
    int z = __builtin_amdgcn_mov_dpp(__float_as_int(s), 0x4E, 0xF, 0xF, 0); // l^2
    return s + __int_as_float(z);
}
// barrier that drains ONLY LDS ops; global loads/stores stay in flight.
__device__ __forceinline__ void lds_barrier() {
    asm volatile("s_waitcnt lgkmcnt(0)\n\ts_barrier" ::: "memory");
}
#define HPOS(e) ((e) + (((e) >> 5) << 2))

// ---------------------------------------------------------------------------
// Split 5 weight sets fp32 -> 3 bf16 planes each in ONE launch (z selects).
// ---------------------------------------------------------------------------
__global__ __launch_bounds__(256)
void splitW_all(const float* __restrict__ w0, const float* __restrict__ w1,
                const float* __restrict__ w2, const float* __restrict__ w3,
                const float* __restrict__ w4,
                ushort* __restrict__ p0, ushort* __restrict__ p1,
                ushort* __restrict__ p2, ushort* __restrict__ p3,
                ushort* __restrict__ p4)
{
    const float* W; ushort* P; int K, Ksp;
    switch (blockIdx.y) {
    case 0: W = w0; P = p0; K = 300;  Ksp = 320;  break;
    case 1: W = w1; P = p1; K = 300;  Ksp = 320;  break;
    case 2: W = w2; P = p2; K = 1024; Ksp = 1024; break;
    case 3: W = w3; P = p3; K = 256;  Ksp = 256;  break;
    default:W = w4; P = p4; K = 256;  Ksp = 256;  break;
    }
    int idx = blockIdx.x * 256 + threadIdx.x;
    int per_row = Ksp >> 2;
    int total = 1024 * per_row;
    if (idx >= total) return;
    int row = idx / per_row;
    int c4  = (idx - row * per_row) * 4;

    short4_t o1, o2, o3;
#pragma unroll
    for (int e = 0; e < 4; ++e) {
        int k = c4 + e;
        float x = (k < K) ? W[(size_t)row * K + k] : 0.f;
        uint32_t u1 = __float_as_uint(x) & 0xffff0000u;
        float r1 = x - __uint_as_float(u1);
        uint32_t u2 = __float_as_uint(r1) & 0xffff0000u;
        float r2 = r1 - __uint_as_float(u2);
        uint32_t u3 = __float_as_uint(r2) & 0xffff0000u;
        o1[e] = (short)(u1 >> 16);
        o2[e] = (short)(u2 >> 16);
        o3[e] = (short)(u3 >> 16);
    }
    size_t base = (size_t)row * Ksp + c4;
    size_t ps = (size_t)1024 * Ksp;
    *reinterpret_cast<short4_t*>(&P[base]) = o1;
    *reinterpret_cast<short4_t*>(&P[ps + base]) = o2;
    *reinterpret_cast<short4_t*>(&P[2 * ps + base]) = o3;
}

// ---------------------------------------------------------------------------
// MFMA GEMM v11: as v10 plus XCD-locality swizzle - the 8 (n0,dir) blocks
// sharing one A-tile are remapped so they land on the SAME XCD (dispatch
// index round-robins XCDs; mblk === lin&7 (mod 8) pins the panel to one L2).
// ---------------------------------------------------------------------------
__global__ __launch_bounds__(256, 2)
void gemm_bf16x3(const float* __restrict__ A, const int* __restrict__ gidx,
                 const ushort* __restrict__ Wpl, const float* __restrict__ bias,
                 float* __restrict__ C, int M, int K, int Ksp)
{
    // --- XCD-locality decode (bijective; requires (M/128) % 8 == 0) ---
    const int lin  = blockIdx.x + 8 * blockIdx.y;  // dispatch index
    const int gx   = lin & 7;                      // XCD (round-robin)
    const int idx  = lin >> 3;
    const int ndir = idx & 7;
    const int mblk = gx + ((idx >> 3) << 3);       // m-tile === gx (mod 8)
    const int n0   = (ndir & 3) * TN;
    const int dir  = ndir >> 2;
    const int m0   = mblk * TM;

    const int tid  = threadIdx.x;
    const int lane = tid & 63;
    const int wid  = tid >> 6;
    const int wm   = (wid >> 1) * 64;
    const int wn   = (wid & 1) * 64;

    __shared__ __align__(16) float  Asf[2][TM * TK];     // 32768 B
    __shared__ __align__(16) ushort Bs[2][3][TN * TK];   // 49152 B

    const int srow = tid >> 3;
    const int scol = tid & 7;
    size_t sArow[4];
#pragma unroll
    for (int r = 0; r < 4; ++r) {
        int m = m0 + srow + r * 32;
        sArow[r] = gidx ? (size_t)gidx[m] : (size_t)m;
    }

    const int s0 = (lane >> 4) * 2;

    f32x4 acc[4][4];
#pragma unroll
    for (int i = 0; i < 4; ++i)
#pragma unroll
        for (int j = 0; j < 4; ++j) acc[i][j] = (f32x4)0.f;

    const size_t wps    = (size_t)1024 * Ksp;
    const size_t wdbase = (size_t)dir * 512 * Ksp;
    const int nt = Ksp / TK;

    auto stageB = [&](int k0, int bufb) {
#pragma unroll
        for (int t = 0; t < 6; ++t) {
            int chunk = wid * 6 + t;
            int pl = chunk >> 3;
            int ch = chunk & 7;
            int rrow = ch * 16 + (lane >> 2);
            int ksw  = ((lane & 3) ^ ((rrow >> 1) & 3)) * 8;
            const ushort* src = Wpl + (size_t)pl * wps + wdbase +
                                (size_t)(n0 + rrow) * Ksp + k0 + ksw;
            ushort* dst = &Bs[bufb][pl][ch * 512];
            __builtin_amdgcn_global_load_lds(
                reinterpret_cast<const __attribute__((address_space(1))) void*>(
                    reinterpret_cast<uintptr_t>(src)),
                reinterpret_cast<__attribute__((address_space(3))) void*>(
                    reinterpret_cast<uintptr_t>(dst)),
                16, 0, 0);
        }
    };
    auto stageA = [&](int k0, int bufb) {
#pragma unroll
        for (int r = 0; r < 4; ++r) {
            int row = srow + r * 32;
            int kf  = k0 + scol * 4;
            float4 v;
            if (kf + 4 <= K) {
                v = *(const float4*)(A + sArow[r] * K + kf);
            } else {
                const float* ap = A + sArow[r] * K;
                v.x = (kf     < K) ? ap[kf]     : 0.f;
                v.y = (kf + 1 < K) ? ap[kf + 1] : 0.f;
                v.z = (kf + 2 < K) ? ap[kf + 2] : 0.f;
                v.w = (kf + 3 < K) ? ap[kf + 3] : 0.f;
            }
            int sw = scol ^ (row & 7);
            *(float4*)&Asf[bufb][row * TK + sw * 4] = v;
        }
    };

    stageB(0, 0);
    stageA(0, 0);
    __syncthreads();

    int buf = 0;
    for (int kt = 0; kt < nt; ++kt) {
        if (kt + 1 < nt) {
            stageB((kt + 1) * TK, buf ^ 1);
            stageA((kt + 1) * TK, buf ^ 1);
        }

        short8_t bf0[4], bf1[4], bf2[4];
#pragma unroll
        for (int j = 0; j < 4; ++j) {
            int nrow = wn + j * 16 + (lane & 15);
            int ks = (((lane >> 4) ^ ((nrow >> 1) & 3)) * 8);
            bf0[j] = *reinterpret_cast<const short8_t*>(&Bs[buf][0][nrow * TK + ks]);
            bf1[j] = *reinterpret_cast<const short8_t*>(&Bs[buf][1][nrow * TK + ks]);
            bf2[j] = *reinterpret_cast<const short8_t*>(&Bs[buf][2][nrow * TK + ks]);
        }

#pragma unroll
        for (int i = 0; i < 4; ++i) {
            int mrow = wm + i * 16 + (lane & 15);
            int rx = mrow & 7;
            float4 fa = *(const float4*)&Asf[buf][mrow * TK + ((s0)     ^ rx) * 4];
            float4 fb = *(const float4*)&Asf[buf][mrow * TK + ((s0 + 1) ^ rx) * 4];
            float xs[8] = {fa.x, fa.y, fa.z, fa.w, fb.x, fb.y, fb.z, fb.w};
            short8_t a1, a2, a3;
#pragma unroll
            for (int e = 0; e < 8; ++e) {
                uint32_t u1 = __float_as_uint(xs[e]) & 0xffff0000u;
                float r1 = xs[e] - __uint_as_float(u1);
                uint32_t u2 = __float_as_uint(r1) & 0xffff0000u;
                float r2 = r1 - __uint_as_float(u2);
                uint32_t u3 = __float_as_uint(r2) & 0xffff0000u;
                a1[e] = (short)(u1 >> 16);
                a2[e] = (short)(u2 >> 16);
                a3[e] = (short)(u3 >> 16);
            }
#pragma unroll
            for (int j = 0; j < 4; ++j) {
                f32x4 c = acc[i][j];
                c = __builtin_amdgcn_mfma_f32_16x16x32_bf16(a1, bf0[j], c, 0, 0, 0);
                c = __builtin_amdgcn_mfma_f32_16x16x32_bf16(a1, bf1[j], c, 0, 0, 0);
                c = __builtin_amdgcn_mfma_f32_16x16x32_bf16(a2, bf0[j], c, 0, 0, 0);
                c = __builtin_amdgcn_mfma_f32_16x16x32_bf16(a2, bf1[j], c, 0, 0, 0);
                c = __builtin_amdgcn_mfma_f32_16x16x32_bf16(a1, bf2[j], c, 0, 0, 0);
                c = __builtin_amdgcn_mfma_f32_16x16x32_bf16(a3, bf0[j], c, 0, 0, 0);
                acc[i][j] = c;
            }
        }
        __syncthreads();
        buf ^= 1;
    }

    float* Cd = C + (size_t)dir * M * 512;
#pragma unroll
    for (int j = 0; j < 4; ++j) {
        int col = n0 + wn + j * 16 + (lane & 15);
        float bv = bias[dir * 512 + col];
#pragma unroll
        for (int i = 0; i < 4; ++i) {
            int rbase = m0 + wm + i * 16 + ((lane >> 4) << 2);
#pragma unroll
            for (int r = 0; r < 4; ++r)
                Cd[(size_t)(rbase + r) * 512 + col] = acc[i][j][r] + bv;
        }
    }
}

// ---------------------------------------------------------------------------
// LSTM scan v11 (unchanged; measured pass @1.5e-5).
// ---------------------------------------------------------------------------
__global__ __launch_bounds__(512) __attribute__((amdgpu_waves_per_eu(2, 2)))
void lstm_dpp(const float* __restrict__ xgP, const float* __restrict__ WhhP,
              float* __restrict__ hoP, int TP,
              const float* __restrict__ xgQ, const float* __restrict__ WhhQ,
              float* __restrict__ hoQ, int TQ)
{
    const int b    = blockIdx.x;
    const int dir  = blockIdx.y;
    const int tid  = threadIdx.x;
    const int l    = tid & 63;
    const int w    = tid >> 6;
    const int u    = w * 16 + (l >> 2);   // hidden unit 0..127
    const int s    = l & 3;               // k-slice 0..3

    const float* xg; const float* Whh; float* ho; int T;
    if (blockIdx.z == 0) { xg = xgP; Whh = WhhP; ho = hoP; T = TP; }
    else                 { xg = xgQ; Whh = WhhQ; ho = hoQ; T = TQ; }

    const float* xgd = xg + (size_t)dir * BB * T * GATES;

    f32x2 wv2[4][16];
#pragma unroll
    for (int g = 0; g < 4; ++g) {
        const float* wr = Whh + ((size_t)dir * GATES + g * 128 + u) * HD + s * 32;
#pragma unroll
        for (int j = 0; j < 8; ++j) {
            float4 t4 = *(const float4*)(wr + j * 4);
            wv2[g][2 * j]     = f32x2{t4.x, t4.y};
            wv2[g][2 * j + 1] = f32x2{t4.z, t4.w};
        }
    }

    __shared__ __align__(16) float hs[2][140];

    if (tid < 140) { hs[0][tid] = 0.f; }
    float c = 0.f;

    int t = dir ? (T - 1) : 0;
    const int dt = dir ? -1 : 1;

    float xc[4], xn1[4], xn2[4];
    {
        int t1 = t + dt; if (t1 < 0) t1 = 0; if (t1 >= T) t1 = T - 1;
#pragma unroll
        for (int g = 0; g < 4; ++g) {
            xc[g]  = xgd[((size_t)b * T + t)  * GATES + g * 128 + u];
            xn1[g] = xgd[((size_t)b * T + t1) * GATES + g * 128 + u];
        }
    }

    const int rdbase = HPOS(s * 32);
    __syncthreads();

    for (int step = 0; step < T; ++step) {
        const int rbuf = step & 1, wbuf = rbuf ^ 1;

        {
            int t2 = t + 2 * dt;
            if (t2 < 0) t2 = 0; if (t2 >= T) t2 = T - 1;
#pragma unroll
            for (int g = 0; g < 4; ++g)
                xn2[g] = xgd[((size_t)b * T + t2) * GATES + g * 128 + u];
        }

        f32x2 p0 = {0.f, 0.f}, p1 = {0.f, 0.f}, p2 = {0.f, 0.f}, p3 = {0.f, 0.f};
#pragma unroll
        for (int j = 0; j < 8; ++j) {
            float4 h4 = *(const float4*)&hs[rbuf][rdbase + j * 4];
            f32x2 hl = {h4.x, h4.y}, hh = {h4.z, h4.w};
            p0 = __builtin_elementwise_fma(wv2[0][2 * j], hl, p0);
            p1 = __builtin_elementwise_fma(wv2[1][2 * j], hl, p1);
            p2 = __builtin_elementwise_fma(wv2[2][2 * j], hl, p2);
            p3 = __builtin_elementwise_fma(wv2[3][2 * j], hl, p3);
            p0 = __builtin_elementwise_fma(wv2[0][2 * j + 1], hh, p0);
            p1 = __builtin_elementwise_fma(wv2[1][2 * j + 1], hh, p1);
            p2 = __builtin_elementwise_fma(wv2[2][2 * j + 1], hh, p2);
            p3 = __builtin_elementwise_fma(wv2[3][2 * j + 1], hh, p3);
        }
        float pre0 = quad_sum(p0.x + p0.y) + xc[0];
        float pre1 = quad_sum(p1.x + p1.y) + xc[1];
        float pre2 = quad_sum(p2.x + p2.y) + xc[2];
        float pre3 = quad_sum(p3.x + p3.y) + xc[3];

        float ig = fast_sigmoid(pre0);
        float fg = fast_sigmoid(pre1);
        float gg = fast_tanh(pre2);
        float og = fast_sigmoid(pre3);
        c = fg * c + ig * gg;
        float h = og * fast_tanh(c);

        if (s == 0) {
            hs[wbuf][HPOS(u)] = h;
            ho[((size_t)b * T + t) * 256 + dir * HD + u] = h;
        }
        lds_barrier();

#pragma unroll
        for (int g = 0; g < 4; ++g) { xc[g] = xn1[g]; xn1[g] = xn2[g]; }
        t += dt;
    }
}

// ---------------------------------------------------------------------------
// Fused attention: similarity + q-softmax + row max (round-13 version).
// ---------------------------------------------------------------------------
__global__ __launch_bounds__(256)
void att_sm(const float* __restrict__ co, const float* __restrict__ qo,
            const float* __restrict__ wc, const float* __restrict__ wq,
            const float* __restrict__ wcq, const float* __restrict__ attb,
            float* __restrict__ a_out, float* __restrict__ smax)
{
    int b  = blockIdx.x;
    int c0 = blockIdx.y * 64;
    int tid = threadIdx.x;
    int tq = tid & 15, trc = tid >> 4;
    int cbase = c0 + trc * 4, qbase = tq * 4;

    float acc[4][4], cwa[4], qwa[4];
#pragma unroll
    for (int i = 0; i < 4; ++i) {
        cwa[i] = 0.f; qwa[i] = 0.f;
#pragma unroll
        for (int j = 0; j < 4; ++j) acc[i][j] = 0.f;
    }

    for (int d = 0; d < 256; d += 4) {
        float4 wv  = *(const float4*)&wcq[d];
        float4 wcv = *(const float4*)&wc[d];
        float4 wqv = *(const float4*)&wq[d];
        float4 cvw[4], qv[4];
#pragma unroll
        for (int i = 0; i < 4; ++i) {
            float4 v = *(const float4*)&co[((size_t)b * CL + cbase + i) * 256 + d];
            cwa[i] += v.x * wcv.x + v.y * wcv.y + v.z * wcv.z + v.w * wcv.w;
            cvw[i].x = v.x * wv.x; cvw[i].y = v.y * wv.y;
            cvw[i].z = v.z * wv.z; cvw[i].w = v.w * wv.w;
        }
#pragma unroll
        for (int j = 0; j < 4; ++j) {
            qv[j] = *(const float4*)&qo[((size_t)b * QL + qbase + j) * 256 + d];
            qwa[j] += qv[j].x * wqv.x + qv[j].y * wqv.y +
                      qv[j].z * wqv.z + qv[j].w * wqv.w;
        }
#pragma unroll
        for (int i = 0; i < 4; ++i)
#pragma unroll
            for (int j = 0; j < 4; ++j)
                acc[i][j] += cvw[i].x * qv[j].x + cvw[i].y * qv[j].y +
                             cvw[i].z * qv[j].z + cvw[i].w * qv[j].w;
    }
    float ab = attb[0];
#pragma unroll
    for (int i = 0; i < 4; ++i) {
        float sv[4];
#pragma unroll
        for (int j = 0; j < 4; ++j)
            sv[j] = acc[i][j] + cwa[i] + qwa[j] + ab;
        float m = fmaxf(fmaxf(sv[0], sv[1]), fmaxf(sv[2], sv[3]));
#pragma unroll
        for (int off = 8; off; off >>= 1) m = fmaxf(m, __shfl_xor(m, off));
        float e0 = expf(sv[0] - m), e1 = expf(sv[1] - m);
        float e2 = expf(sv[2] - m), e3 = expf(sv[3] - m);
        float ls = (e0 + e1) + (e2 + e3);
#pragma unroll
        for (int off = 8; off; off >>= 1) ls += __shfl_xor(ls, off);
        float inv = 1.f / ls;
        float* ar = a_out + ((size_t)b * CL + cbase + i) * QL + qbase;
        ar[0] = e0 * inv; ar[1] = e1 * inv; ar[2] = e2 * inv; ar[3] = e3 * inv;
        if (tq == 0) smax[b * CL + cbase + i] = m;
    }
}

// ---------------------------------------------------------------------------
// Fused bw (softmax over c of smax) + q2c (bw-weighted co sum). Block per b.
// Phase 1: 512 threads compute bw into LDS; phase 2: 256 threads do q2c.
// ---------------------------------------------------------------------------
__global__ __launch_bounds__(512)
void bwq2c_k(const float* __restrict__ smax, const float* __restrict__ co,
             float* __restrict__ q2c)
{
    int b = blockIdx.x, c = threadIdx.x;
    int lane = c & 63, wid = c >> 6;
    __shared__ float red[8];
    __shared__ float bwsh[CL];

    float v = smax[b * CL + c];
    float mx = v;
#pragma unroll
    for (int off = 32; off; off >>= 1) mx = fmaxf(mx, __shfl_xor(mx, off));
    if (lane == 0) red[wid] = mx;
    __syncthreads();
    float bm = red[0];
#pragma unroll
    for (int w = 1; w < 8; ++w) bm = fmaxf(bm, red[w]);
    float e = expf(v - bm);
    float sm = e;
#pragma unroll
    for (int off = 32; off; off >>= 1) sm += __shfl_xor(sm, off);
    __syncthreads();
    if (lane == 0) red[wid] = sm;
    __syncthreads();
    float ts = 0.f;
#pragma unroll
    for (int w = 0; w < 8; ++w) ts += red[w];
    bwsh[c] = e / ts;
    __syncthreads();

    if (c < 256) {
        int d = c;
        float acc = 0.f;
        for (int cc = 0; cc < CL; ++cc)
            acc += bwsh[cc] * co[((size_t)b * CL + cc) * 256 + d];
        q2c[b * 256 + d] = acc;
    }
}

// ---------------------------------------------------------------------------
__global__ __launch_bounds__(256)
void c2q_g(const float* __restrict__ a, const float* __restrict__ qo,
           const float* __restrict__ co, const float* __restrict__ q2c,
           float* __restrict__ g)
{
    int b  = blockIdx.x;
    int c  = blockIdx.y * 64 + (threadIdx.x >> 2);
    int gq = threadIdx.x & 3;

    float4 acc[16];
#pragma unroll
    for (int jj = 0; jj < 16; ++jj) acc[jj] = make_float4(0.f, 0.f, 0.f, 0.f);

    const float* ar = a + ((size_t)b * CL + c) * QL;
    for (int q = 0; q < QL; ++q) {
        float av = ar[q];
        const float* qr = qo + ((size_t)b * QL + q) * 256;
#pragma unroll
        for (int jj = 0; jj < 16; ++jj) {
            float4 qv = *(const float4*)&qr[4 * gq + 16 * jj];
            acc[jj].x += av * qv.x; acc[jj].y += av * qv.y;
            acc[jj].z += av * qv.z; acc[jj].w += av * qv.w;
        }
    }
    size_t gbase = ((size_t)b * CL + c) * 1024;
    const float* corow = co + ((size_t)b * CL + c) * 256;
    const float* q2cr  = q2c + b * 256;
#pragma unroll
    for (int jj = 0; jj < 16; ++jj) {
        int d = 4 * gq + 16 * jj;
        float4 cv = *(const float4*)&corow[d];
        float4 qc = *(const float4*)&q2cr[d];
        float4 cq = acc[jj];
        *(float4*)&g[gbase + d] = cv;
        *(float4*)&g[gbase + 256 + d] = cq;
        float4 t;
        t.x = cv.x * cq.x; t.y = cv.y * cq.y; t.z = cv.z * cq.z; t.w = cv.w * cq.w;
        *(float4*)&g[gbase + 512 + d] = t;
        t.x = cv.x * qc.x; t.y = cv.y * qc.y; t.z = cv.z * qc.z; t.w = cv.w * qc.w;
        *(float4*)&g[gbase + 768 + d] = t;
    }
}

// ---------------------------------------------------------------------------
__global__ void logits_k(const float* __restrict__ g, const float* __restrict__ m,
                         const float* __restrict__ m2o,
                         const float* __restrict__ p1wg, const float* __restrict__ p1wm,
                         const float* __restrict__ p1b,
                         const float* __restrict__ p2wg, const float* __restrict__ p2wm,
                         const float* __restrict__ p2b,
                         float* __restrict__ lp1, float* __restrict__ lp2)
{
    int row  = (int)((blockIdx.x * blockDim.x + threadIdx.x) >> 6);
    int lane = threadIdx.x & 63;
    const float* gr = g + (size_t)row * 1024;
    float s1 = 0.f, s2 = 0.f;
    for (int d = lane; d < 1024; d += 64) {
        float gv = gr[d];
        s1 += gv * p1wg[d];
        s2 += gv * p2wg[d];
    }
    const float* mr  = m   + (size_t)row * 256;
    const float* m2r = m2o + (size_t)row * 256;
    for (int d = lane; d < 256; d += 64) {
        s1 += mr[d] * p1wm[d];
        s2 += m2r[d] * p2wm[d];
    }
#pragma unroll
    for (int off = 32; off; off >>= 1) {
        s1 += __shfl_down(s1, off);
        s2 += __shfl_down(s2, off);
    }
    if (lane == 0) {
        lp1[row] = s1 + p1b[0];
        lp2[row] = s2 + p2b[0];
    }
}

// ---------------------------------------------------------------------------
__global__ __launch_bounds__(512)
void masked_softmax(const float* __restrict__ lp1, const float* __restrict__ lp2,
                    const int* __restrict__ p, float* __restrict__ out)
{
    int b = blockIdx.x, c = threadIdx.x;
    int lane = c & 63, wid = c >> 6;
    const float* lp = blockIdx.y ? lp2 : lp1;
    float* o = out + (size_t)blockIdx.y * BB * CL;

    __shared__ float red[8];
    float v = (p[b * CL + c] != 0) ? lp[b * CL + c] : -INFINITY;
    float mx = v;
#pragma unroll
    for (int off = 32; off; off >>= 1) mx = fmaxf(mx, __shfl_xor(mx, off));
    if (lane == 0) red[wid] = mx;
    __syncthreads();
    float bm = red[0];
#pragma unroll
    for (int w = 1; w < 8; ++w) bm = fmaxf(bm, red[w]);
    float e = expf(v - bm);
    float sm = e;
#pragma unroll
    for (int off = 32; off; off >>= 1) sm += __shfl_xor(sm, off);
    __syncthreads();
    if (lane == 0) red[wid] = sm;
    __syncthreads();
    float ts = 0.f;
#pragma unroll
    for (int w = 0; w < 8; ++w) ts += red[w];
    o[b * CL + c] = e / ts;
}

// ---------------------------------------------------------------------------
extern "C" void kernel_launch(void* const* d_in, const int* in_sizes, int n_in,
                              void* d_out, int out_size, void* d_ws, size_t ws_size,
                              hipStream_t stream)
{
    const int*   p        = (const int*)d_in[0];
    const int*   q        = (const int*)d_in[1];
    const float* emb      = (const float*)d_in[2];
    const float* qenc_Wih = (const float*)d_in[3];
    const float* qenc_Whh = (const float*)d_in[4];
    const float* qenc_b   = (const float*)d_in[5];
    const float* penc_Wih = (const float*)d_in[6];
    const float* penc_Whh = (const float*)d_in[7];
    const float* penc_b   = (const float*)d_in[8];
    const float* m1_Wih   = (const float*)d_in[9];
    const float* m1_Whh   = (const float*)d_in[10];
    const float* m1_b     = (const float*)d_in[11];
    const float* m2_Wih   = (const float*)d_in[12];
    const float* m2_Whh   = (const float*)d_in[13];
    const float* m2_b     = (const float*)d_in[14];
    const float* out_Wih  = (const float*)d_in[15];
    const float* out_Whh  = (const float*)d_in[16];
    const float* out_b    = (const float*)d_in[17];
    const float* att_wc   = (const float*)d_in[18];
    const float* att_wq   = (const float*)d_in[19];
    const float* att_wcq  = (const float*)d_in[20];
    const float* att_b    = (const float*)d_in[21];
    const float* p1_wg    = (const float*)d_in[22];
    const float* p1_wm    = (const float*)d_in[23];
    const float* p1_b     = (const float*)d_in[24];
    const float* p2_wg    = (const float*)d_in[25];
    const float* p2_wm    = (const float*)d_in[26];
    const float* p2_b     = (const float*)d_in[27];

    float* ws = (float*)d_ws;
    size_t off = 0;
    auto alloc = [&](size_t n) { float* r = ws + off; off += n; return r; };
    auto allocU = [&](size_t nsh) { ushort* r = (ushort*)(ws + off); off += (nsh + 1) / 2; return r; };

    const size_t NC = (size_t)BB * CL;     // 32768
    const size_t NQ = (size_t)BB * QL;     // 4096

    float* xgA  = alloc(2 * NC * GATES);   // gate preacts, reused per layer
    float* gbuf = alloc(NC * 1024);        // g  (xgQ aliases its head: dead before g written)
    float* xgQ  = gbuf;
    float* co   = alloc(NC * 256);
    float* qo   = alloc(NQ * 256);
    float* sbuf = alloc(NC * QL);          // a (softmaxed attention)
    float* smax = alloc(NC);
    float* q2c  = alloc((size_t)BB * 256);
    float* mmid = alloc(NC * 256);
    float* mbuf = alloc(NC * 256);
    float* m2o  = alloc(NC * 256);
    float* lp1  = alloc(NC);
    float* lp2  = alloc(NC);
    // bf16 weight planes: [3][1024][Ksp]
    ushort* WqP  = allocU((size_t)3 * 1024 * 320);
    ushort* WpP  = allocU((size_t)3 * 1024 * 320);
    ushort* Wm1P = allocU((size_t)3 * 1024 * 1024);
    ushort* Wm2P = allocU((size_t)3 * 1024 * 256);
    ushort* WoP  = allocU((size_t)3 * 1024 * 256);
    (void)ws_size; (void)in_sizes; (void)n_in; (void)out_size;

    // ---- weight splits (single launch) ----
    splitW_all<<<dim3(1024, 5), 256, 0, stream>>>(qenc_Wih, penc_Wih, m1_Wih,
                                                  m2_Wih, out_Wih,
                                                  WqP, WpP, Wm1P, Wm2P, WoP);

    // ---- encoders (P and Q scans in one launch via z) ----
    gemm_bf16x3<<<dim3(8, (int)(NQ / TM)), 256, 0, stream>>>(emb, q, WqP, qenc_b, xgQ, (int)NQ, 300, 320);
    gemm_bf16x3<<<dim3(8, (int)(NC / TM)), 256, 0, stream>>>(emb, p, WpP, penc_b, xgA, (int)NC, 300, 320);
    lstm_dpp<<<dim3(BB, 2, 2), 512, 0, stream>>>(xgA, penc_Whh, co, CL,
                                                 xgQ, qenc_Whh, qo, QL);

    // ---- attention ----
    att_sm<<<dim3(BB, CL / 64), 256, 0, stream>>>(co, qo, att_wc, att_wq,
                                                  att_wcq, att_b, sbuf, smax);
    bwq2c_k<<<dim3(BB), 512, 0, stream>>>(smax, co, q2c);
    c2q_g<<<dim3(BB, CL / 64), 256, 0, stream>>>(sbuf, qo, co, q2c, gbuf);

    // ---- modeling layers ----
    gemm_bf16x3<<<dim3(8, (int)(NC / TM)), 256, 0, stream>>>(gbuf, nullptr, Wm1P, m1_b, xgA, (int)NC, 1024, 1024);
    lstm_dpp<<<dim3(BB, 2, 1), 512, 0, stream>>>(xgA, m1_Whh, mmid, CL,
                                                 xgA, m1_Whh, mmid, CL);
    gemm_bf16x3<<<dim3(8, (int)(NC / TM)), 256, 0, stream>>>(mmid, nullptr, Wm2P, m2_b, xgA, (int)NC, 256, 256);
    lstm_dpp<<<dim3(BB, 2, 1), 512, 0, stream>>>(xgA, m2_Whh, mbuf, CL,
                                                 xgA, m2_Whh, mbuf, CL);
    gemm_bf16x3<<<dim3(8, (int)(NC / TM)), 256, 0, stream>>>(mbuf, nullptr, WoP, out_b, xgA, (int)NC, 256, 256);
    lstm_dpp<<<dim3(BB, 2, 1), 512, 0, stream>>>(xgA, out_Whh, m2o, CL,
                                                 xgA, out_Whh, m2o, CL);

    // ---- output ----
    logits_k<<<dim3((int)(NC * 64 / 256)), 256, 0, stream>>>(gbuf, mbuf, m2o,
        p1_wg, p1_wm, p1_b, p2_wg, p2_wm, p2_b, lp1, lp2);
    masked_softmax<<<dim3(BB, 2), 512, 0, stream>>>(lp1, lp2, p, (float*)d_out);
}

// Round 16
// 2378.557 us; speedup vs baseline: 1.3262x; 1.0583x over previous
//
#include <hip/hip_runtime.h>
#include <math.h>
#include <stdint.h>

#define HD    128      // hidden
#define GATES 512      // 4H
#define BB    64       // batch
#define CL    512      // context len
#define QL    64       // query len

#define TM 128
#define TN 128
#define TK 32

typedef __attribute__((ext_vector_type(8))) short short8_t;
typedef __attribute__((ext_vector_type(8))) _Float16 half8_t;
typedef __attribute__((ext_vector_type(4))) float f32x4;
typedef __attribute__((ext_vector_type(2))) float f32x2;

__device__ __forceinline__ float fast_sigmoid(float x) {
    float e = __builtin_amdgcn_exp2f(-1.44269504f * x);
    return __builtin_amdgcn_rcpf(1.f + e);
}
__device__ __forceinline__ float fast_tanh(float x) {
    float e = __builtin_amdgcn_exp2f(2.88539008f * x);
    float r = __builtin_amdgcn_rcpf(e + 1.f);
    return 1.f - 2.f * r;
}
__device__ __forceinline__ float quad_sum(float v) {
    int y = __builtin_amdgcn_mov_dpp(__float_as_int(v), 0xB1, 0xF, 0xF, 0); // l^1
    float s = v + __int_as_float(y);
    int z = __builtin_amdgcn_mov_dpp(__float_as_int(s), 0x4E, 0xF, 0xF, 0); // l^2
    return s + __int_as_float(z);
}
// barrier that drains ONLY LDS ops; global loads/stores stay in flight.
__device__ __forceinline__ void lds_barrier() {
    asm volatile("s_waitcnt lgkmcnt(0)\n\ts_barrier" ::: "memory");
}
#define HPOS(e) ((e) + (((e) >> 5) << 2))

// ---------------------------------------------------------------------------
// Split 5 weight sets fp32 -> 2 fp16 planes each (RNE; residual exact) in
// ONE launch. Plane layout [2][1024][Ksp] ushort (fp16 bits).
// ---------------------------------------------------------------------------
__global__ __launch_bounds__(256)
void splitW_all(const float* __restrict__ w0, const float* __restrict__ w1,
                const float* __restrict__ w2, const float* __restrict__ w3,
                const float* __restrict__ w4,
                ushort* __restrict__ p0, ushort* __restrict__ p1,
                ushort* __restrict__ p2, ushort* __restrict__ p3,
                ushort* __restrict__ p4)
{
    const float* W; ushort* P; int K, Ksp;
    switch (blockIdx.y) {
    case 0: W = w0; P = p0; K = 300;  Ksp = 320;  break;
    case 1: W = w1; P = p1; K = 300;  Ksp = 320;  break;
    case 2: W = w2; P = p2; K = 1024; Ksp = 1024; break;
    case 3: W = w3; P = p3; K = 256;  Ksp = 256;  break;
    default:W = w4; P = p4; K = 256;  Ksp = 256;  break;
    }
    int idx = blockIdx.x * 256 + threadIdx.x;
    int per_row = Ksp >> 2;
    int total = 1024 * per_row;
    if (idx >= total) return;
    int row = idx / per_row;
    int c4  = (idx - row * per_row) * 4;

    ushort o1[4], o2[4];
#pragma unroll
    for (int e = 0; e < 4; ++e) {
        int k = c4 + e;
        float x = (k < K) ? W[(size_t)row * K + k] : 0.f;
        _Float16 h1 = (_Float16)x;           // RNE
        float r1 = x - (float)h1;            // exact
        _Float16 h2 = (_Float16)r1;          // RNE
        o1[e] = *(ushort*)&h1;
        o2[e] = *(ushort*)&h2;
    }
    size_t base = (size_t)row * Ksp + c4;
    size_t ps = (size_t)1024 * Ksp;
#pragma unroll
    for (int e = 0; e < 4; ++e) {
        P[base + e]      = o1[e];
        P[ps + base + e] = o2[e];
    }
}

// ---------------------------------------------------------------------------
// MFMA GEMM v12 (fp16x2, 3 cross terms): A staged in LDS as raw fp32 with
// 16B-slot XOR swizzle, split to 2 fp16 planes IN-REGISTER after the read;
// B = 2 pre-split fp16 planes via global_load_lds (swizzled src+read).
// Both double-buffered, ONE barrier per k-tile. XCD-locality block swizzle.
// Error: dropped terms <= ~3*2^-22|ab| -> ~2e-6 pre-act (safe per r4/r5).
// ---------------------------------------------------------------------------
__global__ __launch_bounds__(256, 2)
void gemm_f16x2(const float* __restrict__ A, const int* __restrict__ gidx,
                const ushort* __restrict__ Wpl, const float* __restrict__ bias,
                float* __restrict__ C, int M, int K, int Ksp)
{
    // --- XCD-locality decode (bijective; requires (M/128) % 8 == 0) ---
    const int lin  = blockIdx.x + 8 * blockIdx.y;
    const int gx   = lin & 7;
    const int idx  = lin >> 3;
    const int ndir = idx & 7;
    const int mblk = gx + ((idx >> 3) << 3);
    const int n0   = (ndir & 3) * TN;
    const int dir  = ndir >> 2;
    const int m0   = mblk * TM;

    const int tid  = threadIdx.x;
    const int lane = tid & 63;
    const int wid  = tid >> 6;
    const int wm   = (wid >> 1) * 64;
    const int wn   = (wid & 1) * 64;

    __shared__ __align__(16) float  Asf[2][TM * TK];     // 32768 B
    __shared__ __align__(16) ushort Bs[2][2][TN * TK];   // 32768 B

    const int srow = tid >> 3;
    const int scol = tid & 7;
    size_t sArow[4];
#pragma unroll
    for (int r = 0; r < 4; ++r) {
        int m = m0 + srow + r * 32;
        sArow[r] = gidx ? (size_t)gidx[m] : (size_t)m;
    }

    const int s0 = (lane >> 4) * 2;

    f32x4 acc[4][4];
#pragma unroll
    for (int i = 0; i < 4; ++i)
#pragma unroll
        for (int j = 0; j < 4; ++j) acc[i][j] = (f32x4)0.f;

    const size_t wps    = (size_t)1024 * Ksp;
    const size_t wdbase = (size_t)dir * 512 * Ksp;
    const int nt = Ksp / TK;

    auto stageB = [&](int k0, int bufb) {
#pragma unroll
        for (int t = 0; t < 4; ++t) {
            int chunk = wid * 4 + t;        // 0..15: 2 planes x 8 chunks
            int pl = chunk >> 3;
            int ch = chunk & 7;
            int rrow = ch * 16 + (lane >> 2);
            int ksw  = ((lane & 3) ^ ((rrow >> 1) & 3)) * 8;
            const ushort* src = Wpl + (size_t)pl * wps + wdbase +
                                (size_t)(n0 + rrow) * Ksp + k0 + ksw;
            ushort* dst = &Bs[bufb][pl][ch * 512];
            __builtin_amdgcn_global_load_lds(
                reinterpret_cast<const __attribute__((address_space(1))) void*>(
                    reinterpret_cast<uintptr_t>(src)),
                reinterpret_cast<__attribute__((address_space(3))) void*>(
                    reinterpret_cast<uintptr_t>(dst)),
                16, 0, 0);
        }
    };
    auto stageA = [&](int k0, int bufb) {
#pragma unroll
        for (int r = 0; r < 4; ++r) {
            int row = srow + r * 32;
            int kf  = k0 + scol * 4;
            float4 v;
            if (kf + 4 <= K) {
                v = *(const float4*)(A + sArow[r] * K + kf);
            } else {
                const float* ap = A + sArow[r] * K;
                v.x = (kf     < K) ? ap[kf]     : 0.f;
                v.y = (kf + 1 < K) ? ap[kf + 1] : 0.f;
                v.z = (kf + 2 < K) ? ap[kf + 2] : 0.f;
                v.w = (kf + 3 < K) ? ap[kf + 3] : 0.f;
            }
            int sw = scol ^ (row & 7);
            *(float4*)&Asf[bufb][row * TK + sw * 4] = v;
        }
    };

    stageB(0, 0);
    stageA(0, 0);
    __syncthreads();

    int buf = 0;
    for (int kt = 0; kt < nt; ++kt) {
        if (kt + 1 < nt) {
            stageB((kt + 1) * TK, buf ^ 1);
            stageA((kt + 1) * TK, buf ^ 1);
        }

        half8_t bf0[4], bf1[4];
#pragma unroll
        for (int j = 0; j < 4; ++j) {
            int nrow = wn + j * 16 + (lane & 15);
            int ks = (((lane >> 4) ^ ((nrow >> 1) & 3)) * 8);
            bf0[j] = *reinterpret_cast<const half8_t*>(&Bs[buf][0][nrow * TK + ks]);
            bf1[j] = *reinterpret_cast<const half8_t*>(&Bs[buf][1][nrow * TK + ks]);
        }

#pragma unroll
        for (int i = 0; i < 4; ++i) {
            int mrow = wm + i * 16 + (lane & 15);
            int rx = mrow & 7;
            float4 fa = *(const float4*)&Asf[buf][mrow * TK + ((s0)     ^ rx) * 4];
            float4 fb = *(const float4*)&Asf[buf][mrow * TK + ((s0 + 1) ^ rx) * 4];
            float xs[8] = {fa.x, fa.y, fa.z, fa.w, fb.x, fb.y, fb.z, fb.w};
            half8_t a1, a2;
#pragma unroll
            for (int e = 0; e < 8; ++e) {
                _Float16 h1 = (_Float16)xs[e];
                float r = xs[e] - (float)h1;
                a1[e] = h1;
                a2[e] = (_Float16)r;
            }
#pragma unroll
            for (int j = 0; j < 4; ++j) {
                f32x4 c = acc[i][j];
                c = __builtin_amdgcn_mfma_f32_16x16x32_f16(a1, bf0[j], c, 0, 0, 0);
                c = __builtin_amdgcn_mfma_f32_16x16x32_f16(a1, bf1[j], c, 0, 0, 0);
                c = __builtin_amdgcn_mfma_f32_16x16x32_f16(a2, bf0[j], c, 0, 0, 0);
                acc[i][j] = c;
            }
        }
        __syncthreads();
        buf ^= 1;
    }

    float* Cd = C + (size_t)dir * M * 512;
#pragma unroll
    for (int j = 0; j < 4; ++j) {
        int col = n0 + wn + j * 16 + (lane & 15);
        float bv = bias[dir * 512 + col];
#pragma unroll
        for (int i = 0; i < 4; ++i) {
            int rbase = m0 + wm + i * 16 + ((lane >> 4) << 2);
#pragma unroll
            for (int r = 0; r < 4; ++r)
                Cd[(size_t)(rbase + r) * 512 + col] = acc[i][j][r] + bv;
        }
    }
}

// ---------------------------------------------------------------------------
// LSTM scan v11 (unchanged; measured pass @1.5e-5).
// ---------------------------------------------------------------------------
__global__ __launch_bounds__(512) __attribute__((amdgpu_waves_per_eu(2, 2)))
void lstm_dpp(const float* __restrict__ xgP, const float* __restrict__ WhhP,
              float* __restrict__ hoP, int TP,
              const float* __restrict__ xgQ, const float* __restrict__ WhhQ,
              float* __restrict__ hoQ, int TQ)
{
    const int b    = blockIdx.x;
    const int dir  = blockIdx.y;
    const int tid  = threadIdx.x;
    const int l    = tid & 63;
    const int w    = tid >> 6;
    const int u    = w * 16 + (l >> 2);   // hidden unit 0..127
    const int s    = l & 3;               // k-slice 0..3

    const float* xg; const float* Whh; float* ho; int T;
    if (blockIdx.z == 0) { xg = xgP; Whh = WhhP; ho = hoP; T = TP; }
    else                 { xg = xgQ; Whh = WhhQ; ho = hoQ; T = TQ; }

    const float* xgd = xg + (size_t)dir * BB * T * GATES;

    f32x2 wv2[4][16];
#pragma unroll
    for (int g = 0; g < 4; ++g) {
        const float* wr = Whh + ((size_t)dir * GATES + g * 128 + u) * HD + s * 32;
#pragma unroll
        for (int j = 0; j < 8; ++j) {
            float4 t4 = *(const float4*)(wr + j * 4);
            wv2[g][2 * j]     = f32x2{t4.x, t4.y};
            wv2[g][2 * j + 1] = f32x2{t4.z, t4.w};
        }
    }

    __shared__ __align__(16) float hs[2][140];

    if (tid < 140) { hs[0][tid] = 0.f; }
    float c = 0.f;

    int t = dir ? (T - 1) : 0;
    const int dt = dir ? -1 : 1;

    float xc[4], xn1[4], xn2[4];
    {
        int t1 = t + dt; if (t1 < 0) t1 = 0; if (t1 >= T) t1 = T - 1;
#pragma unroll
        for (int g = 0; g < 4; ++g) {
            xc[g]  = xgd[((size_t)b * T + t)  * GATES + g * 128 + u];
            xn1[g] = xgd[((size_t)b * T + t1) * GATES + g * 128 + u];
        }
    }

    const int rdbase = HPOS(s * 32);
    __syncthreads();

    for (int step = 0; step < T; ++step) {
        const int rbuf = step & 1, wbuf = rbuf ^ 1;

        {
            int t2 = t + 2 * dt;
            if (t2 < 0) t2 = 0; if (t2 >= T) t2 = T - 1;
#pragma unroll
            for (int g = 0; g < 4; ++g)
                xn2[g] = xgd[((size_t)b * T + t2) * GATES + g * 128 + u];
        }

        f32x2 p0 = {0.f, 0.f}, p1 = {0.f, 0.f}, p2 = {0.f, 0.f}, p3 = {0.f, 0.f};
#pragma unroll
        for (int j = 0; j < 8; ++j) {
            float4 h4 = *(const float4*)&hs[rbuf][rdbase + j * 4];
            f32x2 hl = {h4.x, h4.y}, hh = {h4.z, h4.w};
            p0 = __builtin_elementwise_fma(wv2[0][2 * j], hl, p0);
            p1 = __builtin_elementwise_fma(wv2[1][2 * j], hl, p1);
            p2 = __builtin_elementwise_fma(wv2[2][2 * j], hl, p2);
            p3 = __builtin_elementwise_fma(wv2[3][2 * j], hl, p3);
            p0 = __builtin_elementwise_fma(wv2[0][2 * j + 1], hh, p0);
            p1 = __builtin_elementwise_fma(wv2[1][2 * j + 1], hh, p1);
            p2 = __builtin_elementwise_fma(wv2[2][2 * j + 1], hh, p2);
            p3 = __builtin_elementwise_fma(wv2[3][2 * j + 1], hh, p3);
        }
        float pre0 = quad_sum(p0.x + p0.y) + xc[0];
        float pre1 = quad_sum(p1.x + p1.y) + xc[1];
        float pre2 = quad_sum(p2.x + p2.y) + xc[2];
        float pre3 = quad_sum(p3.x + p3.y) + xc[3];

        float ig = fast_sigmoid(pre0);
        float fg = fast_sigmoid(pre1);
        float gg = fast_tanh(pre2);
        float og = fast_sigmoid(pre3);
        c = fg * c + ig * gg;
        float h = og * fast_tanh(c);

        if (s == 0) {
            hs[wbuf][HPOS(u)] = h;
            ho[((size_t)b * T + t) * 256 + dir * HD + u] = h;
        }
        lds_barrier();

#pragma unroll
        for (int g = 0; g < 4; ++g) { xc[g] = xn1[g]; xn1[g] = xn2[g]; }
        t += dt;
    }
}

// ---------------------------------------------------------------------------
// Fused attention: similarity + q-softmax + row max.
// ---------------------------------------------------------------------------
__global__ __launch_bounds__(256)
void att_sm(const float* __restrict__ co, const float* __restrict__ qo,
            const float* __restrict__ wc, const float* __restrict__ wq,
            const float* __restrict__ wcq, const float* __restrict__ attb,
            float* __restrict__ a_out, float* __restrict__ smax)
{
    int b  = blockIdx.x;
    int c0 = blockIdx.y * 64;
    int tid = threadIdx.x;
    int tq = tid & 15, trc = tid >> 4;
    int cbase = c0 + trc * 4, qbase = tq * 4;

    float acc[4][4], cwa[4], qwa[4];
#pragma unroll
    for (int i = 0; i < 4; ++i) {
        cwa[i] = 0.f; qwa[i] = 0.f;
#pragma unroll
        for (int j = 0; j < 4; ++j) acc[i][j] = 0.f;
    }

    for (int d = 0; d < 256; d += 4) {
        float4 wv  = *(const float4*)&wcq[d];
        float4 wcv = *(const float4*)&wc[d];
        float4 wqv = *(const float4*)&wq[d];
        float4 cvw[4], qv[4];
#pragma unroll
        for (int i = 0; i < 4; ++i) {
            float4 v = *(const float4*)&co[((size_t)b * CL + cbase + i) * 256 + d];
            cwa[i] += v.x * wcv.x + v.y * wcv.y + v.z * wcv.z + v.w * wcv.w;
            cvw[i].x = v.x * wv.x; cvw[i].y = v.y * wv.y;
            cvw[i].z = v.z * wv.z; cvw[i].w = v.w * wv.w;
        }
#pragma unroll
        for (int j = 0; j < 4; ++j) {
            qv[j] = *(const float4*)&qo[((size_t)b * QL + qbase + j) * 256 + d];
            qwa[j] += qv[j].x * wqv.x + qv[j].y * wqv.y +
                      qv[j].z * wqv.z + qv[j].w * wqv.w;
        }
#pragma unroll
        for (int i = 0; i < 4; ++i)
#pragma unroll
            for (int j = 0; j < 4; ++j)
                acc[i][j] += cvw[i].x * qv[j].x + cvw[i].y * qv[j].y +
                             cvw[i].z * qv[j].z + cvw[i].w * qv[j].w;
    }
    float ab = attb[0];
#pragma unroll
    for (int i = 0; i < 4; ++i) {
        float sv[4];
#pragma unroll
        for (int j = 0; j < 4; ++j)
            sv[j] = acc[i][j] + cwa[i] + qwa[j] + ab;
        float m = fmaxf(fmaxf(sv[0], sv[1]), fmaxf(sv[2], sv[3]));
#pragma unroll
        for (int off = 8; off; off >>= 1) m = fmaxf(m, __shfl_xor(m, off));
        float e0 = expf(sv[0] - m), e1 = expf(sv[1] - m);
        float e2 = expf(sv[2] - m), e3 = expf(sv[3] - m);
        float ls = (e0 + e1) + (e2 + e3);
#pragma unroll
        for (int off = 8; off; off >>= 1) ls += __shfl_xor(ls, off);
        float inv = 1.f / ls;
        float* ar = a_out + ((size_t)b * CL + cbase + i) * QL + qbase;
        ar[0] = e0 * inv; ar[1] = e1 * inv; ar[2] = e2 * inv; ar[3] = e3 * inv;
        if (tq == 0) smax[b * CL + cbase + i] = m;
    }
}

// ---------------------------------------------------------------------------
// Fused bw softmax + q2c.
// ---------------------------------------------------------------------------
__global__ __launch_bounds__(512)
void bwq2c_k(const float* __restrict__ smax, const float* __restrict__ co,
             float* __restrict__ q2c)
{
    int b = blockIdx.x, c = threadIdx.x;
    int lane = c & 63, wid = c >> 6;
    __shared__ float red[8];
    __shared__ float bwsh[CL];

    float v = smax[b * CL + c];
    float mx = v;
#pragma unroll
    for (int off = 32; off; off >>= 1) mx = fmaxf(mx, __shfl_xor(mx, off));
    if (lane == 0) red[wid] = mx;
    __syncthreads();
    float bm = red[0];
#pragma unroll
    for (int w = 1; w < 8; ++w) bm = fmaxf(bm, red[w]);
    float e = expf(v - bm);
    float sm = e;
#pragma unroll
    for (int off = 32; off; off >>= 1) sm += __shfl_xor(sm, off);
    __syncthreads();
    if (lane == 0) red[wid] = sm;
    __syncthreads();
    float ts = 0.f;
#pragma unroll
    for (int w = 0; w < 8; ++w) ts += red[w];
    bwsh[c] = e / ts;
    __syncthreads();

    if (c < 256) {
        int d = c;
        float acc = 0.f;
        for (int cc = 0; cc < CL; ++cc)
            acc += bwsh[cc] * co[((size_t)b * CL + cc) * 256 + d];
        q2c[b * 256 + d] = acc;
    }
}

// ---------------------------------------------------------------------------
__global__ __launch_bounds__(256)
void c2q_g(const float* __restrict__ a, const float* __restrict__ qo,
           const float* __restrict__ co, const float* __restrict__ q2c,
           float* __restrict__ g)
{
    int b  = blockIdx.x;
    int c  = blockIdx.y * 64 + (threadIdx.x >> 2);
    int gq = threadIdx.x & 3;

    float4 acc[16];
#pragma unroll
    for (int jj = 0; jj < 16; ++jj) acc[jj] = make_float4(0.f, 0.f, 0.f, 0.f);

    const float* ar = a + ((size_t)b * CL + c) * QL;
    for (int q = 0; q < QL; ++q) {
        float av = ar[q];
        const float* qr = qo + ((size_t)b * QL + q) * 256;
#pragma unroll
        for (int jj = 0; jj < 16; ++jj) {
            float4 qv = *(const float4*)&qr[4 * gq + 16 * jj];
            acc[jj].x += av * qv.x; acc[jj].y += av * qv.y;
            acc[jj].z += av * qv.z; acc[jj].w += av * qv.w;
        }
    }
    size_t gbase = ((size_t)b * CL + c) * 1024;
    const float* corow = co + ((size_t)b * CL + c) * 256;
    const float* q2cr  = q2c + b * 256;
#pragma unroll
    for (int jj = 0; jj < 16; ++jj) {
        int d = 4 * gq + 16 * jj;
        float4 cv = *(const float4*)&corow[d];
        float4 qc = *(const float4*)&q2cr[d];
        float4 cq = acc[jj];
        *(float4*)&g[gbase + d] = cv;
        *(float4*)&g[gbase + 256 + d] = cq;
        float4 t;
        t.x = cv.x * cq.x; t.y = cv.y * cq.y; t.z = cv.z * cq.z; t.w = cv.w * cq.w;
        *(float4*)&g[gbase + 512 + d] = t;
        t.x = cv.x * qc.x; t.y = cv.y * qc.y; t.z = cv.z * qc.z; t.w = cv.w * qc.w;
        *(float4*)&g[gbase + 768 + d] = t;
    }
}

// ---------------------------------------------------------------------------
__global__ void logits_k(const float* __restrict__ g, const float* __restrict__ m,
                         const float* __restrict__ m2o,
                         const float* __restrict__ p1wg, const float* __restrict__ p1wm,
                         const float* __restrict__ p1b,
                         const float* __restrict__ p2wg, const float* __restrict__ p2wm,
                         const float* __restrict__ p2b,
                         float* __restrict__ lp1, float* __restrict__ lp2)
{
    int row  = (int)((blockIdx.x * blockDim.x + threadIdx.x) >> 6);
    int lane = threadIdx.x & 63;
    const float* gr = g + (size_t)row * 1024;
    float s1 = 0.f, s2 = 0.f;
    for (int d = lane; d < 1024; d += 64) {
        float gv = gr[d];
        s1 += gv * p1wg[d];
        s2 += gv * p2wg[d];
    }
    const float* mr  = m   + (size_t)row * 256;
    const float* m2r = m2o + (size_t)row * 256;
    for (int d = lane; d < 256; d += 64) {
        s1 += mr[d] * p1wm[d];
        s2 += m2r[d] * p2wm[d];
    }
#pragma unroll
    for (int off = 32; off; off >>= 1) {
        s1 += __shfl_down(s1, off);
        s2 += __shfl_down(s2, off);
    }
    if (lane == 0) {
        lp1[row] = s1 + p1b[0];
        lp2[row] = s2 + p2b[0];
    }
}

// ---------------------------------------------------------------------------
__global__ __launch_bounds__(512)
void masked_softmax(const float* __restrict__ lp1, const float* __restrict__ lp2,
                    const int* __restrict__ p, float* __restrict__ out)
{
    int b = blockIdx.x, c = threadIdx.x;
    int lane = c & 63, wid = c >> 6;
    const float* lp = blockIdx.y ? lp2 : lp1;
    float* o = out + (size_t)blockIdx.y * BB * CL;

    __shared__ float red[8];
    float v = (p[b * CL + c] != 0) ? lp[b * CL + c] : -INFINITY;
    float mx = v;
#pragma unroll
    for (int off = 32; off; off >>= 1) mx = fmaxf(mx, __shfl_xor(mx, off));
    if (lane == 0) red[wid] = mx;
    __syncthreads();
    float bm = red[0];
#pragma unroll
    for (int w = 1; w < 8; ++w) bm = fmaxf(bm, red[w]);
    float e = expf(v - bm);
    float sm = e;
#pragma unroll
    for (int off = 32; off; off >>= 1) sm += __shfl_xor(sm, off);
    __syncthreads();
    if (lane == 0) red[wid] = sm;
    __syncthreads();
    float ts = 0.f;
#pragma unroll
    for (int w = 0; w < 8; ++w) ts += red[w];
    o[b * CL + c] = e / ts;
}

// ---------------------------------------------------------------------------
extern "C" void kernel_launch(void* const* d_in, const int* in_sizes, int n_in,
                              void* d_out, int out_size, void* d_ws, size_t ws_size,
                              hipStream_t stream)
{
    const int*   p        = (const int*)d_in[0];
    const int*   q        = (const int*)d_in[1];
    const float* emb      = (const float*)d_in[2];
    const float* qenc_Wih = (const float*)d_in[3];
    const float* qenc_Whh = (const float*)d_in[4];
    const float* qenc_b   = (const float*)d_in[5];
    const float* penc_Wih = (const float*)d_in[6];
    const float* penc_Whh = (const float*)d_in[7];
    const float* penc_b   = (const float*)d_in[8];
    const float* m1_Wih   = (const float*)d_in[9];
    const float* m1_Whh   = (const float*)d_in[10];
    const float* m1_b     = (const float*)d_in[11];
    const float* m2_Wih   = (const float*)d_in[12];
    const float* m2_Whh   = (const float*)d_in[13];
    const float* m2_b     = (const float*)d_in[14];
    const float* out_Wih  = (const float*)d_in[15];
    const float* out_Whh  = (const float*)d_in[16];
    const float* out_b    = (const float*)d_in[17];
    const float* att_wc   = (const float*)d_in[18];
    const float* att_wq   = (const float*)d_in[19];
    const float* att_wcq  = (const float*)d_in[20];
    const float* att_b    = (const float*)d_in[21];
    const float* p1_wg    = (const float*)d_in[22];
    const float* p1_wm    = (const float*)d_in[23];
    const float* p1_b     = (const float*)d_in[24];
    const float* p2_wg    = (const float*)d_in[25];
    const float* p2_wm    = (const float*)d_in[26];
    const float* p2_b     = (const float*)d_in[27];

    float* ws = (float*)d_ws;
    size_t off = 0;
    auto alloc = [&](size_t n) { float* r = ws + off; off += n; return r; };
    auto allocU = [&](size_t nsh) { ushort* r = (ushort*)(ws + off); off += (nsh + 1) / 2; return r; };

    const size_t NC = (size_t)BB * CL;     // 32768
    const size_t NQ = (size_t)BB * QL;     // 4096

    float* xgA  = alloc(2 * NC * GATES);   // gate preacts, reused per layer
    float* gbuf = alloc(NC * 1024);        // g  (xgQ aliases its head: dead before g written)
    float* xgQ  = gbuf;
    float* co   = alloc(NC * 256);
    float* qo   = alloc(NQ * 256);
    float* sbuf = alloc(NC * QL);          // a (softmaxed attention)
    float* smax = alloc(NC);
    float* q2c  = alloc((size_t)BB * 256);
    float* mmid = alloc(NC * 256);
    float* mbuf = alloc(NC * 256);
    float* m2o  = alloc(NC * 256);
    float* lp1  = alloc(NC);
    float* lp2  = alloc(NC);
    // fp16 weight planes: [2][1024][Ksp]
    ushort* WqP  = allocU((size_t)2 * 1024 * 320);
    ushort* WpP  = allocU((size_t)2 * 1024 * 320);
    ushort* Wm1P = allocU((size_t)2 * 1024 * 1024);
    ushort* Wm2P = allocU((size_t)2 * 1024 * 256);
    ushort* WoP  = allocU((size_t)2 * 1024 * 256);
    (void)ws_size; (void)in_sizes; (void)n_in; (void)out_size;

    // ---- weight splits (single launch) ----
    splitW_all<<<dim3(1024, 5), 256, 0, stream>>>(qenc_Wih, penc_Wih, m1_Wih,
                                                  m2_Wih, out_Wih,
                                                  WqP, WpP, Wm1P, Wm2P, WoP);

    // ---- encoders (P and Q scans in one launch via z) ----
    gemm_f16x2<<<dim3(8, (int)(NQ / TM)), 256, 0, stream>>>(emb, q, WqP, qenc_b, xgQ, (int)NQ, 300, 320);
    gemm_f16x2<<<dim3(8, (int)(NC / TM)), 256, 0, stream>>>(emb, p, WpP, penc_b, xgA, (int)NC, 300, 320);
    lstm_dpp<<<dim3(BB, 2, 2), 512, 0, stream>>>(xgA, penc_Whh, co, CL,
                                                 xgQ, qenc_Whh, qo, QL);

    // ---- attention ----
    att_sm<<<dim3(BB, CL / 64), 256, 0, stream>>>(co, qo, att_wc, att_wq,
                                                  att_wcq, att_b, sbuf, smax);
    bwq2c_k<<<dim3(BB), 512, 0, stream>>>(smax, co, q2c);
    c2q_g<<<dim3(BB, CL / 64), 256, 0, stream>>>(sbuf, qo, co, q2c, gbuf);

    // ---- modeling layers ----
    gemm_f16x2<<<dim3(8, (int)(NC / TM)), 256, 0, stream>>>(gbuf, nullptr, Wm1P, m1_b, xgA, (int)NC, 1024, 1024);
    lstm_dpp<<<dim3(BB, 2, 1), 512, 0, stream>>>(xgA, m1_Whh, mmid, CL,
                                                 xgA, m1_Whh, mmid, CL);
    gemm_f16x2<<<dim3(8, (int)(NC / TM)), 256, 0, stream>>>(mmid, nullptr, Wm2P, m2_b, xgA, (int)NC, 256, 256);
    lstm_dpp<<<dim3(BB, 2, 1), 512, 0, stream>>>(xgA, m2_Whh, mbuf, CL,
                                                 xgA, m2_Whh, mbuf, CL);
    gemm_f16x2<<<dim3(8, (int)(NC / TM)), 256, 0, stream>>>(mbuf, nullptr, WoP, out_b, xgA, (int)NC, 256, 256);
    lstm_dpp<<<dim3(BB, 2, 1), 512, 0, stream>>>(xgA, out_Whh, m2o, CL,
                                                 xgA, out_Whh, m2o, CL);

    // ---- output ----
    logits_k<<<dim3((int)(NC * 64 / 256)), 256, 0, stream>>>(gbuf, mbuf, m2o,
        p1_wg, p1_wm, p1_b, p2_wg, p2_wm, p2_b, lp1, lp2);
    masked_softmax<<<dim3(BB, 2), 512, 0, stream>>>(lp1, lp2, p, (float*)d_out);
}

// Round 17
// 2239.279 us; speedup vs baseline: 1.4087x; 1.0622x over previous
//
#include <hip/hip_runtime.h>
#include <math.h>
#include <stdint.h>

#define HD    128      // hidden
#define GATES 512      // 4H
#define BB    64       // batch
#define CL    512      // context len
#define QL    64       // query len

#define TM 128
#define TN 128
#define TK 32
#define ASTR 36        // A row stride in floats: 144B, 16B-aligned, 2-way banks

typedef __attribute__((ext_vector_type(8))) short short8_t;
typedef __attribute__((ext_vector_type(8))) _Float16 half8_t;
typedef __attribute__((ext_vector_type(4))) float f32x4;
typedef __attribute__((ext_vector_type(2))) float f32x2;

__device__ __forceinline__ float fast_sigmoid(float x) {
    float e = __builtin_amdgcn_exp2f(-1.44269504f * x);
    return __builtin_amdgcn_rcpf(1.f + e);
}
__device__ __forceinline__ float fast_tanh(float x) {
    float e = __builtin_amdgcn_exp2f(2.88539008f * x);
    float r = __builtin_amdgcn_rcpf(e + 1.f);
    return 1.f - 2.f * r;
}
__device__ __forceinline__ float quad_sum(float v) {
    int y = __builtin_amdgcn_mov_dpp(__float_as_int(v), 0xB1, 0xF, 0xF, 0); // l^1
    float s = v + __int_as_float(y);
    int z = __builtin_amdgcn_mov_dpp(__float_as_int(s), 0x4E, 0xF, 0xF, 0); // l^2
    return s + __int_as_float(z);
}
// barrier that drains ONLY LDS ops; global loads/stores stay in flight.
__device__ __forceinline__ void lds_barrier() {
    asm volatile("s_waitcnt lgkmcnt(0)\n\ts_barrier" ::: "memory");
}
#define HPOS(e) ((e) + (((e) >> 5) << 2))

// ---------------------------------------------------------------------------
// Split 5 weight sets fp32 -> 2 fp16 planes each (RNE) in ONE launch.
// ---------------------------------------------------------------------------
__global__ __launch_bounds__(256)
void splitW_all(const float* __restrict__ w0, const float* __restrict__ w1,
                const float* __restrict__ w2, const float* __restrict__ w3,
                const float* __restrict__ w4,
                ushort* __restrict__ p0, ushort* __restrict__ p1,
                ushort* __restrict__ p2, ushort* __restrict__ p3,
                ushort* __restrict__ p4)
{
    const float* W; ushort* P; int K, Ksp;
    switch (blockIdx.y) {
    case 0: W = w0; P = p0; K = 300;  Ksp = 320;  break;
    case 1: W = w1; P = p1; K = 300;  Ksp = 320;  break;
    case 2: W = w2; P = p2; K = 1024; Ksp = 1024; break;
    case 3: W = w3; P = p3; K = 256;  Ksp = 256;  break;
    default:W = w4; P = p4; K = 256;  Ksp = 256;  break;
    }
    int idx = blockIdx.x * 256 + threadIdx.x;
    int per_row = Ksp >> 2;
    int total = 1024 * per_row;
    if (idx >= total) return;
    int row = idx / per_row;
    int c4  = (idx - row * per_row) * 4;

    ushort o1[4], o2[4];
#pragma unroll
    for (int e = 0; e < 4; ++e) {
        int k = c4 + e;
        float x = (k < K) ? W[(size_t)row * K + k] : 0.f;
        _Float16 h1 = (_Float16)x;           // RNE
        float r1 = x - (float)h1;            // exact
        _Float16 h2 = (_Float16)r1;          // RNE
        o1[e] = *(ushort*)&h1;
        o2[e] = *(ushort*)&h2;
    }
    size_t base = (size_t)row * Ksp + c4;
    size_t ps = (size_t)1024 * Ksp;
#pragma unroll
    for (int e = 0; e < 4; ++e) {
        P[base + e]      = o1[e];
        P[ps + base + e] = o2[e];
    }
}

// ---------------------------------------------------------------------------
// MFMA GEMM v13 (fp16x2, 3 cross terms): A SINGLE-buffered in LDS as raw
// fp32 with row stride 36 floats (2-way banks, no XOR needed); B = 2 fp16
// planes via global_load_lds, double-buffered (swizzled src+read).
// 51200B LDS -> 3 blocks/CU (12 waves/CU of DS-latency hiding).
// Per tile: read frags -> lgkm barrier -> stage next (A write + B DMA,
// overlapping MFMA) -> MFMA -> syncthreads.
// ---------------------------------------------------------------------------
__global__ __launch_bounds__(256, 3)
void gemm_f16x2(const float* __restrict__ A, const int* __restrict__ gidx,
                const ushort* __restrict__ Wpl, const float* __restrict__ bias,
                float* __restrict__ C, int M, int K, int Ksp)
{
    // --- XCD-locality decode (bijective; requires (M/128) % 8 == 0) ---
    const int lin  = blockIdx.x + 8 * blockIdx.y;
    const int gx   = lin & 7;
    const int idx  = lin >> 3;
    const int ndir = idx & 7;
    const int mblk = gx + ((idx >> 3) << 3);
    const int n0   = (ndir & 3) * TN;
    const int dir  = ndir >> 2;
    const int m0   = mblk * TM;

    const int tid  = threadIdx.x;
    const int lane = tid & 63;
    const int wid  = tid >> 6;
    const int wm   = (wid >> 1) * 64;
    const int wn   = (wid & 1) * 64;

    __shared__ __align__(16) float  Asf[TM * ASTR];      // 18432 B
    __shared__ __align__(16) ushort Bs[2][2][TN * TK];   // 32768 B

    const int srow = tid >> 3;
    const int scol = tid & 7;
    size_t sArow[4];
#pragma unroll
    for (int r = 0; r < 4; ++r) {
        int m = m0 + srow + r * 32;
        sArow[r] = gidx ? (size_t)gidx[m] : (size_t)m;
    }

    const int s0 = (lane >> 4) * 2;

    f32x4 acc[4][4];
#pragma unroll
    for (int i = 0; i < 4; ++i)
#pragma unroll
        for (int j = 0; j < 4; ++j) acc[i][j] = (f32x4)0.f;

    const size_t wps    = (size_t)1024 * Ksp;
    const size_t wdbase = (size_t)dir * 512 * Ksp;
    const int nt = Ksp / TK;

    auto stageB = [&](int k0, int bufb) {
#pragma unroll
        for (int t = 0; t < 4; ++t) {
            int chunk = wid * 4 + t;        // 0..15: 2 planes x 8 chunks
            int pl = chunk >> 3;
            int ch = chunk & 7;
            int rrow = ch * 16 + (lane >> 2);
            int ksw  = ((lane & 3) ^ ((rrow >> 1) & 3)) * 8;
            const ushort* src = Wpl + (size_t)pl * wps + wdbase +
                                (size_t)(n0 + rrow) * Ksp + k0 + ksw;
            ushort* dst = &Bs[bufb][pl][ch * 512];
            __builtin_amdgcn_global_load_lds(
                reinterpret_cast<const __attribute__((address_space(1))) void*>(
                    reinterpret_cast<uintptr_t>(src)),
                reinterpret_cast<__attribute__((address_space(3))) void*>(
                    reinterpret_cast<uintptr_t>(dst)),
                16, 0, 0);
        }
    };
    auto stageA = [&](int k0) {
#pragma unroll
        for (int r = 0; r < 4; ++r) {
            int row = srow + r * 32;
            int kf  = k0 + scol * 4;
            float4 v;
            if (kf + 4 <= K) {
                v = *(const float4*)(A + sArow[r] * K + kf);
            } else {
                const float* ap = A + sArow[r] * K;
                v.x = (kf     < K) ? ap[kf]     : 0.f;
                v.y = (kf + 1 < K) ? ap[kf + 1] : 0.f;
                v.z = (kf + 2 < K) ? ap[kf + 2] : 0.f;
                v.w = (kf + 3 < K) ? ap[kf + 3] : 0.f;
            }
            *(float4*)&Asf[row * ASTR + scol * 4] = v;
        }
    };

    stageB(0, 0);
    stageA(0);
    __syncthreads();

    int buf = 0;
    for (int kt = 0; kt < nt; ++kt) {
        // ---- read current fragments into registers ----
        float4 fa[4], fb[4];
#pragma unroll
        for (int i = 0; i < 4; ++i) {
            int mrow = wm + i * 16 + (lane & 15);
            fa[i] = *(const float4*)&Asf[mrow * ASTR + (s0)     * 4];
            fb[i] = *(const float4*)&Asf[mrow * ASTR + (s0 + 1) * 4];
        }
        half8_t bf0[4], bf1[4];
#pragma unroll
        for (int j = 0; j < 4; ++j) {
            int nrow = wn + j * 16 + (lane & 15);
            int ks = (((lane >> 4) ^ ((nrow >> 1) & 3)) * 8);
            bf0[j] = *reinterpret_cast<const half8_t*>(&Bs[buf][0][nrow * TK + ks]);
            bf1[j] = *reinterpret_cast<const half8_t*>(&Bs[buf][1][nrow * TK + ks]);
        }
        lds_barrier();   // all waves done reading Asf (lgkm drained)

        // ---- stage next tile (A writes safe; B DMA overlaps MFMA) ----
        if (kt + 1 < nt) {
            stageA((kt + 1) * TK);
            stageB((kt + 1) * TK, buf ^ 1);
        }

        // ---- split + MFMA (register-only) ----
#pragma unroll
        for (int i = 0; i < 4; ++i) {
            float xs[8] = {fa[i].x, fa[i].y, fa[i].z, fa[i].w,
                           fb[i].x, fb[i].y, fb[i].z, fb[i].w};
            half8_t a1, a2;
#pragma unroll
            for (int e = 0; e < 8; ++e) {
                _Float16 h1 = (_Float16)xs[e];
                float r = xs[e] - (float)h1;
                a1[e] = h1;
                a2[e] = (_Float16)r;
            }
#pragma unroll
            for (int j = 0; j < 4; ++j) {
                f32x4 c = acc[i][j];
                c = __builtin_amdgcn_mfma_f32_16x16x32_f16(a1, bf0[j], c, 0, 0, 0);
                c = __builtin_amdgcn_mfma_f32_16x16x32_f16(a1, bf1[j], c, 0, 0, 0);
                c = __builtin_amdgcn_mfma_f32_16x16x32_f16(a2, bf0[j], c, 0, 0, 0);
                acc[i][j] = c;
            }
        }
        __syncthreads();   // A writes visible + B DMA (vmcnt) drained
        buf ^= 1;
    }

    float* Cd = C + (size_t)dir * M * 512;
#pragma unroll
    for (int j = 0; j < 4; ++j) {
        int col = n0 + wn + j * 16 + (lane & 15);
        float bv = bias[dir * 512 + col];
#pragma unroll
        for (int i = 0; i < 4; ++i) {
            int rbase = m0 + wm + i * 16 + ((lane >> 4) << 2);
#pragma unroll
            for (int r = 0; r < 4; ++r)
                Cd[(size_t)(rbase + r) * 512 + col] = acc[i][j][r] + bv;
        }
    }
}

// ---------------------------------------------------------------------------
// LSTM scan v11 (unchanged; measured pass @1.5e-5).
// ---------------------------------------------------------------------------
__global__ __launch_bounds__(512) __attribute__((amdgpu_waves_per_eu(2, 2)))
void lstm_dpp(const float* __restrict__ xgP, const float* __restrict__ WhhP,
              float* __restrict__ hoP, int TP,
              const float* __restrict__ xgQ, const float* __restrict__ WhhQ,
              float* __restrict__ hoQ, int TQ)
{
    const int b    = blockIdx.x;
    const int dir  = blockIdx.y;
    const int tid  = threadIdx.x;
    const int l    = tid & 63;
    const int w    = tid >> 6;
    const int u    = w * 16 + (l >> 2);   // hidden unit 0..127
    const int s    = l & 3;               // k-slice 0..3

    const float* xg; const float* Whh; float* ho; int T;
    if (blockIdx.z == 0) { xg = xgP; Whh = WhhP; ho = hoP; T = TP; }
    else                 { xg = xgQ; Whh = WhhQ; ho = hoQ; T = TQ; }

    const float* xgd = xg + (size_t)dir * BB * T * GATES;

    f32x2 wv2[4][16];
#pragma unroll
    for (int g = 0; g < 4; ++g) {
        const float* wr = Whh + ((size_t)dir * GATES + g * 128 + u) * HD + s * 32;
#pragma unroll
        for (int j = 0; j < 8; ++j) {
            float4 t4 = *(const float4*)(wr + j * 4);
            wv2[g][2 * j]     = f32x2{t4.x, t4.y};
            wv2[g][2 * j + 1] = f32x2{t4.z, t4.w};
        }
    }

    __shared__ __align__(16) float hs[2][140];

    if (tid < 140) { hs[0][tid] = 0.f; }
    float c = 0.f;

    int t = dir ? (T - 1) : 0;
    const int dt = dir ? -1 : 1;

    float xc[4], xn1[4], xn2[4];
    {
        int t1 = t + dt; if (t1 < 0) t1 = 0; if (t1 >= T) t1 = T - 1;
#pragma unroll
        for (int g = 0; g < 4; ++g) {
            xc[g]  = xgd[((size_t)b * T + t)  * GATES + g * 128 + u];
            xn1[g] = xgd[((size_t)b * T + t1) * GATES + g * 128 + u];
        }
    }

    const int rdbase = HPOS(s * 32);
    __syncthreads();

    for (int step = 0; step < T; ++step) {
        const int rbuf = step & 1, wbuf = rbuf ^ 1;

        {
            int t2 = t + 2 * dt;
            if (t2 < 0) t2 = 0; if (t2 >= T) t2 = T - 1;
#pragma unroll
            for (int g = 0; g < 4; ++g)
                xn2[g] = xgd[((size_t)b * T + t2) * GATES + g * 128 + u];
        }

        f32x2 p0 = {0.f, 0.f}, p1 = {0.f, 0.f}, p2 = {0.f, 0.f}, p3 = {0.f, 0.f};
#pragma unroll
        for (int j = 0; j < 8; ++j) {
            float4 h4 = *(const float4*)&hs[rbuf][rdbase + j * 4];
            f32x2 hl = {h4.x, h4.y}, hh = {h4.z, h4.w};
            p0 = __builtin_elementwise_fma(wv2[0][2 * j], hl, p0);
            p1 = __builtin_elementwise_fma(wv2[1][2 * j], hl, p1);
            p2 = __builtin_elementwise_fma(wv2[2][2 * j], hl, p2);
            p3 = __builtin_elementwise_fma(wv2[3][2 * j], hl, p3);
            p0 = __builtin_elementwise_fma(wv2[0][2 * j + 1], hh, p0);
            p1 = __builtin_elementwise_fma(wv2[1][2 * j + 1], hh, p1);
            p2 = __builtin_elementwise_fma(wv2[2][2 * j + 1], hh, p2);
            p3 = __builtin_elementwise_fma(wv2[3][2 * j + 1], hh, p3);
        }
        float pre0 = quad_sum(p0.x + p0.y) + xc[0];
        float pre1 = quad_sum(p1.x + p1.y) + xc[1];
        float pre2 = quad_sum(p2.x + p2.y) + xc[2];
        float pre3 = quad_sum(p3.x + p3.y) + xc[3];

        float ig = fast_sigmoid(pre0);
        float fg = fast_sigmoid(pre1);
        float gg = fast_tanh(pre2);
        float og = fast_sigmoid(pre3);
        c = fg * c + ig * gg;
        float h = og * fast_tanh(c);

        if (s == 0) {
            hs[wbuf][HPOS(u)] = h;
            ho[((size_t)b * T + t) * 256 + dir * HD + u] = h;
        }
        lds_barrier();

#pragma unroll
        for (int g = 0; g < 4; ++g) { xc[g] = xn1[g]; xn1[g] = xn2[g]; }
        t += dt;
    }
}

// ---------------------------------------------------------------------------
// Fused attention: similarity + q-softmax + row max.
// ---------------------------------------------------------------------------
__global__ __launch_bounds__(256)
void att_sm(const float* __restrict__ co, const float* __restrict__ qo,
            const float* __restrict__ wc, const float* __restrict__ wq,
            const float* __restrict__ wcq, const float* __restrict__ attb,
            float* __restrict__ a_out, float* __restrict__ smax)
{
    int b  = blockIdx.x;
    int c0 = blockIdx.y * 64;
    int tid = threadIdx.x;
    int tq = tid & 15, trc = tid >> 4;
    int cbase = c0 + trc * 4, qbase = tq * 4;

    float acc[4][4], cwa[4], qwa[4];
#pragma unroll
    for (int i = 0; i < 4; ++i) {
        cwa[i] = 0.f; qwa[i] = 0.f;
#pragma unroll
        for (int j = 0; j < 4; ++j) acc[i][j] = 0.f;
    }

    for (int d = 0; d < 256; d += 4) {
        float4 wv  = *(const float4*)&wcq[d];
        float4 wcv = *(const float4*)&wc[d];
        float4 wqv = *(const float4*)&wq[d];
        float4 cvw[4], qv[4];
#pragma unroll
        for (int i = 0; i < 4; ++i) {
            float4 v = *(const float4*)&co[((size_t)b * CL + cbase + i) * 256 + d];
            cwa[i] += v.x * wcv.x + v.y * wcv.y + v.z * wcv.z + v.w * wcv.w;
            cvw[i].x = v.x * wv.x; cvw[i].y = v.y * wv.y;
            cvw[i].z = v.z * wv.z; cvw[i].w = v.w * wv.w;
        }
#pragma unroll
        for (int j = 0; j < 4; ++j) {
            qv[j] = *(const float4*)&qo[((size_t)b * QL + qbase + j) * 256 + d];
            qwa[j] += qv[j].x * wqv.x + qv[j].y * wqv.y +
                      qv[j].z * wqv.z + qv[j].w * wqv.w;
        }
#pragma unroll
        for (int i = 0; i < 4; ++i)
#pragma unroll
            for (int j = 0; j < 4; ++j)
                acc[i][j] += cvw[i].x * qv[j].x + cvw[i].y * qv[j].y +
                             cvw[i].z * qv[j].z + cvw[i].w * qv[j].w;
    }
    float ab = attb[0];
#pragma unroll
    for (int i = 0; i < 4; ++i) {
        float sv[4];
#pragma unroll
        for (int j = 0; j < 4; ++j)
            sv[j] = acc[i][j] + cwa[i] + qwa[j] + ab;
        float m = fmaxf(fmaxf(sv[0], sv[1]), fmaxf(sv[2], sv[3]));
#pragma unroll
        for (int off = 8; off; off >>= 1) m = fmaxf(m, __shfl_xor(m, off));
        float e0 = expf(sv[0] - m), e1 = expf(sv[1] - m);
        float e2 = expf(sv[2] - m), e3 = expf(sv[3] - m);
        float ls = (e0 + e1) + (e2 + e3);
#pragma unroll
        for (int off = 8; off; off >>= 1) ls += __shfl_xor(ls, off);
        float inv = 1.f / ls;
        float* ar = a_out + ((size_t)b * CL + cbase + i) * QL + qbase;
        ar[0] = e0 * inv; ar[1] = e1 * inv; ar[2] = e2 * inv; ar[3] = e3 * inv;
        if (tq == 0) smax[b * CL + cbase + i] = m;
    }
}

// ---------------------------------------------------------------------------
// Fused bw softmax + q2c.
// ---------------------------------------------------------------------------
__global__ __launch_bounds__(512)
void bwq2c_k(const float* __restrict__ smax, const float* __restrict__ co,
             float* __restrict__ q2c)
{
    int b = blockIdx.x, c = threadIdx.x;
    int lane = c & 63, wid = c >> 6;
    __shared__ float red[8];
    __shared__ float bwsh[CL];

    float v = smax[b * CL + c];
    float mx = v;
#pragma unroll
    for (int off = 32; off; off >>= 1) mx = fmaxf(mx, __shfl_xor(mx, off));
    if (lane == 0) red[wid] = mx;
    __syncthreads();
    float bm = red[0];
#pragma unroll
    for (int w = 1; w < 8; ++w) bm = fmaxf(bm, red[w]);
    float e = expf(v - bm);
    float sm = e;
#pragma unroll
    for (int off = 32; off; off >>= 1) sm += __shfl_xor(sm, off);
    __syncthreads();
    if (lane == 0) red[wid] = sm;
    __syncthreads();
    float ts = 0.f;
#pragma unroll
    for (int w = 0; w < 8; ++w) ts += red[w];
    bwsh[c] = e / ts;
    __syncthreads();

    if (c < 256) {
        int d = c;
        float acc = 0.f;
        for (int cc = 0; cc < CL; ++cc)
            acc += bwsh[cc] * co[((size_t)b * CL + cc) * 256 + d];
        q2c[b * 256 + d] = acc;
    }
}

// ---------------------------------------------------------------------------
__global__ __launch_bounds__(256)
void c2q_g(const float* __restrict__ a, const float* __restrict__ qo,
           const float* __restrict__ co, const float* __restrict__ q2c,
           float* __restrict__ g)
{
    int b  = blockIdx.x;
    int c  = blockIdx.y * 64 + (threadIdx.x >> 2);
    int gq = threadIdx.x & 3;

    float4 acc[16];
#pragma unroll
    for (int jj = 0; jj < 16; ++jj) acc[jj] = make_float4(0.f, 0.f, 0.f, 0.f);

    const float* ar = a + ((size_t)b * CL + c) * QL;
    for (int q = 0; q < QL; ++q) {
        float av = ar[q];
        const float* qr = qo + ((size_t)b * QL + q) * 256;
#pragma unroll
        for (int jj = 0; jj < 16; ++jj) {
            float4 qv = *(const float4*)&qr[4 * gq + 16 * jj];
            acc[jj].x += av * qv.x; acc[jj].y += av * qv.y;
            acc[jj].z += av * qv.z; acc[jj].w += av * qv.w;
        }
    }
    size_t gbase = ((size_t)b * CL + c) * 1024;
    const float* corow = co + ((size_t)b * CL + c) * 256;
    const float* q2cr  = q2c + b * 256;
#pragma unroll
    for (int jj = 0; jj < 16; ++jj) {
        int d = 4 * gq + 16 * jj;
        float4 cv = *(const float4*)&corow[d];
        float4 qc = *(const float4*)&q2cr[d];
        float4 cq = acc[jj];
        *(float4*)&g[gbase + d] = cv;
        *(float4*)&g[gbase + 256 + d] = cq;
        float4 t;
        t.x = cv.x * cq.x; t.y = cv.y * cq.y; t.z = cv.z * cq.z; t.w = cv.w * cq.w;
        *(float4*)&g[gbase + 512 + d] = t;
        t.x = cv.x * qc.x; t.y = cv.y * qc.y; t.z = cv.z * qc.z; t.w = cv.w * qc.w;
        *(float4*)&g[gbase + 768 + d] = t;
    }
}

// ---------------------------------------------------------------------------
__global__ void logits_k(const float* __restrict__ g, const float* __restrict__ m,
                         const float* __restrict__ m2o,
                         const float* __restrict__ p1wg, const float* __restrict__ p1wm,
                         const float* __restrict__ p1b,
                         const float* __restrict__ p2wg, const float* __restrict__ p2wm,
                         const float* __restrict__ p2b,
                         float* __restrict__ lp1, float* __restrict__ lp2)
{
    int row  = (int)((blockIdx.x * blockDim.x + threadIdx.x) >> 6);
    int lane = threadIdx.x & 63;
    const float* gr = g + (size_t)row * 1024;
    float s1 = 0.f, s2 = 0.f;
    for (int d = lane; d < 1024; d += 64) {
        float gv = gr[d];
        s1 += gv * p1wg[d];
        s2 += gv * p2wg[d];
    }
    const float* mr  = m   + (size_t)row * 256;
    const float* m2r = m2o + (size_t)row * 256;
    for (int d = lane; d < 256; d += 64) {
        s1 += mr[d] * p1wm[d];
        s2 += m2r[d] * p2wm[d];
    }
#pragma unroll
    for (int off = 32; off; off >>= 1) {
        s1 += __shfl_down(s1, off);
        s2 += __shfl_down(s2, off);
    }
    if (lane == 0) {
        lp1[row] = s1 + p1b[0];
        lp2[row] = s2 + p2b[0];
    }
}

// ---------------------------------------------------------------------------
__global__ __launch_bounds__(512)
void masked_softmax(const float* __restrict__ lp1, const float* __restrict__ lp2,
                    const int* __restrict__ p, float* __restrict__ out)
{
    int b = blockIdx.x, c = threadIdx.x;
    int lane = c & 63, wid = c >> 6;
    const float* lp = blockIdx.y ? lp2 : lp1;
    float* o = out + (size_t)blockIdx.y * BB * CL;

    __shared__ float red[8];
    float v = (p[b * CL + c] != 0) ? lp[b * CL + c] : -INFINITY;
    float mx = v;
#pragma unroll
    for (int off = 32; off; off >>= 1) mx = fmaxf(mx, __shfl_xor(mx, off));
    if (lane == 0) red[wid] = mx;
    __syncthreads();
    float bm = red[0];
#pragma unroll
    for (int w = 1; w < 8; ++w) bm = fmaxf(bm, red[w]);
    float e = expf(v - bm);
    float sm = e;
#pragma unroll
    for (int off = 32; off; off >>= 1) sm += __shfl_xor(sm, off);
    __syncthreads();
    if (lane == 0) red[wid] = sm;
    __syncthreads();
    float ts = 0.f;
#pragma unroll
    for (int w = 0; w < 8; ++w) ts += red[w];
    o[b * CL + c] = e / ts;
}

// ---------------------------------------------------------------------------
extern "C" void kernel_launch(void* const* d_in, const int* in_sizes, int n_in,
                              void* d_out, int out_size, void* d_ws, size_t ws_size,
                              hipStream_t stream)
{
    const int*   p        = (const int*)d_in[0];
    const int*   q        = (const int*)d_in[1];
    const float* emb      = (const float*)d_in[2];
    const float* qenc_Wih = (const float*)d_in[3];
    const float* qenc_Whh = (const float*)d_in[4];
    const float* qenc_b   = (const float*)d_in[5];
    const float* penc_Wih = (const float*)d_in[6];
    const float* penc_Whh = (const float*)d_in[7];
    const float* penc_b   = (const float*)d_in[8];
    const float* m1_Wih   = (const float*)d_in[9];
    const float* m1_Whh   = (const float*)d_in[10];
    const float* m1_b     = (const float*)d_in[11];
    const float* m2_Wih   = (const float*)d_in[12];
    const float* m2_Whh   = (const float*)d_in[13];
    const float* m2_b     = (const float*)d_in[14];
    const float* out_Wih  = (const float*)d_in[15];
    const float* out_Whh  = (const float*)d_in[16];
    const float* out_b    = (const float*)d_in[17];
    const float* att_wc   = (const float*)d_in[18];
    const float* att_wq   = (const float*)d_in[19];
    const float* att_wcq  = (const float*)d_in[20];
    const float* att_b    = (const float*)d_in[21];
    const float* p1_wg    = (const float*)d_in[22];
    const float* p1_wm    = (const float*)d_in[23];
    const float* p1_b     = (const float*)d_in[24];
    const float* p2_wg    = (const float*)d_in[25];
    const float* p2_wm    = (const float*)d_in[26];
    const float* p2_b     = (const float*)d_in[27];

    float* ws = (float*)d_ws;
    size_t off = 0;
    auto alloc = [&](size_t n) { float* r = ws + off; off += n; return r; };
    auto allocU = [&](size_t nsh) { ushort* r = (ushort*)(ws + off); off += (nsh + 1) / 2; return r; };

    const size_t NC = (size_t)BB * CL;     // 32768
    const size_t NQ = (size_t)BB * QL;     // 4096

    float* xgA  = alloc(2 * NC * GATES);   // gate preacts, reused per layer
    float* gbuf = alloc(NC * 1024);        // g  (xgQ aliases its head: dead before g written)
    float* xgQ  = gbuf;
    float* co   = alloc(NC * 256);
    float* qo   = alloc(NQ * 256);
    float* sbuf = alloc(NC * QL);          // a (softmaxed attention)
    float* smax = alloc(NC);
    float* q2c  = alloc((size_t)BB * 256);
    float* mmid = alloc(NC * 256);
    float* mbuf = alloc(NC * 256);
    float* m2o  = alloc(NC * 256);
    float* lp1  = alloc(NC);
    float* lp2  = alloc(NC);
    // fp16 weight planes: [2][1024][Ksp]
    ushort* WqP  = allocU((size_t)2 * 1024 * 320);
    ushort* WpP  = allocU((size_t)2 * 1024 * 320);
    ushort* Wm1P = allocU((size_t)2 * 1024 * 1024);
    ushort* Wm2P = allocU((size_t)2 * 1024 * 256);
    ushort* WoP  = allocU((size_t)2 * 1024 * 256);
    (void)ws_size; (void)in_sizes; (void)n_in; (void)out_size;

    // ---- weight splits (single launch) ----
    splitW_all<<<dim3(1024, 5), 256, 0, stream>>>(qenc_Wih, penc_Wih, m1_Wih,
                                                  m2_Wih, out_Wih,
                                                  WqP, WpP, Wm1P, Wm2P, WoP);

    // ---- encoders (P and Q scans in one launch via z) ----
    gemm_f16x2<<<dim3(8, (int)(NQ / TM)), 256, 0, stream>>>(emb, q, WqP, qenc_b, xgQ, (int)NQ, 300, 320);
    gemm_f16x2<<<dim3(8, (int)(NC / TM)), 256, 0, stream>>>(emb, p, WpP, penc_b, xgA, (int)NC, 300, 320);
    lstm_dpp<<<dim3(BB, 2, 2), 512, 0, stream>>>(xgA, penc_Whh, co, CL,
                                                 xgQ, qenc_Whh, qo, QL);

    // ---- attention ----
    att_sm<<<dim3(BB, CL / 64), 256, 0, stream>>>(co, qo, att_wc, att_wq,
                                                  att_wcq, att_b, sbuf, smax);
    bwq2c_k<<<dim3(BB), 512, 0, stream>>>(smax, co, q2c);
    c2q_g<<<dim3(BB, CL / 64), 256, 0, stream>>>(sbuf, qo, co, q2c, gbuf);

    // ---- modeling layers ----
    gemm_f16x2<<<dim3(8, (int)(NC / TM)), 256, 0, stream>>>(gbuf, nullptr, Wm1P, m1_b, xgA, (int)NC, 1024, 1024);
    lstm_dpp<<<dim3(BB, 2, 1), 512, 0, stream>>>(xgA, m1_Whh, mmid, CL,
                                                 xgA, m1_Whh, mmid, CL);
    gemm_f16x2<<<dim3(8, (int)(NC / TM)), 256, 0, stream>>>(mmid, nullptr, Wm2P, m2_b, xgA, (int)NC, 256, 256);
    lstm_dpp<<<dim3(BB, 2, 1), 512, 0, stream>>>(xgA, m2_Whh, mbuf, CL,
                                                 xgA, m2_Whh, mbuf, CL);
    gemm_f16x2<<<dim3(8, (int)(NC / TM)), 256, 0, stream>>>(mbuf, nullptr, WoP, out_b, xgA, (int)NC, 256, 256);
    lstm_dpp<<<dim3(BB, 2, 1), 512, 0, stream>>>(xgA, out_Whh, m2o, CL,
                                                 xgA, out_Whh, m2o, CL);

    // ---- output ----
    logits_k<<<dim3((int)(NC * 64 / 256)), 256, 0, stream>>>(gbuf, mbuf, m2o,
        p1_wg, p1_wm, p1_b, p2_wg, p2_wm, p2_b, lp1, lp2);
    masked_softmax<<<dim3(BB, 2), 512, 0, stream>>>(lp1, lp2, p, (float*)d_out);
}